// Round 12
// baseline (2828.500 us; speedup 1.0000x reference)
//
#include <hip/hip_runtime.h>
#include <cmath>

// ---------------------------------------------------------------------------
// QRNN decoder, MI355X. B=32 T=64 S=128 EMB=H=E=512 V=32000 K=2.
// NUMERICS INVARIANT (r4/r6/r10/r11 pass vs r7/r8/r9 fail): anything feeding
// the c1/h1 recurrence (cpW GEMV, EP) must be f32-exact; fp16 only on
// output-side paths (att_vec, logits) or as hi/lo split pairs.
// PERF MODEL (r11 counters): decode at ~41% of per-CU TA ceiling —
// latency/TLP + phase serialization. This round: 1024 threads (16 waves,
// 4/SIMD), wave-specialized overlap: gv (cpWT GEMV, needs only c1) runs on
// waves 8-15 concurrently with scores (waves 0-7) and softmax (wave 0),
// split 64+64 iters across two barrier intervals. All summation orders and
// lane mappings bit-identical to r11.
// ---------------------------------------------------------------------------

typedef _Float16 half8  __attribute__((ext_vector_type(8)));
typedef float    f32x4  __attribute__((ext_vector_type(4)));

#define DEVFN static __device__ __forceinline__

DEVFN float sigp(float x){ return 1.f/(1.f+expf(-x)); }

DEVFN void glds16(const _Float16* g, _Float16* l){
  __builtin_amdgcn_global_load_lds((const __attribute__((address_space(1))) void*)g,
                                   (__attribute__((address_space(3))) void*)l, 16, 0, 0);
}

// ---------------- encoder-hidden projections: 5 x (B,E)@(E,H), f32 ---------
__global__ void ep_proj(const float* __restrict__ ehid,
    const float* __restrict__ w0, const float* __restrict__ b0,
    const float* __restrict__ w1, const float* __restrict__ b1,
    const float* __restrict__ w2, const float* __restrict__ b2,
    const float* __restrict__ w3, const float* __restrict__ b3,
    const float* __restrict__ w4, const float* __restrict__ b4,
    float* __restrict__ ep)
{
  int gid = blockIdx.x*256 + threadIdx.x;            // 5*32*512*4 = 327680
  int q = gid & 3, h = (gid>>2)&511, b = (gid>>11)&31, p = gid>>16;
  const float* w    = (p==0)?w0:(p==1)?w1:(p==2)?w2:(p==3)?w3:w4;
  const float* bias = (p==0)?b0:(p==1)?b1:(p==2)?b2:(p==3)?b3:b4;
  const float* x  = ehid + ((p>=3)?32*512:0) + b*512 + q*128;
  const float* wr = w + (size_t)h*512 + q*128;
  float acc = 0.f;
  #pragma unroll 8
  for (int j=0;j<128;j+=4){
    float4 wv = *(const float4*)(wr+j);
    float4 xv = *(const float4*)(x+j);
    acc += wv.x*xv.x + wv.y*xv.y + wv.z*xv.z + wv.w*xv.w;
  }
  acc += __shfl_xor(acc,1); acc += __shfl_xor(acc,2);
  if (q==0) ep[p*16384 + b*512 + h] = acc + bias[h];
}

// ---------------- hi/lo fp16 packing + cpW transpose -----------------------
__global__ void pack2(const float* __restrict__ trg,
  const float* __restrict__ zW0, const float* __restrict__ fW0,
  const float* __restrict__ oW0, const float* __restrict__ iW0,
  const float* __restrict__ zW1, const float* __restrict__ fW1,
  const float* __restrict__ oW1,
  const float* __restrict__ enc, const float* __restrict__ kpW,
  const float* __restrict__ cpW,
  _Float16* __restrict__ A0h, _Float16* __restrict__ A0l,
  _Float16* __restrict__ W0h, _Float16* __restrict__ W0l,
  _Float16* __restrict__ W1h, _Float16* __restrict__ W1l,
  _Float16* __restrict__ ench, _Float16* __restrict__ encl,
  _Float16* __restrict__ kph, _Float16* __restrict__ kpl,
  float* __restrict__ cpWT)
{
  int gid = blockIdx.x*256 + threadIdx.x;            // 8,388,608 total
  float v; _Float16 *ph, *pl; int idx;
  if (gid < 2097152) {
    idx = gid;
    int m = idx >> 10, c = idx & 1023, t = m & 63, kk = c >> 9, i = c & 511;
    v = (kk==0) ? ((t>0) ? trg[(size_t)(m-1)*512 + i] : 0.f)
                : trg[(size_t)m*512 + i];
    ph = A0h; pl = A0l;
  } else if (gid < 4194304) {
    idx = gid - 2097152;
    int r = idx >> 10, c = idx & 1023, g = r >> 9, o = r & 511, kk = c >> 9, i = c & 511;
    const float* W = (g==0)?zW0:(g==1)?fW0:(g==2)?oW0:iW0;
    v = W[(size_t)o*1024 + i*2 + kk];
    ph = W0h; pl = W0l;
  } else if (gid < 5767168) {
    idx = gid - 4194304;
    int r = idx >> 10, c = idx & 1023, g = r >> 9, o = r & 511, kk = c >> 9, i = c & 511;
    const float* W = (g==0)?zW1:(g==1)?fW1:oW1;
    v = W[(size_t)o*1024 + i*2 + kk];
    ph = W1h; pl = W1l;
  } else if (gid < 7864320) {
    idx = gid - 5767168;
    v = enc[idx];
    ph = ench; pl = encl;
  } else if (gid < 8126464) {
    idx = gid - 7864320;
    v = kpW[idx];
    ph = kph; pl = kpl;
  } else {                                            // cpWT[c][h] = cpW[h][c]
    idx = gid - 8126464;                              // 262144
    int h = idx >> 9, c = idx & 511;
    cpWT[(size_t)c*512 + h] = cpW[(size_t)h*512 + c];
    return;
  }
  _Float16 hi = (_Float16)v;
  _Float16 lo = (_Float16)(v - (float)hi);
  ph[idx] = hi; pl[idx] = lo;
}

// ---------------- split-fp16 3-term MFMA GEMM ------------------------------
__global__ __launch_bounds__(256) void gemm3(
    const _Float16* __restrict__ Ah, const _Float16* __restrict__ Al,
    const _Float16* __restrict__ Bh, const _Float16* __restrict__ Bl,
    float* __restrict__ C, int Kd, int ldc)
{
  __shared__ __align__(16) _Float16 Ahs[4096];
  __shared__ __align__(16) _Float16 Als[4096];
  __shared__ __align__(16) _Float16 Bhs[4096];
  __shared__ __align__(16) _Float16 Bls[4096];
  const int tid = threadIdx.x, lane = tid & 63, wave = tid >> 6;
  const int bm = blockIdx.x, bn = blockIdx.y;
  const int wm = wave >> 1, wn = wave & 1;
  const size_t aoff = ((size_t)bm*128 + wave*16 + (lane>>2))*Kd + (lane&3)*8;
  const size_t boff = ((size_t)bn*128 + wave*16 + (lane>>2))*Kd + (lane&3)*8;
  const size_t hstep = (size_t)64*Kd;
  _Float16* Ahl = Ahs + wave*512;
  _Float16* All = Als + wave*512;
  _Float16* Bhl = Bhs + wave*512;
  _Float16* Bll = Bls + wave*512;
  f32x4 acc[4][4] = {};
  for (int k0 = 0; k0 < Kd; k0 += 32) {
    glds16(Ah + aoff + k0, Ahl);  glds16(Ah + aoff + hstep + k0, Ahl + 2048);
    glds16(Al + aoff + k0, All);  glds16(Al + aoff + hstep + k0, All + 2048);
    glds16(Bh + boff + k0, Bhl);  glds16(Bh + boff + hstep + k0, Bhl + 2048);
    glds16(Bl + boff + k0, Bll);  glds16(Bl + boff + hstep + k0, Bll + 2048);
    __syncthreads();
    const int ar = lane & 15, kb = (lane>>4)*8;
    half8 ah[4], al[4], bh[4], bl[4];
    #pragma unroll
    for (int m=0;m<4;++m){
      ah[m] = *(const half8*)&Ahs[(wm*64 + m*16 + ar)*32 + kb];
      al[m] = *(const half8*)&Als[(wm*64 + m*16 + ar)*32 + kb];
    }
    #pragma unroll
    for (int n=0;n<4;++n){
      bh[n] = *(const half8*)&Bhs[(wn*64 + n*16 + ar)*32 + kb];
      bl[n] = *(const half8*)&Bls[(wn*64 + n*16 + ar)*32 + kb];
    }
    #pragma unroll
    for (int m=0;m<4;++m)
      #pragma unroll
      for (int n=0;n<4;++n){
        acc[m][n] = __builtin_amdgcn_mfma_f32_16x16x32_f16(ah[m], bh[n], acc[m][n], 0,0,0);
        acc[m][n] = __builtin_amdgcn_mfma_f32_16x16x32_f16(ah[m], bl[n], acc[m][n], 0,0,0);
        acc[m][n] = __builtin_amdgcn_mfma_f32_16x16x32_f16(al[m], bh[n], acc[m][n], 0,0,0);
      }
    __syncthreads();
  }
  const int r0 = bm*128 + wm*64 + ((lane>>4)<<2);
  const int c0 = bn*128 + wn*64 + (lane&15);
  #pragma unroll
  for (int m=0;m<4;++m)
    #pragma unroll
    for (int n=0;n<4;++n)
      #pragma unroll
      for (int e=0;e<4;++e)
        C[(size_t)(r0 + m*16 + e)*ldc + c0 + n*16] = acc[m][n][e];
}

// ---------------- vocab GEMM: plain fp16 A x f32->fp16 B -------------------
__global__ __launch_bounds__(256) void gemm_hf(
    const _Float16* __restrict__ A, const float* __restrict__ Bf,
    float* __restrict__ C, int Kd, int ldc)
{
  __shared__ __align__(16) _Float16 As[128*32];
  __shared__ __align__(16) _Float16 Bs[128*32];
  const int tid = threadIdx.x, lane = tid & 63, wave = tid >> 6;
  const int bm = blockIdx.x, bn = blockIdx.y;
  const int wm = wave >> 1, wn = wave & 1;
  const _Float16* Ag = A + ((size_t)bm*128 + wave*16 + (lane>>2))*Kd + (lane&3)*8;
  _Float16* Al = As + wave*512;
  const float* Bg = Bf + ((size_t)bn*128 + (tid>>2))*Kd + (tid&3)*8;
  f32x4 acc[4][4] = {};
  for (int k0 = 0; k0 < Kd; k0 += 32) {
    glds16(Ag + k0, Al);
    glds16(Ag + (size_t)64*Kd + k0, Al + 2048);
    #pragma unroll
    for (int i=0;i<2;++i){
      const float* src = Bg + (size_t)i*64*Kd + k0;
      float4 f0 = *(const float4*)src;
      float4 f1 = *(const float4*)(src+4);
      half8 hv = {(_Float16)f0.x,(_Float16)f0.y,(_Float16)f0.z,(_Float16)f0.w,
                  (_Float16)f1.x,(_Float16)f1.y,(_Float16)f1.z,(_Float16)f1.w};
      *(half8*)&Bs[i*2048 + tid*8] = hv;
    }
    __syncthreads();
    half8 af[4], bf[4];
    const int ar = lane & 15, kb = (lane>>4)*8;
    #pragma unroll
    for (int m=0;m<4;++m) af[m] = *(const half8*)&As[(wm*64 + m*16 + ar)*32 + kb];
    #pragma unroll
    for (int n=0;n<4;++n) bf[n] = *(const half8*)&Bs[(wn*64 + n*16 + ar)*32 + kb];
    #pragma unroll
    for (int m=0;m<4;++m)
      #pragma unroll
      for (int n=0;n<4;++n)
        acc[m][n] = __builtin_amdgcn_mfma_f32_16x16x32_f16(af[m], bf[n], acc[m][n], 0,0,0);
    __syncthreads();
  }
  const int r0 = bm*128 + wm*64 + ((lane>>4)<<2);
  const int c0 = bn*128 + wn*64 + (lane&15);
  #pragma unroll
  for (int m=0;m<4;++m)
    #pragma unroll
    for (int n=0;n<4;++n)
      #pragma unroll
      for (int e=0;e<4;++e)
        C[(size_t)(r0 + m*16 + e)*ldc + c0 + n*16] = acc[m][n][e];
}

// ---------------- layer-0 scan: f32, writes A1 hi/lo -----------------------
__global__ void scan0(const float* __restrict__ C0, const float* __restrict__ ep,
    const float* __restrict__ zb0, const float* __restrict__ fb0,
    const float* __restrict__ ob0, const float* __restrict__ ib0,
    _Float16* __restrict__ A1h, _Float16* __restrict__ A1l)
{
  int gid = blockIdx.x*256 + threadIdx.x;   // 16384
  int h = gid & 511, b = gid >> 9;
  float ez = ep[b*512 + h];
  float eo = ep[16384 + b*512 + h];
  float ei = ep[32768 + b*512 + h];
  float bz = zb0[h], bff = fb0[h], bo = ob0[h], bi = ib0[h];
  float c = 0.f;
  size_t base = (size_t)b*64*1024;
  A1h[base + h] = (_Float16)0.f;
  A1l[base + h] = (_Float16)0.f;
  for (int t=0;t<64;++t){
    size_t row = (size_t)b*64 + t;
    const float* g = C0 + row*2048;
    float z = tanhf(g[h]      + bz  + ez);
    float f = sigp (g[512+h]  + bff + ez);   // f0 uses epz0 (per reference)
    float o = sigp (g[1024+h] + bo  + eo);
    float i = sigp (g[1536+h] + bi  + ei);
    c = f*c + i*z;
    float h0 = o*c;
    _Float16 hi = (_Float16)h0;
    _Float16 lo = (_Float16)(h0 - (float)hi);
    A1h[row*1024 + 512 + h] = hi;
    A1l[row*1024 + 512 + h] = lo;
    if (t < 63){
      A1h[(row+1)*1024 + h] = hi;
      A1l[(row+1)*1024 + h] = lo;
    }
  }
}

// ---------------- layer-1 activations: F1, O1, PZ=(1-f1)*z1 ----------------
__global__ void act1(const float* __restrict__ C1, const float* __restrict__ ep,
    const float* __restrict__ zb1, const float* __restrict__ fb1,
    const float* __restrict__ ob1,
    float* __restrict__ F1, float* __restrict__ O1, float* __restrict__ PZ)
{
  int gid = blockIdx.x*256 + threadIdx.x;   // 2048*512
  int h = gid & 511; size_t row = gid >> 9; int b = (int)(row >> 6);
  const float* g = C1 + row*1536;
  float ez = ep[3*16384 + b*512 + h];
  float eo = ep[4*16384 + b*512 + h];
  float z1 = tanhf(g[h]      + zb1[h] + ez);
  float f1 = sigp (g[512+h]  + fb1[h] + ez);   // f1 uses epz1 (per reference)
  float o1 = sigp (g[1024+h] + ob1[h] + eo);
  F1[gid] = f1; O1[gid] = o1; PZ[gid] = (1.f - f1)*z1;
}

// ---------------- decode2: 32 blocks (1/b), 1024 threads, wave-specialized -
// waves 0-7: scores->softmax->kp/kv (tid<512 mappings identical to r11);
// waves 8-15: gv = cpWT GEMV (r11 P4a indexing, loop split 64+64 across
// two barrier intervals to overlap with scores and softmax).
__global__ __launch_bounds__(1024,4) void decode2(
  const _Float16* __restrict__ ench_g, const _Float16* __restrict__ encl_g,
  const float* __restrict__ F1, const float* __restrict__ O1,
  const float* __restrict__ PZ, const float* __restrict__ EP,
  const float* __restrict__ cpWT, const float* __restrict__ kpb,
  const float* __restrict__ cpb,
  float* __restrict__ att_probs, float* __restrict__ att_vec,
  _Float16* __restrict__ A2)
{
  __shared__ __align__(16) unsigned char encs[131072];
  __shared__ __align__(16) float kpq[4][512];       // kp partials (f32)
  __shared__ __align__(16) _Float16 kqh[4][512];    // kv partials (fp16, output-only)
  __shared__ __align__(16) float gvp[4][512];       // gv partials (f32)
  __shared__ __align__(16) float c1s[512];
  __shared__ float scores[128], alpha[128];
  // LDS: 131072+8192+4096+8192+2048+512+512 = 154624 <= 163840
  const int b = blockIdx.x, tid = threadIdx.x;
  const int w = tid >> 6, l = tid & 63;
  const _Float16* enchb = ench_g + (size_t)b*65536;
  const _Float16* enclb = encl_g + (size_t)b*65536;
  const float*    EPb   = EP     + (size_t)b*65536;

  // preload enc-hi into LDS, swizzled (16B chunks; swz flips bit4 -> 16B-safe)
  for (int idx = tid; idx < 8192; idx += 1024) {
    int s = idx >> 6, c = idx & 63;
    half8 v = *(const half8*)(enchb + (size_t)s*512 + c*8);
    int byte = (s*1024 + c*16) ^ ((s&7)<<4);
    *(half8*)(encs + byte) = v;
  }
  float h1 = 0.f;
  const float bsum = (tid < 512) ? (kpb[tid] + cpb[tid]) : 0.f;
  const int gvg = (tid >> 7) & 3, gvh = tid & 127;   // gv chunk/col (waves 8-15)
  const float* gwt = cpWT + (size_t)(gvg*128)*512 + gvh*4;
  __syncthreads();

  for (int t = 0; t < 64; ++t) {
    const size_t bt = (size_t)b*64 + t;
    // P1: c1n = f1*h1 + (1-f1)*z1   (h1 in register, thread tid<512 owns h=tid)
    if (tid < 512)
      c1s[tid] = F1[bt*512 + tid]*h1 + PZ[bt*512 + tid];
    __syncthreads();
    float ga0 = 0.f, ga1 = 0.f, ga2 = 0.f, ga3 = 0.f;  // gv accumulators
    // ---- interval A: scores (waves 0-7)  ||  gv first half (waves 8-15)
    if (tid < 512) {
      int s = tid >> 2, q = tid & 3;
      const _Float16* el = enclb + (size_t)s*512;
      float acc = 0.f;
      #pragma unroll
      for (int j = 0; j < 16; ++j) {
        int col = j*32 + q*8;
        int byte = (s*1024 + col*2) ^ ((s&7)<<4);
        half8 eh  = *(const half8*)(encs + byte);
        half8 elv = *(const half8*)(el + col);
        const float* cr = c1s + col;
        #pragma unroll
        for (int u = 0; u < 8; ++u)
          acc += ((float)eh[u] + (float)elv[u]) * cr[u];
      }
      acc += __shfl_xor(acc,1); acc += __shfl_xor(acc,2);
      if (q == 0) scores[s] = acc;
    } else {
      #pragma unroll 8
      for (int c = 0; c < 64; ++c) {
        float cv = c1s[gvg*128 + c];
        float4 wv = *(const float4*)(gwt + (size_t)c*512);
        ga0 += wv.x*cv; ga1 += wv.y*cv; ga2 += wv.z*cv; ga3 += wv.w*cv;
      }
    }
    __syncthreads();
    // ---- interval B: softmax (wave 0)  ||  gv second half (waves 8-15)
    if (tid < 64) {
      float s0 = scores[tid], s1 = scores[tid+64];
      float m = fmaxf(s0, s1);
      #pragma unroll
      for (int off=32; off; off>>=1) m = fmaxf(m, __shfl_xor(m, off));
      float e0 = expf(s0-m), e1 = expf(s1-m);
      float sm = e0+e1;
      #pragma unroll
      for (int off=32; off; off>>=1) sm += __shfl_xor(sm, off);
      float inv = 1.f/sm;
      float a0 = e0*inv, a1 = e1*inv;
      alpha[tid] = a0; alpha[tid+64] = a1;
      att_probs[bt*128 + tid] = a0; att_probs[bt*128 + 64 + tid] = a1;
    } else if (tid >= 512) {
      #pragma unroll 8
      for (int c = 64; c < 128; ++c) {
        float cv = c1s[gvg*128 + c];
        float4 wv = *(const float4*)(gwt + (size_t)c*512);
        ga0 += wv.x*cv; ga1 += wv.y*cv; ga2 += wv.z*cv; ga3 += wv.w*cv;
      }
      *(float4*)&gvp[gvg][gvh*4] = make_float4(ga0,ga1,ga2,ga3);
    }
    __syncthreads();
    // ---- interval C: kp (waves 0-3)  ||  kv (waves 4-7)
    if (w < 4) {
      const float* pr = EPb + (size_t)(w*32)*512 + l*8;
      float p0=0,p1=0,p2=0,p3=0,p4=0,p5=0,p6=0,p7=0;
      #pragma unroll
      for (int si = 0; si < 32; ++si) {
        float a = alpha[w*32 + si];
        float4 q0 = *(const float4*)(pr + (size_t)si*512);
        float4 q1 = *(const float4*)(pr + (size_t)si*512 + 4);
        p0 += a*q0.x; p1 += a*q0.y; p2 += a*q0.z; p3 += a*q0.w;
        p4 += a*q1.x; p5 += a*q1.y; p6 += a*q1.z; p7 += a*q1.w;
      }
      *(float4*)&kpq[w][l*8]   = make_float4(p0,p1,p2,p3);
      *(float4*)&kpq[w][l*8+4] = make_float4(p4,p5,p6,p7);
    } else if (w < 8) {
      int wv = w - 4;
      float k0=0,k1=0,k2=0,k3=0,k4=0,k5=0,k6=0,k7=0;
      #pragma unroll
      for (int si = 0; si < 32; ++si) {
        int s = wv*32 + si;
        int byte = (s*1024 + l*16) ^ ((s&7)<<4);
        half8 v = *(const half8*)(encs + byte);
        float a = alpha[s];
        k0 += a*(float)v[0]; k1 += a*(float)v[1];
        k2 += a*(float)v[2]; k3 += a*(float)v[3];
        k4 += a*(float)v[4]; k5 += a*(float)v[5];
        k6 += a*(float)v[6]; k7 += a*(float)v[7];
      }
      half8 st = {(_Float16)k0,(_Float16)k1,(_Float16)k2,(_Float16)k3,
                  (_Float16)k4,(_Float16)k5,(_Float16)k6,(_Float16)k7};
      *(half8*)&kqh[wv][l*8] = st;
    }
    __syncthreads();
    // P5: combine -> h1n (threads tid<512)
    if (tid < 512) {
      float kp = kpq[0][tid] + kpq[1][tid] + kpq[2][tid] + kpq[3][tid];
      float kv = (float)kqh[0][tid] + (float)kqh[1][tid]
               + (float)kqh[2][tid] + (float)kqh[3][tid];
      float gvv = gvp[0][tid] + gvp[1][tid] + gvp[2][tid] + gvp[3][tid];
      att_vec[bt*512 + tid] = kv;
      float h1n = (gvv + kp + bsum) * O1[bt*512 + tid];
      h1 = h1n;
      A2[bt*512 + tid] = (_Float16)h1n;
    }
    __syncthreads();
  }
}

// ---------------------------------------------------------------------------
extern "C" void kernel_launch(void* const* d_in, const int* in_sizes, int n_in,
                              void* d_out, int out_size, void* d_ws, size_t ws_size,
                              hipStream_t stream) {
  const float* trg  = (const float*)d_in[0];
  const float* enc  = (const float*)d_in[1];
  const float* ehid = (const float*)d_in[2];
  const float* zW0 = (const float*)d_in[5];  const float* zb0 = (const float*)d_in[6];
  const float* fW0 = (const float*)d_in[7];  const float* fb0 = (const float*)d_in[8];
  const float* oW0 = (const float*)d_in[9];  const float* ob0 = (const float*)d_in[10];
  const float* iW0 = (const float*)d_in[11]; const float* ib0 = (const float*)d_in[12];
  const float* epzW0 = (const float*)d_in[13]; const float* epzb0 = (const float*)d_in[14];
  const float* epoW0 = (const float*)d_in[15]; const float* epob0 = (const float*)d_in[16];
  const float* epiW0 = (const float*)d_in[17]; const float* epib0 = (const float*)d_in[18];
  const float* zW1 = (const float*)d_in[19]; const float* zb1 = (const float*)d_in[20];
  const float* fW1 = (const float*)d_in[21]; const float* fb1 = (const float*)d_in[22];
  const float* oW1 = (const float*)d_in[23]; const float* ob1 = (const float*)d_in[24];
  const float* epzW1 = (const float*)d_in[25]; const float* epzb1 = (const float*)d_in[26];
  const float* epoW1 = (const float*)d_in[27]; const float* epob1 = (const float*)d_in[28];
  const float* kpW = (const float*)d_in[29]; const float* kpb = (const float*)d_in[30];
  const float* cpW = (const float*)d_in[31]; const float* cpb = (const float*)d_in[32];
  const float* outW = (const float*)d_in[33];

  float* out = (float*)d_out;
  float* att_probs = out + (size_t)65536000;            // B*T*V
  float* att_vec   = att_probs + (size_t)262144;        // + B*T*S

  // SMALL (persists) in ws; BIG transients in ws if it fits, else inside
  // d_out's logits region (fully overwritten by the final GEMM).
  const size_t SMALL = 2097152 + 327680;
  const size_t BIG   = 92274688;
  char* pA2  = (char*)d_ws;
  char* pep  = pA2  + 2097152;
  char* big = (ws_size >= SMALL + BIG) ? pep + 327680 : (char*)d_out;
  char* p = big;
  _Float16* A0h  = (_Float16*)p; p += 4194304;
  _Float16* A0l  = (_Float16*)p; p += 4194304;
  _Float16* W0h  = (_Float16*)p; p += 4194304;
  _Float16* W0l  = (_Float16*)p; p += 4194304;
  _Float16* A1h  = (_Float16*)p; p += 4194304;
  _Float16* A1l  = (_Float16*)p; p += 4194304;
  _Float16* W1h  = (_Float16*)p; p += 3145728;
  _Float16* W1l  = (_Float16*)p; p += 3145728;
  _Float16* ench = (_Float16*)p; p += 4194304;
  _Float16* encl = (_Float16*)p; p += 4194304;
  _Float16* kph  = (_Float16*)p; p += 524288;
  _Float16* kpl  = (_Float16*)p; p += 524288;
  float*    C0   = (float*)p;    p += 16777216;
  float*    C1   = (float*)p;    p += 12582912;
  float*    F1   = (float*)p;    p += 4194304;
  float*    O1   = (float*)p;    p += 4194304;
  float*    PZ   = (float*)p;    p += 4194304;
  float*    EP   = (float*)p;    p += 8388608;
  float*    cpWT = (float*)p;    p += 1048576;
  _Float16* A2  = (_Float16*)pA2;
  float*    ep  = (float*)pep;

  hipLaunchKernelGGL(ep_proj, dim3(1280), dim3(256), 0, stream,
      ehid, epzW0,epzb0, epoW0,epob0, epiW0,epib0, epzW1,epzb1, epoW1,epob1, ep);
  hipLaunchKernelGGL(pack2, dim3(32768), dim3(256), 0, stream,
      trg, zW0,fW0,oW0,iW0, zW1,fW1,oW1, enc, kpW, cpW,
      A0h,A0l, W0h,W0l, W1h,W1l, ench,encl, kph,kpl, cpWT);
  hipLaunchKernelGGL(gemm3, dim3(16,16), dim3(256), 0, stream,
      A0h, A0l, W0h, W0l, C0, 1024, 2048);
  hipLaunchKernelGGL(scan0, dim3(64), dim3(256), 0, stream,
      C0, ep, zb0,fb0,ob0,ib0, A1h, A1l);
  hipLaunchKernelGGL(gemm3, dim3(16,12), dim3(256), 0, stream,
      A1h, A1l, W1h, W1l, C1, 1024, 1536);
  hipLaunchKernelGGL(act1, dim3(4096), dim3(256), 0, stream,
      C1, ep, zb1,fb1,ob1, F1, O1, PZ);
  hipLaunchKernelGGL(gemm3, dim3(32,4), dim3(256), 0, stream,
      ench, encl, kph, kpl, EP, 512, 512);
  hipLaunchKernelGGL(decode2, dim3(32), dim3(1024), 0, stream,
      ench, encl, F1, O1, PZ, EP, cpWT, kpb, cpb, att_probs, att_vec, A2);
  hipLaunchKernelGGL(gemm_hf, dim3(16,250), dim3(256), 0, stream,
      A2, outW, out, 512, 32000);
}

// Round 13
// 2796.595 us; speedup vs baseline: 1.0114x; 1.0114x over previous
//
#include <hip/hip_runtime.h>
#include <cmath>

// ---------------------------------------------------------------------------
// QRNN decoder, MI355X. B=32 T=64 S=128 EMB=H=E=512 V=32000 K=2.
// NUMERICS INVARIANT (r4/r6/r10/r11 pass vs r7/r8/r9 fail): anything feeding
// the c1/h1 recurrence (cpW GEMV, EP) must be f32-exact; fp16 only on
// output-side paths (att_vec, logits) or as hi/lo split pairs.
// PERF (r12 post-mortem): __launch_bounds__(1024,4) forced VGPR 128->64 ->
// scratch spills (FETCH 20.6->138MB, WRITE +5.7MB) -> 2390us. This round:
// identical kernel with __launch_bounds__(1024) (no min-waves) -> 128 VGPR
// cap from schedulability alone. Wave-specialized overlap unchanged:
// waves 8-15 run the cpWT GEMV concurrent with scores (waves 0-7) and
// softmax (wave 0), split 64+64 cols across two barrier intervals.
// ---------------------------------------------------------------------------

typedef _Float16 half8  __attribute__((ext_vector_type(8)));
typedef float    f32x4  __attribute__((ext_vector_type(4)));

#define DEVFN static __device__ __forceinline__

DEVFN float sigp(float x){ return 1.f/(1.f+expf(-x)); }

DEVFN void glds16(const _Float16* g, _Float16* l){
  __builtin_amdgcn_global_load_lds((const __attribute__((address_space(1))) void*)g,
                                   (__attribute__((address_space(3))) void*)l, 16, 0, 0);
}

// ---------------- encoder-hidden projections: 5 x (B,E)@(E,H), f32 ---------
__global__ void ep_proj(const float* __restrict__ ehid,
    const float* __restrict__ w0, const float* __restrict__ b0,
    const float* __restrict__ w1, const float* __restrict__ b1,
    const float* __restrict__ w2, const float* __restrict__ b2,
    const float* __restrict__ w3, const float* __restrict__ b3,
    const float* __restrict__ w4, const float* __restrict__ b4,
    float* __restrict__ ep)
{
  int gid = blockIdx.x*256 + threadIdx.x;            // 5*32*512*4 = 327680
  int q = gid & 3, h = (gid>>2)&511, b = (gid>>11)&31, p = gid>>16;
  const float* w    = (p==0)?w0:(p==1)?w1:(p==2)?w2:(p==3)?w3:w4;
  const float* bias = (p==0)?b0:(p==1)?b1:(p==2)?b2:(p==3)?b3:b4;
  const float* x  = ehid + ((p>=3)?32*512:0) + b*512 + q*128;
  const float* wr = w + (size_t)h*512 + q*128;
  float acc = 0.f;
  #pragma unroll 8
  for (int j=0;j<128;j+=4){
    float4 wv = *(const float4*)(wr+j);
    float4 xv = *(const float4*)(x+j);
    acc += wv.x*xv.x + wv.y*xv.y + wv.z*xv.z + wv.w*xv.w;
  }
  acc += __shfl_xor(acc,1); acc += __shfl_xor(acc,2);
  if (q==0) ep[p*16384 + b*512 + h] = acc + bias[h];
}

// ---------------- hi/lo fp16 packing + cpW transpose -----------------------
__global__ void pack2(const float* __restrict__ trg,
  const float* __restrict__ zW0, const float* __restrict__ fW0,
  const float* __restrict__ oW0, const float* __restrict__ iW0,
  const float* __restrict__ zW1, const float* __restrict__ fW1,
  const float* __restrict__ oW1,
  const float* __restrict__ enc, const float* __restrict__ kpW,
  const float* __restrict__ cpW,
  _Float16* __restrict__ A0h, _Float16* __restrict__ A0l,
  _Float16* __restrict__ W0h, _Float16* __restrict__ W0l,
  _Float16* __restrict__ W1h, _Float16* __restrict__ W1l,
  _Float16* __restrict__ ench, _Float16* __restrict__ encl,
  _Float16* __restrict__ kph, _Float16* __restrict__ kpl,
  float* __restrict__ cpWT)
{
  int gid = blockIdx.x*256 + threadIdx.x;            // 8,388,608 total
  float v; _Float16 *ph, *pl; int idx;
  if (gid < 2097152) {
    idx = gid;
    int m = idx >> 10, c = idx & 1023, t = m & 63, kk = c >> 9, i = c & 511;
    v = (kk==0) ? ((t>0) ? trg[(size_t)(m-1)*512 + i] : 0.f)
                : trg[(size_t)m*512 + i];
    ph = A0h; pl = A0l;
  } else if (gid < 4194304) {
    idx = gid - 2097152;
    int r = idx >> 10, c = idx & 1023, g = r >> 9, o = r & 511, kk = c >> 9, i = c & 511;
    const float* W = (g==0)?zW0:(g==1)?fW0:(g==2)?oW0:iW0;
    v = W[(size_t)o*1024 + i*2 + kk];
    ph = W0h; pl = W0l;
  } else if (gid < 5767168) {
    idx = gid - 4194304;
    int r = idx >> 10, c = idx & 1023, g = r >> 9, o = r & 511, kk = c >> 9, i = c & 511;
    const float* W = (g==0)?zW1:(g==1)?fW1:oW1;
    v = W[(size_t)o*1024 + i*2 + kk];
    ph = W1h; pl = W1l;
  } else if (gid < 7864320) {
    idx = gid - 5767168;
    v = enc[idx];
    ph = ench; pl = encl;
  } else if (gid < 8126464) {
    idx = gid - 7864320;
    v = kpW[idx];
    ph = kph; pl = kpl;
  } else {                                            // cpWT[c][h] = cpW[h][c]
    idx = gid - 8126464;                              // 262144
    int h = idx >> 9, c = idx & 511;
    cpWT[(size_t)c*512 + h] = cpW[(size_t)h*512 + c];
    return;
  }
  _Float16 hi = (_Float16)v;
  _Float16 lo = (_Float16)(v - (float)hi);
  ph[idx] = hi; pl[idx] = lo;
}

// ---------------- split-fp16 3-term MFMA GEMM ------------------------------
__global__ __launch_bounds__(256) void gemm3(
    const _Float16* __restrict__ Ah, const _Float16* __restrict__ Al,
    const _Float16* __restrict__ Bh, const _Float16* __restrict__ Bl,
    float* __restrict__ C, int Kd, int ldc)
{
  __shared__ __align__(16) _Float16 Ahs[4096];
  __shared__ __align__(16) _Float16 Als[4096];
  __shared__ __align__(16) _Float16 Bhs[4096];
  __shared__ __align__(16) _Float16 Bls[4096];
  const int tid = threadIdx.x, lane = tid & 63, wave = tid >> 6;
  const int bm = blockIdx.x, bn = blockIdx.y;
  const int wm = wave >> 1, wn = wave & 1;
  const size_t aoff = ((size_t)bm*128 + wave*16 + (lane>>2))*Kd + (lane&3)*8;
  const size_t boff = ((size_t)bn*128 + wave*16 + (lane>>2))*Kd + (lane&3)*8;
  const size_t hstep = (size_t)64*Kd;
  _Float16* Ahl = Ahs + wave*512;
  _Float16* All = Als + wave*512;
  _Float16* Bhl = Bhs + wave*512;
  _Float16* Bll = Bls + wave*512;
  f32x4 acc[4][4] = {};
  for (int k0 = 0; k0 < Kd; k0 += 32) {
    glds16(Ah + aoff + k0, Ahl);  glds16(Ah + aoff + hstep + k0, Ahl + 2048);
    glds16(Al + aoff + k0, All);  glds16(Al + aoff + hstep + k0, All + 2048);
    glds16(Bh + boff + k0, Bhl);  glds16(Bh + boff + hstep + k0, Bhl + 2048);
    glds16(Bl + boff + k0, Bll);  glds16(Bl + boff + hstep + k0, Bll + 2048);
    __syncthreads();
    const int ar = lane & 15, kb = (lane>>4)*8;
    half8 ah[4], al[4], bh[4], bl[4];
    #pragma unroll
    for (int m=0;m<4;++m){
      ah[m] = *(const half8*)&Ahs[(wm*64 + m*16 + ar)*32 + kb];
      al[m] = *(const half8*)&Als[(wm*64 + m*16 + ar)*32 + kb];
    }
    #pragma unroll
    for (int n=0;n<4;++n){
      bh[n] = *(const half8*)&Bhs[(wn*64 + n*16 + ar)*32 + kb];
      bl[n] = *(const half8*)&Bls[(wn*64 + n*16 + ar)*32 + kb];
    }
    #pragma unroll
    for (int m=0;m<4;++m)
      #pragma unroll
      for (int n=0;n<4;++n){
        acc[m][n] = __builtin_amdgcn_mfma_f32_16x16x32_f16(ah[m], bh[n], acc[m][n], 0,0,0);
        acc[m][n] = __builtin_amdgcn_mfma_f32_16x16x32_f16(ah[m], bl[n], acc[m][n], 0,0,0);
        acc[m][n] = __builtin_amdgcn_mfma_f32_16x16x32_f16(al[m], bh[n], acc[m][n], 0,0,0);
      }
    __syncthreads();
  }
  const int r0 = bm*128 + wm*64 + ((lane>>4)<<2);
  const int c0 = bn*128 + wn*64 + (lane&15);
  #pragma unroll
  for (int m=0;m<4;++m)
    #pragma unroll
    for (int n=0;n<4;++n)
      #pragma unroll
      for (int e=0;e<4;++e)
        C[(size_t)(r0 + m*16 + e)*ldc + c0 + n*16] = acc[m][n][e];
}

// ---------------- vocab GEMM: plain fp16 A x f32->fp16 B -------------------
__global__ __launch_bounds__(256) void gemm_hf(
    const _Float16* __restrict__ A, const float* __restrict__ Bf,
    float* __restrict__ C, int Kd, int ldc)
{
  __shared__ __align__(16) _Float16 As[128*32];
  __shared__ __align__(16) _Float16 Bs[128*32];
  const int tid = threadIdx.x, lane = tid & 63, wave = tid >> 6;
  const int bm = blockIdx.x, bn = blockIdx.y;
  const int wm = wave >> 1, wn = wave & 1;
  const _Float16* Ag = A + ((size_t)bm*128 + wave*16 + (lane>>2))*Kd + (lane&3)*8;
  _Float16* Al = As + wave*512;
  const float* Bg = Bf + ((size_t)bn*128 + (tid>>2))*Kd + (tid&3)*8;
  f32x4 acc[4][4] = {};
  for (int k0 = 0; k0 < Kd; k0 += 32) {
    glds16(Ag + k0, Al);
    glds16(Ag + (size_t)64*Kd + k0, Al + 2048);
    #pragma unroll
    for (int i=0;i<2;++i){
      const float* src = Bg + (size_t)i*64*Kd + k0;
      float4 f0 = *(const float4*)src;
      float4 f1 = *(const float4*)(src+4);
      half8 hv = {(_Float16)f0.x,(_Float16)f0.y,(_Float16)f0.z,(_Float16)f0.w,
                  (_Float16)f1.x,(_Float16)f1.y,(_Float16)f1.z,(_Float16)f1.w};
      *(half8*)&Bs[i*2048 + tid*8] = hv;
    }
    __syncthreads();
    half8 af[4], bf[4];
    const int ar = lane & 15, kb = (lane>>4)*8;
    #pragma unroll
    for (int m=0;m<4;++m) af[m] = *(const half8*)&As[(wm*64 + m*16 + ar)*32 + kb];
    #pragma unroll
    for (int n=0;n<4;++n) bf[n] = *(const half8*)&Bs[(wn*64 + n*16 + ar)*32 + kb];
    #pragma unroll
    for (int m=0;m<4;++m)
      #pragma unroll
      for (int n=0;n<4;++n)
        acc[m][n] = __builtin_amdgcn_mfma_f32_16x16x32_f16(af[m], bf[n], acc[m][n], 0,0,0);
    __syncthreads();
  }
  const int r0 = bm*128 + wm*64 + ((lane>>4)<<2);
  const int c0 = bn*128 + wn*64 + (lane&15);
  #pragma unroll
  for (int m=0;m<4;++m)
    #pragma unroll
    for (int n=0;n<4;++n)
      #pragma unroll
      for (int e=0;e<4;++e)
        C[(size_t)(r0 + m*16 + e)*ldc + c0 + n*16] = acc[m][n][e];
}

// ---------------- layer-0 scan: f32, writes A1 hi/lo -----------------------
__global__ void scan0(const float* __restrict__ C0, const float* __restrict__ ep,
    const float* __restrict__ zb0, const float* __restrict__ fb0,
    const float* __restrict__ ob0, const float* __restrict__ ib0,
    _Float16* __restrict__ A1h, _Float16* __restrict__ A1l)
{
  int gid = blockIdx.x*256 + threadIdx.x;   // 16384
  int h = gid & 511, b = gid >> 9;
  float ez = ep[b*512 + h];
  float eo = ep[16384 + b*512 + h];
  float ei = ep[32768 + b*512 + h];
  float bz = zb0[h], bff = fb0[h], bo = ob0[h], bi = ib0[h];
  float c = 0.f;
  size_t base = (size_t)b*64*1024;
  A1h[base + h] = (_Float16)0.f;
  A1l[base + h] = (_Float16)0.f;
  for (int t=0;t<64;++t){
    size_t row = (size_t)b*64 + t;
    const float* g = C0 + row*2048;
    float z = tanhf(g[h]      + bz  + ez);
    float f = sigp (g[512+h]  + bff + ez);   // f0 uses epz0 (per reference)
    float o = sigp (g[1024+h] + bo  + eo);
    float i = sigp (g[1536+h] + bi  + ei);
    c = f*c + i*z;
    float h0 = o*c;
    _Float16 hi = (_Float16)h0;
    _Float16 lo = (_Float16)(h0 - (float)hi);
    A1h[row*1024 + 512 + h] = hi;
    A1l[row*1024 + 512 + h] = lo;
    if (t < 63){
      A1h[(row+1)*1024 + h] = hi;
      A1l[(row+1)*1024 + h] = lo;
    }
  }
}

// ---------------- layer-1 activations: F1, O1, PZ=(1-f1)*z1 ----------------
__global__ void act1(const float* __restrict__ C1, const float* __restrict__ ep,
    const float* __restrict__ zb1, const float* __restrict__ fb1,
    const float* __restrict__ ob1,
    float* __restrict__ F1, float* __restrict__ O1, float* __restrict__ PZ)
{
  int gid = blockIdx.x*256 + threadIdx.x;   // 2048*512
  int h = gid & 511; size_t row = gid >> 9; int b = (int)(row >> 6);
  const float* g = C1 + row*1536;
  float ez = ep[3*16384 + b*512 + h];
  float eo = ep[4*16384 + b*512 + h];
  float z1 = tanhf(g[h]      + zb1[h] + ez);
  float f1 = sigp (g[512+h]  + fb1[h] + ez);   // f1 uses epz1 (per reference)
  float o1 = sigp (g[1024+h] + ob1[h] + eo);
  F1[gid] = f1; O1[gid] = o1; PZ[gid] = (1.f - f1)*z1;
}

// ---------------- decode2: 32 blocks (1/b), 1024 threads, wave-specialized -
// waves 0-7: scores->softmax->kp/kv (tid<512 mappings identical to r11);
// waves 8-15: gv = cpWT GEMV (r11 P4a indexing, loop split 64+64 across
// two barrier intervals). NOTE: no min-waves in launch_bounds — r12's
// (1024,4) forced VGPR to 64 and spilled to scratch (+118MB FETCH).
__global__ __launch_bounds__(1024) void decode2(
  const _Float16* __restrict__ ench_g, const _Float16* __restrict__ encl_g,
  const float* __restrict__ F1, const float* __restrict__ O1,
  const float* __restrict__ PZ, const float* __restrict__ EP,
  const float* __restrict__ cpWT, const float* __restrict__ kpb,
  const float* __restrict__ cpb,
  float* __restrict__ att_probs, float* __restrict__ att_vec,
  _Float16* __restrict__ A2)
{
  __shared__ __align__(16) unsigned char encs[131072];
  __shared__ __align__(16) float kpq[4][512];       // kp partials (f32)
  __shared__ __align__(16) _Float16 kqh[4][512];    // kv partials (fp16, output-only)
  __shared__ __align__(16) float gvp[4][512];       // gv partials (f32)
  __shared__ __align__(16) float c1s[512];
  __shared__ float scores[128], alpha[128];
  // LDS: 131072+8192+4096+8192+2048+512+512 = 154624 <= 163840
  const int b = blockIdx.x, tid = threadIdx.x;
  const int w = tid >> 6, l = tid & 63;
  const _Float16* enchb = ench_g + (size_t)b*65536;
  const _Float16* enclb = encl_g + (size_t)b*65536;
  const float*    EPb   = EP     + (size_t)b*65536;

  // preload enc-hi into LDS, swizzled (16B chunks; swz flips bit4 -> 16B-safe)
  for (int idx = tid; idx < 8192; idx += 1024) {
    int s = idx >> 6, c = idx & 63;
    half8 v = *(const half8*)(enchb + (size_t)s*512 + c*8);
    int byte = (s*1024 + c*16) ^ ((s&7)<<4);
    *(half8*)(encs + byte) = v;
  }
  float h1 = 0.f;
  const float bsum = (tid < 512) ? (kpb[tid] + cpb[tid]) : 0.f;
  const int gvg = (tid >> 7) & 3, gvh = tid & 127;   // gv chunk/col (waves 8-15)
  const float* gwt = cpWT + (size_t)(gvg*128)*512 + gvh*4;
  __syncthreads();

  for (int t = 0; t < 64; ++t) {
    const size_t bt = (size_t)b*64 + t;
    // P1: c1n = f1*h1 + (1-f1)*z1   (h1 in register, thread tid<512 owns h=tid)
    if (tid < 512)
      c1s[tid] = F1[bt*512 + tid]*h1 + PZ[bt*512 + tid];
    __syncthreads();
    float ga0 = 0.f, ga1 = 0.f, ga2 = 0.f, ga3 = 0.f;  // gv accumulators
    // ---- interval A: scores (waves 0-7)  ||  gv first half (waves 8-15)
    if (tid < 512) {
      int s = tid >> 2, q = tid & 3;
      const _Float16* el = enclb + (size_t)s*512;
      float acc = 0.f;
      #pragma unroll
      for (int j = 0; j < 16; ++j) {
        int col = j*32 + q*8;
        int byte = (s*1024 + col*2) ^ ((s&7)<<4);
        half8 eh  = *(const half8*)(encs + byte);
        half8 elv = *(const half8*)(el + col);
        const float* cr = c1s + col;
        #pragma unroll
        for (int u = 0; u < 8; ++u)
          acc += ((float)eh[u] + (float)elv[u]) * cr[u];
      }
      acc += __shfl_xor(acc,1); acc += __shfl_xor(acc,2);
      if (q == 0) scores[s] = acc;
    } else {
      #pragma unroll 8
      for (int c = 0; c < 64; ++c) {
        float cv = c1s[gvg*128 + c];
        float4 wv = *(const float4*)(gwt + (size_t)c*512);
        ga0 += wv.x*cv; ga1 += wv.y*cv; ga2 += wv.z*cv; ga3 += wv.w*cv;
      }
    }
    __syncthreads();
    // ---- interval B: softmax (wave 0)  ||  gv second half (waves 8-15)
    if (tid < 64) {
      float s0 = scores[tid], s1 = scores[tid+64];
      float m = fmaxf(s0, s1);
      #pragma unroll
      for (int off=32; off; off>>=1) m = fmaxf(m, __shfl_xor(m, off));
      float e0 = expf(s0-m), e1 = expf(s1-m);
      float sm = e0+e1;
      #pragma unroll
      for (int off=32; off; off>>=1) sm += __shfl_xor(sm, off);
      float inv = 1.f/sm;
      float a0 = e0*inv, a1 = e1*inv;
      alpha[tid] = a0; alpha[tid+64] = a1;
      att_probs[bt*128 + tid] = a0; att_probs[bt*128 + 64 + tid] = a1;
    } else if (tid >= 512) {
      #pragma unroll 8
      for (int c = 64; c < 128; ++c) {
        float cv = c1s[gvg*128 + c];
        float4 wv = *(const float4*)(gwt + (size_t)c*512);
        ga0 += wv.x*cv; ga1 += wv.y*cv; ga2 += wv.z*cv; ga3 += wv.w*cv;
      }
      *(float4*)&gvp[gvg][gvh*4] = make_float4(ga0,ga1,ga2,ga3);
    }
    __syncthreads();
    // ---- interval C: kp (waves 0-3)  ||  kv (waves 4-7)
    if (w < 4) {
      const float* pr = EPb + (size_t)(w*32)*512 + l*8;
      float p0=0,p1=0,p2=0,p3=0,p4=0,p5=0,p6=0,p7=0;
      #pragma unroll
      for (int si = 0; si < 32; ++si) {
        float a = alpha[w*32 + si];
        float4 q0 = *(const float4*)(pr + (size_t)si*512);
        float4 q1 = *(const float4*)(pr + (size_t)si*512 + 4);
        p0 += a*q0.x; p1 += a*q0.y; p2 += a*q0.z; p3 += a*q0.w;
        p4 += a*q1.x; p5 += a*q1.y; p6 += a*q1.z; p7 += a*q1.w;
      }
      *(float4*)&kpq[w][l*8]   = make_float4(p0,p1,p2,p3);
      *(float4*)&kpq[w][l*8+4] = make_float4(p4,p5,p6,p7);
    } else if (w < 8) {
      int wv = w - 4;
      float k0=0,k1=0,k2=0,k3=0,k4=0,k5=0,k6=0,k7=0;
      #pragma unroll
      for (int si = 0; si < 32; ++si) {
        int s = wv*32 + si;
        int byte = (s*1024 + l*16) ^ ((s&7)<<4);
        half8 v = *(const half8*)(encs + byte);
        float a = alpha[s];
        k0 += a*(float)v[0]; k1 += a*(float)v[1];
        k2 += a*(float)v[2]; k3 += a*(float)v[3];
        k4 += a*(float)v[4]; k5 += a*(float)v[5];
        k6 += a*(float)v[6]; k7 += a*(float)v[7];
      }
      half8 st = {(_Float16)k0,(_Float16)k1,(_Float16)k2,(_Float16)k3,
                  (_Float16)k4,(_Float16)k5,(_Float16)k6,(_Float16)k7};
      *(half8*)&kqh[wv][l*8] = st;
    }
    __syncthreads();
    // P5: combine -> h1n (threads tid<512)
    if (tid < 512) {
      float kp = kpq[0][tid] + kpq[1][tid] + kpq[2][tid] + kpq[3][tid];
      float kv = (float)kqh[0][tid] + (float)kqh[1][tid]
               + (float)kqh[2][tid] + (float)kqh[3][tid];
      float gvv = gvp[0][tid] + gvp[1][tid] + gvp[2][tid] + gvp[3][tid];
      att_vec[bt*512 + tid] = kv;
      float h1n = (gvv + kp + bsum) * O1[bt*512 + tid];
      h1 = h1n;
      A2[bt*512 + tid] = (_Float16)h1n;
    }
    __syncthreads();
  }
}

// ---------------------------------------------------------------------------
extern "C" void kernel_launch(void* const* d_in, const int* in_sizes, int n_in,
                              void* d_out, int out_size, void* d_ws, size_t ws_size,
                              hipStream_t stream) {
  const float* trg  = (const float*)d_in[0];
  const float* enc  = (const float*)d_in[1];
  const float* ehid = (const float*)d_in[2];
  const float* zW0 = (const float*)d_in[5];  const float* zb0 = (const float*)d_in[6];
  const float* fW0 = (const float*)d_in[7];  const float* fb0 = (const float*)d_in[8];
  const float* oW0 = (const float*)d_in[9];  const float* ob0 = (const float*)d_in[10];
  const float* iW0 = (const float*)d_in[11]; const float* ib0 = (const float*)d_in[12];
  const float* epzW0 = (const float*)d_in[13]; const float* epzb0 = (const float*)d_in[14];
  const float* epoW0 = (const float*)d_in[15]; const float* epob0 = (const float*)d_in[16];
  const float* epiW0 = (const float*)d_in[17]; const float* epib0 = (const float*)d_in[18];
  const float* zW1 = (const float*)d_in[19]; const float* zb1 = (const float*)d_in[20];
  const float* fW1 = (const float*)d_in[21]; const float* fb1 = (const float*)d_in[22];
  const float* oW1 = (const float*)d_in[23]; const float* ob1 = (const float*)d_in[24];
  const float* epzW1 = (const float*)d_in[25]; const float* epzb1 = (const float*)d_in[26];
  const float* epoW1 = (const float*)d_in[27]; const float* epob1 = (const float*)d_in[28];
  const float* kpW = (const float*)d_in[29]; const float* kpb = (const float*)d_in[30];
  const float* cpW = (const float*)d_in[31]; const float* cpb = (const float*)d_in[32];
  const float* outW = (const float*)d_in[33];

  float* out = (float*)d_out;
  float* att_probs = out + (size_t)65536000;            // B*T*V
  float* att_vec   = att_probs + (size_t)262144;        // + B*T*S

  // SMALL (persists) in ws; BIG transients in ws if it fits, else inside
  // d_out's logits region (fully overwritten by the final GEMM).
  const size_t SMALL = 2097152 + 327680;
  const size_t BIG   = 92274688;
  char* pA2  = (char*)d_ws;
  char* pep  = pA2  + 2097152;
  char* big = (ws_size >= SMALL + BIG) ? pep + 327680 : (char*)d_out;
  char* p = big;
  _Float16* A0h  = (_Float16*)p; p += 4194304;
  _Float16* A0l  = (_Float16*)p; p += 4194304;
  _Float16* W0h  = (_Float16*)p; p += 4194304;
  _Float16* W0l  = (_Float16*)p; p += 4194304;
  _Float16* A1h  = (_Float16*)p; p += 4194304;
  _Float16* A1l  = (_Float16*)p; p += 4194304;
  _Float16* W1h  = (_Float16*)p; p += 3145728;
  _Float16* W1l  = (_Float16*)p; p += 3145728;
  _Float16* ench = (_Float16*)p; p += 4194304;
  _Float16* encl = (_Float16*)p; p += 4194304;
  _Float16* kph  = (_Float16*)p; p += 524288;
  _Float16* kpl  = (_Float16*)p; p += 524288;
  float*    C0   = (float*)p;    p += 16777216;
  float*    C1   = (float*)p;    p += 12582912;
  float*    F1   = (float*)p;    p += 4194304;
  float*    O1   = (float*)p;    p += 4194304;
  float*    PZ   = (float*)p;    p += 4194304;
  float*    EP   = (float*)p;    p += 8388608;
  float*    cpWT = (float*)p;    p += 1048576;
  _Float16* A2  = (_Float16*)pA2;
  float*    ep  = (float*)pep;

  hipLaunchKernelGGL(ep_proj, dim3(1280), dim3(256), 0, stream,
      ehid, epzW0,epzb0, epoW0,epob0, epiW0,epib0, epzW1,epzb1, epoW1,epob1, ep);
  hipLaunchKernelGGL(pack2, dim3(32768), dim3(256), 0, stream,
      trg, zW0,fW0,oW0,iW0, zW1,fW1,oW1, enc, kpW, cpW,
      A0h,A0l, W0h,W0l, W1h,W1l, ench,encl, kph,kpl, cpWT);
  hipLaunchKernelGGL(gemm3, dim3(16,16), dim3(256), 0, stream,
      A0h, A0l, W0h, W0l, C0, 1024, 2048);
  hipLaunchKernelGGL(scan0, dim3(64), dim3(256), 0, stream,
      C0, ep, zb0,fb0,ob0,ib0, A1h, A1l);
  hipLaunchKernelGGL(gemm3, dim3(16,12), dim3(256), 0, stream,
      A1h, A1l, W1h, W1l, C1, 1024, 1536);
  hipLaunchKernelGGL(act1, dim3(4096), dim3(256), 0, stream,
      C1, ep, zb1,fb1,ob1, F1, O1, PZ);
  hipLaunchKernelGGL(gemm3, dim3(32,4), dim3(256), 0, stream,
      ench, encl, kph, kpl, EP, 512, 512);
  hipLaunchKernelGGL(decode2, dim3(32), dim3(1024), 0, stream,
      ench, encl, F1, O1, PZ, EP, cpWT, kpb, cpb, att_probs, att_vec, A2);
  hipLaunchKernelGGL(gemm_hf, dim3(16,250), dim3(256), 0, stream,
      A2, outW, out, 512, 32000);
}

// Round 14
// 1393.651 us; speedup vs baseline: 2.0296x; 2.0067x over previous
//
#include <hip/hip_runtime.h>
#include <cmath>

// ---------------------------------------------------------------------------
// QRNN decoder, MI355X. B=32 T=64 S=128 EMB=H=E=512 V=32000 K=2.
// NUMERICS INVARIANT (r4/r6/r10/r11 pass vs r7/r8/r9 fail): anything feeding
// the c1/h1 recurrence (cpW GEMV, EP) must be f32-exact; fp16 only on
// output-side paths (att_vec, logits) or as hi/lo split pairs.
// PERF (r12/r13 post-mortem): backend caps 1024-thread kernels at 64 VGPR by
// default -> spills (FETCH 21->139MB). Fix: amdgpu_waves_per_eu(4,4) to lift
// the cap to 128, plus unroll-4 on memory loops so even a 64-VGPR allocation
// fits spill-free (16 waves/CU needs only ~4 outstanding loads/wave).
// Wave-specialized overlap unchanged: waves 8-15 run the cpWT GEMV concurrent
// with scores (waves 0-7) and softmax (wave 0).
// ---------------------------------------------------------------------------

typedef _Float16 half8  __attribute__((ext_vector_type(8)));
typedef float    f32x4  __attribute__((ext_vector_type(4)));

#define DEVFN static __device__ __forceinline__

DEVFN float sigp(float x){ return 1.f/(1.f+expf(-x)); }

DEVFN void glds16(const _Float16* g, _Float16* l){
  __builtin_amdgcn_global_load_lds((const __attribute__((address_space(1))) void*)g,
                                   (__attribute__((address_space(3))) void*)l, 16, 0, 0);
}

// ---------------- encoder-hidden projections: 5 x (B,E)@(E,H), f32 ---------
__global__ void ep_proj(const float* __restrict__ ehid,
    const float* __restrict__ w0, const float* __restrict__ b0,
    const float* __restrict__ w1, const float* __restrict__ b1,
    const float* __restrict__ w2, const float* __restrict__ b2,
    const float* __restrict__ w3, const float* __restrict__ b3,
    const float* __restrict__ w4, const float* __restrict__ b4,
    float* __restrict__ ep)
{
  int gid = blockIdx.x*256 + threadIdx.x;            // 5*32*512*4 = 327680
  int q = gid & 3, h = (gid>>2)&511, b = (gid>>11)&31, p = gid>>16;
  const float* w    = (p==0)?w0:(p==1)?w1:(p==2)?w2:(p==3)?w3:w4;
  const float* bias = (p==0)?b0:(p==1)?b1:(p==2)?b2:(p==3)?b3:b4;
  const float* x  = ehid + ((p>=3)?32*512:0) + b*512 + q*128;
  const float* wr = w + (size_t)h*512 + q*128;
  float acc = 0.f;
  #pragma unroll 8
  for (int j=0;j<128;j+=4){
    float4 wv = *(const float4*)(wr+j);
    float4 xv = *(const float4*)(x+j);
    acc += wv.x*xv.x + wv.y*xv.y + wv.z*xv.z + wv.w*xv.w;
  }
  acc += __shfl_xor(acc,1); acc += __shfl_xor(acc,2);
  if (q==0) ep[p*16384 + b*512 + h] = acc + bias[h];
}

// ---------------- hi/lo fp16 packing + cpW transpose -----------------------
__global__ void pack2(const float* __restrict__ trg,
  const float* __restrict__ zW0, const float* __restrict__ fW0,
  const float* __restrict__ oW0, const float* __restrict__ iW0,
  const float* __restrict__ zW1, const float* __restrict__ fW1,
  const float* __restrict__ oW1,
  const float* __restrict__ enc, const float* __restrict__ kpW,
  const float* __restrict__ cpW,
  _Float16* __restrict__ A0h, _Float16* __restrict__ A0l,
  _Float16* __restrict__ W0h, _Float16* __restrict__ W0l,
  _Float16* __restrict__ W1h, _Float16* __restrict__ W1l,
  _Float16* __restrict__ ench, _Float16* __restrict__ encl,
  _Float16* __restrict__ kph, _Float16* __restrict__ kpl,
  float* __restrict__ cpWT)
{
  int gid = blockIdx.x*256 + threadIdx.x;            // 8,388,608 total
  float v; _Float16 *ph, *pl; int idx;
  if (gid < 2097152) {
    idx = gid;
    int m = idx >> 10, c = idx & 1023, t = m & 63, kk = c >> 9, i = c & 511;
    v = (kk==0) ? ((t>0) ? trg[(size_t)(m-1)*512 + i] : 0.f)
                : trg[(size_t)m*512 + i];
    ph = A0h; pl = A0l;
  } else if (gid < 4194304) {
    idx = gid - 2097152;
    int r = idx >> 10, c = idx & 1023, g = r >> 9, o = r & 511, kk = c >> 9, i = c & 511;
    const float* W = (g==0)?zW0:(g==1)?fW0:(g==2)?oW0:iW0;
    v = W[(size_t)o*1024 + i*2 + kk];
    ph = W0h; pl = W0l;
  } else if (gid < 5767168) {
    idx = gid - 4194304;
    int r = idx >> 10, c = idx & 1023, g = r >> 9, o = r & 511, kk = c >> 9, i = c & 511;
    const float* W = (g==0)?zW1:(g==1)?fW1:oW1;
    v = W[(size_t)o*1024 + i*2 + kk];
    ph = W1h; pl = W1l;
  } else if (gid < 7864320) {
    idx = gid - 5767168;
    v = enc[idx];
    ph = ench; pl = encl;
  } else if (gid < 8126464) {
    idx = gid - 7864320;
    v = kpW[idx];
    ph = kph; pl = kpl;
  } else {                                            // cpWT[c][h] = cpW[h][c]
    idx = gid - 8126464;                              // 262144
    int h = idx >> 9, c = idx & 511;
    cpWT[(size_t)c*512 + h] = cpW[(size_t)h*512 + c];
    return;
  }
  _Float16 hi = (_Float16)v;
  _Float16 lo = (_Float16)(v - (float)hi);
  ph[idx] = hi; pl[idx] = lo;
}

// ---------------- split-fp16 3-term MFMA GEMM ------------------------------
__global__ __launch_bounds__(256) void gemm3(
    const _Float16* __restrict__ Ah, const _Float16* __restrict__ Al,
    const _Float16* __restrict__ Bh, const _Float16* __restrict__ Bl,
    float* __restrict__ C, int Kd, int ldc)
{
  __shared__ __align__(16) _Float16 Ahs[4096];
  __shared__ __align__(16) _Float16 Als[4096];
  __shared__ __align__(16) _Float16 Bhs[4096];
  __shared__ __align__(16) _Float16 Bls[4096];
  const int tid = threadIdx.x, lane = tid & 63, wave = tid >> 6;
  const int bm = blockIdx.x, bn = blockIdx.y;
  const int wm = wave >> 1, wn = wave & 1;
  const size_t aoff = ((size_t)bm*128 + wave*16 + (lane>>2))*Kd + (lane&3)*8;
  const size_t boff = ((size_t)bn*128 + wave*16 + (lane>>2))*Kd + (lane&3)*8;
  const size_t hstep = (size_t)64*Kd;
  _Float16* Ahl = Ahs + wave*512;
  _Float16* All = Als + wave*512;
  _Float16* Bhl = Bhs + wave*512;
  _Float16* Bll = Bls + wave*512;
  f32x4 acc[4][4] = {};
  for (int k0 = 0; k0 < Kd; k0 += 32) {
    glds16(Ah + aoff + k0, Ahl);  glds16(Ah + aoff + hstep + k0, Ahl + 2048);
    glds16(Al + aoff + k0, All);  glds16(Al + aoff + hstep + k0, All + 2048);
    glds16(Bh + boff + k0, Bhl);  glds16(Bh + boff + hstep + k0, Bhl + 2048);
    glds16(Bl + boff + k0, Bll);  glds16(Bl + boff + hstep + k0, Bll + 2048);
    __syncthreads();
    const int ar = lane & 15, kb = (lane>>4)*8;
    half8 ah[4], al[4], bh[4], bl[4];
    #pragma unroll
    for (int m=0;m<4;++m){
      ah[m] = *(const half8*)&Ahs[(wm*64 + m*16 + ar)*32 + kb];
      al[m] = *(const half8*)&Als[(wm*64 + m*16 + ar)*32 + kb];
    }
    #pragma unroll
    for (int n=0;n<4;++n){
      bh[n] = *(const half8*)&Bhs[(wn*64 + n*16 + ar)*32 + kb];
      bl[n] = *(const half8*)&Bls[(wn*64 + n*16 + ar)*32 + kb];
    }
    #pragma unroll
    for (int m=0;m<4;++m)
      #pragma unroll
      for (int n=0;n<4;++n){
        acc[m][n] = __builtin_amdgcn_mfma_f32_16x16x32_f16(ah[m], bh[n], acc[m][n], 0,0,0);
        acc[m][n] = __builtin_amdgcn_mfma_f32_16x16x32_f16(ah[m], bl[n], acc[m][n], 0,0,0);
        acc[m][n] = __builtin_amdgcn_mfma_f32_16x16x32_f16(al[m], bh[n], acc[m][n], 0,0,0);
      }
    __syncthreads();
  }
  const int r0 = bm*128 + wm*64 + ((lane>>4)<<2);
  const int c0 = bn*128 + wn*64 + (lane&15);
  #pragma unroll
  for (int m=0;m<4;++m)
    #pragma unroll
    for (int n=0;n<4;++n)
      #pragma unroll
      for (int e=0;e<4;++e)
        C[(size_t)(r0 + m*16 + e)*ldc + c0 + n*16] = acc[m][n][e];
}

// ---------------- vocab GEMM: plain fp16 A x f32->fp16 B -------------------
__global__ __launch_bounds__(256) void gemm_hf(
    const _Float16* __restrict__ A, const float* __restrict__ Bf,
    float* __restrict__ C, int Kd, int ldc)
{
  __shared__ __align__(16) _Float16 As[128*32];
  __shared__ __align__(16) _Float16 Bs[128*32];
  const int tid = threadIdx.x, lane = tid & 63, wave = tid >> 6;
  const int bm = blockIdx.x, bn = blockIdx.y;
  const int wm = wave >> 1, wn = wave & 1;
  const _Float16* Ag = A + ((size_t)bm*128 + wave*16 + (lane>>2))*Kd + (lane&3)*8;
  _Float16* Al = As + wave*512;
  const float* Bg = Bf + ((size_t)bn*128 + (tid>>2))*Kd + (tid&3)*8;
  f32x4 acc[4][4] = {};
  for (int k0 = 0; k0 < Kd; k0 += 32) {
    glds16(Ag + k0, Al);
    glds16(Ag + (size_t)64*Kd + k0, Al + 2048);
    #pragma unroll
    for (int i=0;i<2;++i){
      const float* src = Bg + (size_t)i*64*Kd + k0;
      float4 f0 = *(const float4*)src;
      float4 f1 = *(const float4*)(src+4);
      half8 hv = {(_Float16)f0.x,(_Float16)f0.y,(_Float16)f0.z,(_Float16)f0.w,
                  (_Float16)f1.x,(_Float16)f1.y,(_Float16)f1.z,(_Float16)f1.w};
      *(half8*)&Bs[i*2048 + tid*8] = hv;
    }
    __syncthreads();
    half8 af[4], bf[4];
    const int ar = lane & 15, kb = (lane>>4)*8;
    #pragma unroll
    for (int m=0;m<4;++m) af[m] = *(const half8*)&As[(wm*64 + m*16 + ar)*32 + kb];
    #pragma unroll
    for (int n=0;n<4;++n) bf[n] = *(const half8*)&Bs[(wn*64 + n*16 + ar)*32 + kb];
    #pragma unroll
    for (int m=0;m<4;++m)
      #pragma unroll
      for (int n=0;n<4;++n)
        acc[m][n] = __builtin_amdgcn_mfma_f32_16x16x32_f16(af[m], bf[n], acc[m][n], 0,0,0);
    __syncthreads();
  }
  const int r0 = bm*128 + wm*64 + ((lane>>4)<<2);
  const int c0 = bn*128 + wn*64 + (lane&15);
  #pragma unroll
  for (int m=0;m<4;++m)
    #pragma unroll
    for (int n=0;n<4;++n)
      #pragma unroll
      for (int e=0;e<4;++e)
        C[(size_t)(r0 + m*16 + e)*ldc + c0 + n*16] = acc[m][n][e];
}

// ---------------- layer-0 scan: f32, writes A1 hi/lo -----------------------
__global__ void scan0(const float* __restrict__ C0, const float* __restrict__ ep,
    const float* __restrict__ zb0, const float* __restrict__ fb0,
    const float* __restrict__ ob0, const float* __restrict__ ib0,
    _Float16* __restrict__ A1h, _Float16* __restrict__ A1l)
{
  int gid = blockIdx.x*256 + threadIdx.x;   // 16384
  int h = gid & 511, b = gid >> 9;
  float ez = ep[b*512 + h];
  float eo = ep[16384 + b*512 + h];
  float ei = ep[32768 + b*512 + h];
  float bz = zb0[h], bff = fb0[h], bo = ob0[h], bi = ib0[h];
  float c = 0.f;
  size_t base = (size_t)b*64*1024;
  A1h[base + h] = (_Float16)0.f;
  A1l[base + h] = (_Float16)0.f;
  for (int t=0;t<64;++t){
    size_t row = (size_t)b*64 + t;
    const float* g = C0 + row*2048;
    float z = tanhf(g[h]      + bz  + ez);
    float f = sigp (g[512+h]  + bff + ez);   // f0 uses epz0 (per reference)
    float o = sigp (g[1024+h] + bo  + eo);
    float i = sigp (g[1536+h] + bi  + ei);
    c = f*c + i*z;
    float h0 = o*c;
    _Float16 hi = (_Float16)h0;
    _Float16 lo = (_Float16)(h0 - (float)hi);
    A1h[row*1024 + 512 + h] = hi;
    A1l[row*1024 + 512 + h] = lo;
    if (t < 63){
      A1h[(row+1)*1024 + h] = hi;
      A1l[(row+1)*1024 + h] = lo;
    }
  }
}

// ---------------- layer-1 activations: F1, O1, PZ=(1-f1)*z1 ----------------
__global__ void act1(const float* __restrict__ C1, const float* __restrict__ ep,
    const float* __restrict__ zb1, const float* __restrict__ fb1,
    const float* __restrict__ ob1,
    float* __restrict__ F1, float* __restrict__ O1, float* __restrict__ PZ)
{
  int gid = blockIdx.x*256 + threadIdx.x;   // 2048*512
  int h = gid & 511; size_t row = gid >> 9; int b = (int)(row >> 6);
  const float* g = C1 + row*1536;
  float ez = ep[3*16384 + b*512 + h];
  float eo = ep[4*16384 + b*512 + h];
  float z1 = tanhf(g[h]      + zb1[h] + ez);
  float f1 = sigp (g[512+h]  + fb1[h] + ez);   // f1 uses epz1 (per reference)
  float o1 = sigp (g[1024+h] + ob1[h] + eo);
  F1[gid] = f1; O1[gid] = o1; PZ[gid] = (1.f - f1)*z1;
}

// ---------------- decode2: 32 blocks (1/b), 1024 threads, wave-specialized -
// waves 0-7: scores->softmax->kp/kv; waves 8-15: gv = cpWT GEMV split 64+64
// across two barrier intervals. amdgpu_waves_per_eu(4,4) lifts the backend's
// 64-VGPR default for 1024-thread kernels to 128 (4 waves/SIMD x 128 = 512).
// Memory loops unroll-4 so even a 64-VGPR allocation stays spill-free.
__global__ __launch_bounds__(1024)
__attribute__((amdgpu_waves_per_eu(4, 4)))
void decode2(
  const _Float16* __restrict__ ench_g, const _Float16* __restrict__ encl_g,
  const float* __restrict__ F1, const float* __restrict__ O1,
  const float* __restrict__ PZ, const float* __restrict__ EP,
  const float* __restrict__ cpWT, const float* __restrict__ kpb,
  const float* __restrict__ cpb,
  float* __restrict__ att_probs, float* __restrict__ att_vec,
  _Float16* __restrict__ A2)
{
  __shared__ __align__(16) unsigned char encs[131072];
  __shared__ __align__(16) float kpq[4][512];       // kp partials (f32)
  __shared__ __align__(16) _Float16 kqh[4][512];    // kv partials (fp16, output-only)
  __shared__ __align__(16) float gvp[4][512];       // gv partials (f32)
  __shared__ __align__(16) float c1s[512];
  __shared__ float scores[128], alpha[128];
  // LDS: 131072+8192+4096+8192+2048+512+512 = 154624 <= 163840
  const int b = blockIdx.x, tid = threadIdx.x;
  const int w = tid >> 6, l = tid & 63;
  const _Float16* enchb = ench_g + (size_t)b*65536;
  const _Float16* enclb = encl_g + (size_t)b*65536;
  const float*    EPb   = EP     + (size_t)b*65536;

  // preload enc-hi into LDS, swizzled (16B chunks; swz flips bit4 -> 16B-safe)
  for (int idx = tid; idx < 8192; idx += 1024) {
    int s = idx >> 6, c = idx & 63;
    half8 v = *(const half8*)(enchb + (size_t)s*512 + c*8);
    int byte = (s*1024 + c*16) ^ ((s&7)<<4);
    *(half8*)(encs + byte) = v;
  }
  float h1 = 0.f;
  const float bsum = (tid < 512) ? (kpb[tid] + cpb[tid]) : 0.f;
  const int gvg = (tid >> 7) & 3, gvh = tid & 127;   // gv chunk/col (waves 8-15)
  const float* gwt = cpWT + (size_t)(gvg*128)*512 + gvh*4;
  __syncthreads();

  for (int t = 0; t < 64; ++t) {
    const size_t bt = (size_t)b*64 + t;
    // P1: c1n = f1*h1 + (1-f1)*z1   (h1 in register, thread tid<512 owns h=tid)
    if (tid < 512)
      c1s[tid] = F1[bt*512 + tid]*h1 + PZ[bt*512 + tid];
    __syncthreads();
    float ga0 = 0.f, ga1 = 0.f, ga2 = 0.f, ga3 = 0.f;  // gv accumulators
    // ---- interval A: scores (waves 0-7)  ||  gv first half (waves 8-15)
    if (tid < 512) {
      int s = tid >> 2, q = tid & 3;
      const _Float16* el = enclb + (size_t)s*512;
      float acc = 0.f;
      #pragma unroll 4
      for (int j = 0; j < 16; ++j) {
        int col = j*32 + q*8;
        int byte = (s*1024 + col*2) ^ ((s&7)<<4);
        half8 eh  = *(const half8*)(encs + byte);
        half8 elv = *(const half8*)(el + col);
        const float* cr = c1s + col;
        #pragma unroll
        for (int u = 0; u < 8; ++u)
          acc += ((float)eh[u] + (float)elv[u]) * cr[u];
      }
      acc += __shfl_xor(acc,1); acc += __shfl_xor(acc,2);
      if (q == 0) scores[s] = acc;
    } else {
      #pragma unroll 4
      for (int c = 0; c < 64; ++c) {
        float cv = c1s[gvg*128 + c];
        float4 wv = *(const float4*)(gwt + (size_t)c*512);
        ga0 += wv.x*cv; ga1 += wv.y*cv; ga2 += wv.z*cv; ga3 += wv.w*cv;
      }
    }
    __syncthreads();
    // ---- interval B: softmax (wave 0)  ||  gv second half (waves 8-15)
    if (tid < 64) {
      float s0 = scores[tid], s1 = scores[tid+64];
      float m = fmaxf(s0, s1);
      #pragma unroll
      for (int off=32; off; off>>=1) m = fmaxf(m, __shfl_xor(m, off));
      float e0 = expf(s0-m), e1 = expf(s1-m);
      float sm = e0+e1;
      #pragma unroll
      for (int off=32; off; off>>=1) sm += __shfl_xor(sm, off);
      float inv = 1.f/sm;
      float a0 = e0*inv, a1 = e1*inv;
      alpha[tid] = a0; alpha[tid+64] = a1;
      att_probs[bt*128 + tid] = a0; att_probs[bt*128 + 64 + tid] = a1;
    } else if (tid >= 512) {
      #pragma unroll 4
      for (int c = 64; c < 128; ++c) {
        float cv = c1s[gvg*128 + c];
        float4 wv = *(const float4*)(gwt + (size_t)c*512);
        ga0 += wv.x*cv; ga1 += wv.y*cv; ga2 += wv.z*cv; ga3 += wv.w*cv;
      }
      *(float4*)&gvp[gvg][gvh*4] = make_float4(ga0,ga1,ga2,ga3);
    }
    __syncthreads();
    // ---- interval C: kp (waves 0-3)  ||  kv (waves 4-7)
    if (w < 4) {
      const float* pr = EPb + (size_t)(w*32)*512 + l*8;
      float p0=0,p1=0,p2=0,p3=0,p4=0,p5=0,p6=0,p7=0;
      #pragma unroll 4
      for (int si = 0; si < 32; ++si) {
        float a = alpha[w*32 + si];
        float4 q0 = *(const float4*)(pr + (size_t)si*512);
        float4 q1 = *(const float4*)(pr + (size_t)si*512 + 4);
        p0 += a*q0.x; p1 += a*q0.y; p2 += a*q0.z; p3 += a*q0.w;
        p4 += a*q1.x; p5 += a*q1.y; p6 += a*q1.z; p7 += a*q1.w;
      }
      *(float4*)&kpq[w][l*8]   = make_float4(p0,p1,p2,p3);
      *(float4*)&kpq[w][l*8+4] = make_float4(p4,p5,p6,p7);
    } else if (w < 8) {
      int wv = w - 4;
      float k0=0,k1=0,k2=0,k3=0,k4=0,k5=0,k6=0,k7=0;
      #pragma unroll 4
      for (int si = 0; si < 32; ++si) {
        int s = wv*32 + si;
        int byte = (s*1024 + l*16) ^ ((s&7)<<4);
        half8 v = *(const half8*)(encs + byte);
        float a = alpha[s];
        k0 += a*(float)v[0]; k1 += a*(float)v[1];
        k2 += a*(float)v[2]; k3 += a*(float)v[3];
        k4 += a*(float)v[4]; k5 += a*(float)v[5];
        k6 += a*(float)v[6]; k7 += a*(float)v[7];
      }
      half8 st = {(_Float16)k0,(_Float16)k1,(_Float16)k2,(_Float16)k3,
                  (_Float16)k4,(_Float16)k5,(_Float16)k6,(_Float16)k7};
      *(half8*)&kqh[wv][l*8] = st;
    }
    __syncthreads();
    // P5: combine -> h1n (threads tid<512)
    if (tid < 512) {
      float kp = kpq[0][tid] + kpq[1][tid] + kpq[2][tid] + kpq[3][tid];
      float kv = (float)kqh[0][tid] + (float)kqh[1][tid]
               + (float)kqh[2][tid] + (float)kqh[3][tid];
      float gvv = gvp[0][tid] + gvp[1][tid] + gvp[2][tid] + gvp[3][tid];
      att_vec[bt*512 + tid] = kv;
      float h1n = (gvv + kp + bsum) * O1[bt*512 + tid];
      h1 = h1n;
      A2[bt*512 + tid] = (_Float16)h1n;
    }
    __syncthreads();
  }
}

// ---------------------------------------------------------------------------
extern "C" void kernel_launch(void* const* d_in, const int* in_sizes, int n_in,
                              void* d_out, int out_size, void* d_ws, size_t ws_size,
                              hipStream_t stream) {
  const float* trg  = (const float*)d_in[0];
  const float* enc  = (const float*)d_in[1];
  const float* ehid = (const float*)d_in[2];
  const float* zW0 = (const float*)d_in[5];  const float* zb0 = (const float*)d_in[6];
  const float* fW0 = (const float*)d_in[7];  const float* fb0 = (const float*)d_in[8];
  const float* oW0 = (const float*)d_in[9];  const float* ob0 = (const float*)d_in[10];
  const float* iW0 = (const float*)d_in[11]; const float* ib0 = (const float*)d_in[12];
  const float* epzW0 = (const float*)d_in[13]; const float* epzb0 = (const float*)d_in[14];
  const float* epoW0 = (const float*)d_in[15]; const float* epob0 = (const float*)d_in[16];
  const float* epiW0 = (const float*)d_in[17]; const float* epib0 = (const float*)d_in[18];
  const float* zW1 = (const float*)d_in[19]; const float* zb1 = (const float*)d_in[20];
  const float* fW1 = (const float*)d_in[21]; const float* fb1 = (const float*)d_in[22];
  const float* oW1 = (const float*)d_in[23]; const float* ob1 = (const float*)d_in[24];
  const float* epzW1 = (const float*)d_in[25]; const float* epzb1 = (const float*)d_in[26];
  const float* epoW1 = (const float*)d_in[27]; const float* epob1 = (const float*)d_in[28];
  const float* kpW = (const float*)d_in[29]; const float* kpb = (const float*)d_in[30];
  const float* cpW = (const float*)d_in[31]; const float* cpb = (const float*)d_in[32];
  const float* outW = (const float*)d_in[33];

  float* out = (float*)d_out;
  float* att_probs = out + (size_t)65536000;            // B*T*V
  float* att_vec   = att_probs + (size_t)262144;        // + B*T*S

  // SMALL (persists) in ws; BIG transients in ws if it fits, else inside
  // d_out's logits region (fully overwritten by the final GEMM).
  const size_t SMALL = 2097152 + 327680;
  const size_t BIG   = 92274688;
  char* pA2  = (char*)d_ws;
  char* pep  = pA2  + 2097152;
  char* big = (ws_size >= SMALL + BIG) ? pep + 327680 : (char*)d_out;
  char* p = big;
  _Float16* A0h  = (_Float16*)p; p += 4194304;
  _Float16* A0l  = (_Float16*)p; p += 4194304;
  _Float16* W0h  = (_Float16*)p; p += 4194304;
  _Float16* W0l  = (_Float16*)p; p += 4194304;
  _Float16* A1h  = (_Float16*)p; p += 4194304;
  _Float16* A1l  = (_Float16*)p; p += 4194304;
  _Float16* W1h  = (_Float16*)p; p += 3145728;
  _Float16* W1l  = (_Float16*)p; p += 3145728;
  _Float16* ench = (_Float16*)p; p += 4194304;
  _Float16* encl = (_Float16*)p; p += 4194304;
  _Float16* kph  = (_Float16*)p; p += 524288;
  _Float16* kpl  = (_Float16*)p; p += 524288;
  float*    C0   = (float*)p;    p += 16777216;
  float*    C1   = (float*)p;    p += 12582912;
  float*    F1   = (float*)p;    p += 4194304;
  float*    O1   = (float*)p;    p += 4194304;
  float*    PZ   = (float*)p;    p += 4194304;
  float*    EP   = (float*)p;    p += 8388608;
  float*    cpWT = (float*)p;    p += 1048576;
  _Float16* A2  = (_Float16*)pA2;
  float*    ep  = (float*)pep;

  hipLaunchKernelGGL(ep_proj, dim3(1280), dim3(256), 0, stream,
      ehid, epzW0,epzb0, epoW0,epob0, epiW0,epib0, epzW1,epzb1, epoW1,epob1, ep);
  hipLaunchKernelGGL(pack2, dim3(32768), dim3(256), 0, stream,
      trg, zW0,fW0,oW0,iW0, zW1,fW1,oW1, enc, kpW, cpW,
      A0h,A0l, W0h,W0l, W1h,W1l, ench,encl, kph,kpl, cpWT);
  hipLaunchKernelGGL(gemm3, dim3(16,16), dim3(256), 0, stream,
      A0h, A0l, W0h, W0l, C0, 1024, 2048);
  hipLaunchKernelGGL(scan0, dim3(64), dim3(256), 0, stream,
      C0, ep, zb0,fb0,ob0,ib0, A1h, A1l);
  hipLaunchKernelGGL(gemm3, dim3(16,12), dim3(256), 0, stream,
      A1h, A1l, W1h, W1l, C1, 1024, 1536);
  hipLaunchKernelGGL(act1, dim3(4096), dim3(256), 0, stream,
      C1, ep, zb1,fb1,ob1, F1, O1, PZ);
  hipLaunchKernelGGL(gemm3, dim3(32,4), dim3(256), 0, stream,
      ench, encl, kph, kpl, EP, 512, 512);
  hipLaunchKernelGGL(decode2, dim3(32), dim3(1024), 0, stream,
      ench, encl, F1, O1, PZ, EP, cpWT, kpb, cpb, att_probs, att_vec, A2);
  hipLaunchKernelGGL(gemm_hf, dim3(16,250), dim3(256), 0, stream,
      A2, outW, out, 512, 32000);
}

// Round 15
// 1350.962 us; speedup vs baseline: 2.0937x; 1.0316x over previous
//
#include <hip/hip_runtime.h>
#include <cmath>

// ---------------------------------------------------------------------------
// QRNN decoder, MI355X. B=32 T=64 S=128 EMB=H=E=512 V=32000 K=2.
// NUMERICS INVARIANT (r4/r6/r10/r11/r14 pass vs r7/r8/r9 fail): anything
// feeding the c1/h1 recurrence (cpW GEMV, EP) must be f32-exact; fp16 only on
// output-side paths (att_vec, logits) or as hi/lo split pairs.
// PERF (r14 post-mortem): spills fixed (unroll-4, VGPR 52); decode at 15.6
// us/step vs 9.3 TA floor. This round: 3 barriers/step (was 5), per-wave
// inline softmax (bit-identical shuffle reduce, alpha via __shfl broadcast,
// no alpha LDS), kp/kv overlapped with gv's second half, gv unroll 8.
// ---------------------------------------------------------------------------

typedef _Float16 half8  __attribute__((ext_vector_type(8)));
typedef float    f32x4  __attribute__((ext_vector_type(4)));

#define DEVFN static __device__ __forceinline__

DEVFN float sigp(float x){ return 1.f/(1.f+expf(-x)); }

DEVFN void glds16(const _Float16* g, _Float16* l){
  __builtin_amdgcn_global_load_lds((const __attribute__((address_space(1))) void*)g,
                                   (__attribute__((address_space(3))) void*)l, 16, 0, 0);
}

// ---------------- encoder-hidden projections: 5 x (B,E)@(E,H), f32 ---------
__global__ void ep_proj(const float* __restrict__ ehid,
    const float* __restrict__ w0, const float* __restrict__ b0,
    const float* __restrict__ w1, const float* __restrict__ b1,
    const float* __restrict__ w2, const float* __restrict__ b2,
    const float* __restrict__ w3, const float* __restrict__ b3,
    const float* __restrict__ w4, const float* __restrict__ b4,
    float* __restrict__ ep)
{
  int gid = blockIdx.x*256 + threadIdx.x;            // 5*32*512*4 = 327680
  int q = gid & 3, h = (gid>>2)&511, b = (gid>>11)&31, p = gid>>16;
  const float* w    = (p==0)?w0:(p==1)?w1:(p==2)?w2:(p==3)?w3:w4;
  const float* bias = (p==0)?b0:(p==1)?b1:(p==2)?b2:(p==3)?b3:b4;
  const float* x  = ehid + ((p>=3)?32*512:0) + b*512 + q*128;
  const float* wr = w + (size_t)h*512 + q*128;
  float acc = 0.f;
  #pragma unroll 8
  for (int j=0;j<128;j+=4){
    float4 wv = *(const float4*)(wr+j);
    float4 xv = *(const float4*)(x+j);
    acc += wv.x*xv.x + wv.y*xv.y + wv.z*xv.z + wv.w*xv.w;
  }
  acc += __shfl_xor(acc,1); acc += __shfl_xor(acc,2);
  if (q==0) ep[p*16384 + b*512 + h] = acc + bias[h];
}

// ---------------- hi/lo fp16 packing + cpW transpose -----------------------
__global__ void pack2(const float* __restrict__ trg,
  const float* __restrict__ zW0, const float* __restrict__ fW0,
  const float* __restrict__ oW0, const float* __restrict__ iW0,
  const float* __restrict__ zW1, const float* __restrict__ fW1,
  const float* __restrict__ oW1,
  const float* __restrict__ enc, const float* __restrict__ kpW,
  const float* __restrict__ cpW,
  _Float16* __restrict__ A0h, _Float16* __restrict__ A0l,
  _Float16* __restrict__ W0h, _Float16* __restrict__ W0l,
  _Float16* __restrict__ W1h, _Float16* __restrict__ W1l,
  _Float16* __restrict__ ench, _Float16* __restrict__ encl,
  _Float16* __restrict__ kph, _Float16* __restrict__ kpl,
  float* __restrict__ cpWT)
{
  int gid = blockIdx.x*256 + threadIdx.x;            // 8,388,608 total
  float v; _Float16 *ph, *pl; int idx;
  if (gid < 2097152) {
    idx = gid;
    int m = idx >> 10, c = idx & 1023, t = m & 63, kk = c >> 9, i = c & 511;
    v = (kk==0) ? ((t>0) ? trg[(size_t)(m-1)*512 + i] : 0.f)
                : trg[(size_t)m*512 + i];
    ph = A0h; pl = A0l;
  } else if (gid < 4194304) {
    idx = gid - 2097152;
    int r = idx >> 10, c = idx & 1023, g = r >> 9, o = r & 511, kk = c >> 9, i = c & 511;
    const float* W = (g==0)?zW0:(g==1)?fW0:(g==2)?oW0:iW0;
    v = W[(size_t)o*1024 + i*2 + kk];
    ph = W0h; pl = W0l;
  } else if (gid < 5767168) {
    idx = gid - 4194304;
    int r = idx >> 10, c = idx & 1023, g = r >> 9, o = r & 511, kk = c >> 9, i = c & 511;
    const float* W = (g==0)?zW1:(g==1)?fW1:oW1;
    v = W[(size_t)o*1024 + i*2 + kk];
    ph = W1h; pl = W1l;
  } else if (gid < 7864320) {
    idx = gid - 5767168;
    v = enc[idx];
    ph = ench; pl = encl;
  } else if (gid < 8126464) {
    idx = gid - 7864320;
    v = kpW[idx];
    ph = kph; pl = kpl;
  } else {                                            // cpWT[c][h] = cpW[h][c]
    idx = gid - 8126464;                              // 262144
    int h = idx >> 9, c = idx & 511;
    cpWT[(size_t)c*512 + h] = cpW[(size_t)h*512 + c];
    return;
  }
  _Float16 hi = (_Float16)v;
  _Float16 lo = (_Float16)(v - (float)hi);
  ph[idx] = hi; pl[idx] = lo;
}

// ---------------- split-fp16 3-term MFMA GEMM ------------------------------
__global__ __launch_bounds__(256) void gemm3(
    const _Float16* __restrict__ Ah, const _Float16* __restrict__ Al,
    const _Float16* __restrict__ Bh, const _Float16* __restrict__ Bl,
    float* __restrict__ C, int Kd, int ldc)
{
  __shared__ __align__(16) _Float16 Ahs[4096];
  __shared__ __align__(16) _Float16 Als[4096];
  __shared__ __align__(16) _Float16 Bhs[4096];
  __shared__ __align__(16) _Float16 Bls[4096];
  const int tid = threadIdx.x, lane = tid & 63, wave = tid >> 6;
  const int bm = blockIdx.x, bn = blockIdx.y;
  const int wm = wave >> 1, wn = wave & 1;
  const size_t aoff = ((size_t)bm*128 + wave*16 + (lane>>2))*Kd + (lane&3)*8;
  const size_t boff = ((size_t)bn*128 + wave*16 + (lane>>2))*Kd + (lane&3)*8;
  const size_t hstep = (size_t)64*Kd;
  _Float16* Ahl = Ahs + wave*512;
  _Float16* All = Als + wave*512;
  _Float16* Bhl = Bhs + wave*512;
  _Float16* Bll = Bls + wave*512;
  f32x4 acc[4][4] = {};
  for (int k0 = 0; k0 < Kd; k0 += 32) {
    glds16(Ah + aoff + k0, Ahl);  glds16(Ah + aoff + hstep + k0, Ahl + 2048);
    glds16(Al + aoff + k0, All);  glds16(Al + aoff + hstep + k0, All + 2048);
    glds16(Bh + boff + k0, Bhl);  glds16(Bh + boff + hstep + k0, Bhl + 2048);
    glds16(Bl + boff + k0, Bll);  glds16(Bl + boff + hstep + k0, Bll + 2048);
    __syncthreads();
    const int ar = lane & 15, kb = (lane>>4)*8;
    half8 ah[4], al[4], bh[4], bl[4];
    #pragma unroll
    for (int m=0;m<4;++m){
      ah[m] = *(const half8*)&Ahs[(wm*64 + m*16 + ar)*32 + kb];
      al[m] = *(const half8*)&Als[(wm*64 + m*16 + ar)*32 + kb];
    }
    #pragma unroll
    for (int n=0;n<4;++n){
      bh[n] = *(const half8*)&Bhs[(wn*64 + n*16 + ar)*32 + kb];
      bl[n] = *(const half8*)&Bls[(wn*64 + n*16 + ar)*32 + kb];
    }
    #pragma unroll
    for (int m=0;m<4;++m)
      #pragma unroll
      for (int n=0;n<4;++n){
        acc[m][n] = __builtin_amdgcn_mfma_f32_16x16x32_f16(ah[m], bh[n], acc[m][n], 0,0,0);
        acc[m][n] = __builtin_amdgcn_mfma_f32_16x16x32_f16(ah[m], bl[n], acc[m][n], 0,0,0);
        acc[m][n] = __builtin_amdgcn_mfma_f32_16x16x32_f16(al[m], bh[n], acc[m][n], 0,0,0);
      }
    __syncthreads();
  }
  const int r0 = bm*128 + wm*64 + ((lane>>4)<<2);
  const int c0 = bn*128 + wn*64 + (lane&15);
  #pragma unroll
  for (int m=0;m<4;++m)
    #pragma unroll
    for (int n=0;n<4;++n)
      #pragma unroll
      for (int e=0;e<4;++e)
        C[(size_t)(r0 + m*16 + e)*ldc + c0 + n*16] = acc[m][n][e];
}

// ---------------- vocab GEMM: plain fp16 A x f32->fp16 B -------------------
__global__ __launch_bounds__(256) void gemm_hf(
    const _Float16* __restrict__ A, const float* __restrict__ Bf,
    float* __restrict__ C, int Kd, int ldc)
{
  __shared__ __align__(16) _Float16 As[128*32];
  __shared__ __align__(16) _Float16 Bs[128*32];
  const int tid = threadIdx.x, lane = tid & 63, wave = tid >> 6;
  const int bm = blockIdx.x, bn = blockIdx.y;
  const int wm = wave >> 1, wn = wave & 1;
  const _Float16* Ag = A + ((size_t)bm*128 + wave*16 + (lane>>2))*Kd + (lane&3)*8;
  _Float16* Al = As + wave*512;
  const float* Bg = Bf + ((size_t)bn*128 + (tid>>2))*Kd + (tid&3)*8;
  f32x4 acc[4][4] = {};
  for (int k0 = 0; k0 < Kd; k0 += 32) {
    glds16(Ag + k0, Al);
    glds16(Ag + (size_t)64*Kd + k0, Al + 2048);
    #pragma unroll
    for (int i=0;i<2;++i){
      const float* src = Bg + (size_t)i*64*Kd + k0;
      float4 f0 = *(const float4*)src;
      float4 f1 = *(const float4*)(src+4);
      half8 hv = {(_Float16)f0.x,(_Float16)f0.y,(_Float16)f0.z,(_Float16)f0.w,
                  (_Float16)f1.x,(_Float16)f1.y,(_Float16)f1.z,(_Float16)f1.w};
      *(half8*)&Bs[i*2048 + tid*8] = hv;
    }
    __syncthreads();
    half8 af[4], bf[4];
    const int ar = lane & 15, kb = (lane>>4)*8;
    #pragma unroll
    for (int m=0;m<4;++m) af[m] = *(const half8*)&As[(wm*64 + m*16 + ar)*32 + kb];
    #pragma unroll
    for (int n=0;n<4;++n) bf[n] = *(const half8*)&Bs[(wn*64 + n*16 + ar)*32 + kb];
    #pragma unroll
    for (int m=0;m<4;++m)
      #pragma unroll
      for (int n=0;n<4;++n)
        acc[m][n] = __builtin_amdgcn_mfma_f32_16x16x32_f16(af[m], bf[n], acc[m][n], 0,0,0);
    __syncthreads();
  }
  const int r0 = bm*128 + wm*64 + ((lane>>4)<<2);
  const int c0 = bn*128 + wn*64 + (lane&15);
  #pragma unroll
  for (int m=0;m<4;++m)
    #pragma unroll
    for (int n=0;n<4;++n)
      #pragma unroll
      for (int e=0;e<4;++e)
        C[(size_t)(r0 + m*16 + e)*ldc + c0 + n*16] = acc[m][n][e];
}

// ---------------- layer-0 scan: f32, writes A1 hi/lo -----------------------
__global__ void scan0(const float* __restrict__ C0, const float* __restrict__ ep,
    const float* __restrict__ zb0, const float* __restrict__ fb0,
    const float* __restrict__ ob0, const float* __restrict__ ib0,
    _Float16* __restrict__ A1h, _Float16* __restrict__ A1l)
{
  int gid = blockIdx.x*256 + threadIdx.x;   // 16384
  int h = gid & 511, b = gid >> 9;
  float ez = ep[b*512 + h];
  float eo = ep[16384 + b*512 + h];
  float ei = ep[32768 + b*512 + h];
  float bz = zb0[h], bff = fb0[h], bo = ob0[h], bi = ib0[h];
  float c = 0.f;
  size_t base = (size_t)b*64*1024;
  A1h[base + h] = (_Float16)0.f;
  A1l[base + h] = (_Float16)0.f;
  for (int t=0;t<64;++t){
    size_t row = (size_t)b*64 + t;
    const float* g = C0 + row*2048;
    float z = tanhf(g[h]      + bz  + ez);
    float f = sigp (g[512+h]  + bff + ez);   // f0 uses epz0 (per reference)
    float o = sigp (g[1024+h] + bo  + eo);
    float i = sigp (g[1536+h] + bi  + ei);
    c = f*c + i*z;
    float h0 = o*c;
    _Float16 hi = (_Float16)h0;
    _Float16 lo = (_Float16)(h0 - (float)hi);
    A1h[row*1024 + 512 + h] = hi;
    A1l[row*1024 + 512 + h] = lo;
    if (t < 63){
      A1h[(row+1)*1024 + h] = hi;
      A1l[(row+1)*1024 + h] = lo;
    }
  }
}

// ---------------- layer-1 activations: F1, O1, PZ=(1-f1)*z1 ----------------
__global__ void act1(const float* __restrict__ C1, const float* __restrict__ ep,
    const float* __restrict__ zb1, const float* __restrict__ fb1,
    const float* __restrict__ ob1,
    float* __restrict__ F1, float* __restrict__ O1, float* __restrict__ PZ)
{
  int gid = blockIdx.x*256 + threadIdx.x;   // 2048*512
  int h = gid & 511; size_t row = gid >> 9; int b = (int)(row >> 6);
  const float* g = C1 + row*1536;
  float ez = ep[3*16384 + b*512 + h];
  float eo = ep[4*16384 + b*512 + h];
  float z1 = tanhf(g[h]      + zb1[h] + ez);
  float f1 = sigp (g[512+h]  + fb1[h] + ez);   // f1 uses epz1 (per reference)
  float o1 = sigp (g[1024+h] + ob1[h] + eo);
  F1[gid] = f1; O1[gid] = o1; PZ[gid] = (1.f - f1)*z1;
}

// ---------------- decode2: 32 blocks (1/b), 1024 threads, 3 barriers/step --
// body = [P1; bar; A: scores(0-7)||gv1(8-15); bar;
//         B: softmax+kp(0-3) || softmax+kv(4-7) || gv2(8-15); bar; P5]
// P5 -> next P1 is barrier-free (h1 in register; no buffer conflict).
// Softmax computed redundantly per wave with the identical shuffle-reduce
// sequence (bit-identical alpha); kp/kv get alpha via __shfl broadcast.
__global__ __launch_bounds__(1024)
__attribute__((amdgpu_waves_per_eu(4, 4)))
void decode2(
  const _Float16* __restrict__ ench_g, const _Float16* __restrict__ encl_g,
  const float* __restrict__ F1, const float* __restrict__ O1,
  const float* __restrict__ PZ, const float* __restrict__ EP,
  const float* __restrict__ cpWT, const float* __restrict__ kpb,
  const float* __restrict__ cpb,
  float* __restrict__ att_probs, float* __restrict__ att_vec,
  _Float16* __restrict__ A2)
{
  __shared__ __align__(16) unsigned char encs[131072];
  __shared__ __align__(16) float kpq[4][512];       // kp partials (f32)
  __shared__ __align__(16) _Float16 kqh[4][512];    // kv partials (fp16, output-only)
  __shared__ __align__(16) float gvp[4][512];       // gv partials (f32)
  __shared__ __align__(16) float c1s[512];
  __shared__ float scores[128];
  // LDS: 131072+8192+4096+8192+2048+512 = 154112 <= 163840
  const int b = blockIdx.x, tid = threadIdx.x;
  const int w = tid >> 6, l = tid & 63;
  const _Float16* enchb = ench_g + (size_t)b*65536;
  const _Float16* enclb = encl_g + (size_t)b*65536;
  const float*    EPb   = EP     + (size_t)b*65536;

  // preload enc-hi into LDS, swizzled (16B chunks; swz flips bit4 -> 16B-safe)
  for (int idx = tid; idx < 8192; idx += 1024) {
    int s = idx >> 6, c = idx & 63;
    half8 v = *(const half8*)(enchb + (size_t)s*512 + c*8);
    int byte = (s*1024 + c*16) ^ ((s&7)<<4);
    *(half8*)(encs + byte) = v;
  }
  float h1 = 0.f;
  const float bsum = (tid < 512) ? (kpb[tid] + cpb[tid]) : 0.f;
  const int gvg = (tid >> 7) & 3, gvh = tid & 127;   // gv chunk/col (waves 8-15)
  const float* gwt = cpWT + (size_t)(gvg*128)*512 + gvh*4;
  __syncthreads();

  for (int t = 0; t < 64; ++t) {
    const size_t bt = (size_t)b*64 + t;
    // P1: c1n = f1*h1 + (1-f1)*z1   (h1 in register, thread tid<512 owns h=tid)
    if (tid < 512)
      c1s[tid] = F1[bt*512 + tid]*h1 + PZ[bt*512 + tid];
    __syncthreads();
    float ga0 = 0.f, ga1 = 0.f, ga2 = 0.f, ga3 = 0.f;  // gv accumulators
    // ---- interval A: scores (waves 0-7)  ||  gv first half (waves 8-15)
    if (tid < 512) {
      int s = tid >> 2, q = tid & 3;
      const _Float16* el = enclb + (size_t)s*512;
      float acc = 0.f;
      #pragma unroll 4
      for (int j = 0; j < 16; ++j) {
        int col = j*32 + q*8;
        int byte = (s*1024 + col*2) ^ ((s&7)<<4);
        half8 eh  = *(const half8*)(encs + byte);
        half8 elv = *(const half8*)(el + col);
        const float* cr = c1s + col;
        #pragma unroll
        for (int u = 0; u < 8; ++u)
          acc += ((float)eh[u] + (float)elv[u]) * cr[u];
      }
      acc += __shfl_xor(acc,1); acc += __shfl_xor(acc,2);
      if (q == 0) scores[s] = acc;
    } else {
      #pragma unroll 8
      for (int c = 0; c < 64; ++c) {
        float cv = c1s[gvg*128 + c];
        float4 wv = *(const float4*)(gwt + (size_t)c*512);
        ga0 += wv.x*cv; ga1 += wv.y*cv; ga2 += wv.z*cv; ga3 += wv.w*cv;
      }
    }
    __syncthreads();
    // ---- interval B: per-wave softmax + kp (w 0-3) / kv (w 4-7) || gv2
    float a0 = 0.f, a1 = 0.f;
    if (w < 8) {   // inline softmax, identical reduce sequence per wave
      float s0 = scores[l], s1 = scores[l+64];
      float m = fmaxf(s0, s1);
      #pragma unroll
      for (int off=32; off; off>>=1) m = fmaxf(m, __shfl_xor(m, off));
      float e0 = expf(s0-m), e1 = expf(s1-m);
      float sm = e0+e1;
      #pragma unroll
      for (int off=32; off; off>>=1) sm += __shfl_xor(sm, off);
      float inv = 1.f/sm;
      a0 = e0*inv; a1 = e1*inv;
      if (w == 0) {
        att_probs[bt*128 + l]      = a0;
        att_probs[bt*128 + 64 + l] = a1;
      }
    }
    if (w < 4) {        // kp partials = alpha . EP (f32, coalesced)
      const float* pr = EPb + (size_t)(w*32)*512 + l*8;
      float p0=0,p1=0,p2=0,p3=0,p4=0,p5=0,p6=0,p7=0;
      #pragma unroll 4
      for (int si = 0; si < 32; ++si) {
        int s = w*32 + si;
        float a = (s < 64) ? __shfl(a0, s) : __shfl(a1, s - 64);
        float4 q0 = *(const float4*)(pr + (size_t)si*512);
        float4 q1 = *(const float4*)(pr + (size_t)si*512 + 4);
        p0 += a*q0.x; p1 += a*q0.y; p2 += a*q0.z; p3 += a*q0.w;
        p4 += a*q1.x; p5 += a*q1.y; p6 += a*q1.z; p7 += a*q1.w;
      }
      *(float4*)&kpq[w][l*8]   = make_float4(p0,p1,p2,p3);
      *(float4*)&kpq[w][l*8+4] = make_float4(p4,p5,p6,p7);
    } else if (w < 8) { // kv partials = alpha . enc_hi (LDS rows, fp16 out-only)
      int wv = w - 4;
      float k0=0,k1=0,k2=0,k3=0,k4=0,k5=0,k6=0,k7=0;
      #pragma unroll 4
      for (int si = 0; si < 32; ++si) {
        int s = wv*32 + si;
        float a = (s < 64) ? __shfl(a0, s) : __shfl(a1, s - 64);
        int byte = (s*1024 + l*16) ^ ((s&7)<<4);
        half8 v = *(const half8*)(encs + byte);
        k0 += a*(float)v[0]; k1 += a*(float)v[1];
        k2 += a*(float)v[2]; k3 += a*(float)v[3];
        k4 += a*(float)v[4]; k5 += a*(float)v[5];
        k6 += a*(float)v[6]; k7 += a*(float)v[7];
      }
      half8 st = {(_Float16)k0,(_Float16)k1,(_Float16)k2,(_Float16)k3,
                  (_Float16)k4,(_Float16)k5,(_Float16)k6,(_Float16)k7};
      *(half8*)&kqh[wv][l*8] = st;
    } else {            // gv second half
      #pragma unroll 8
      for (int c = 64; c < 128; ++c) {
        float cv = c1s[gvg*128 + c];
        float4 wv = *(const float4*)(gwt + (size_t)c*512);
        ga0 += wv.x*cv; ga1 += wv.y*cv; ga2 += wv.z*cv; ga3 += wv.w*cv;
      }
      *(float4*)&gvp[gvg][gvh*4] = make_float4(ga0,ga1,ga2,ga3);
    }
    __syncthreads();
    // P5: combine -> h1n (threads tid<512); no barrier before next P1
    if (tid < 512) {
      float kp = kpq[0][tid] + kpq[1][tid] + kpq[2][tid] + kpq[3][tid];
      float kv = (float)kqh[0][tid] + (float)kqh[1][tid]
               + (float)kqh[2][tid] + (float)kqh[3][tid];
      float gvv = gvp[0][tid] + gvp[1][tid] + gvp[2][tid] + gvp[3][tid];
      att_vec[bt*512 + tid] = kv;
      float h1n = (gvv + kp + bsum) * O1[bt*512 + tid];
      h1 = h1n;
      A2[bt*512 + tid] = (_Float16)h1n;
    }
  }
}

// ---------------------------------------------------------------------------
extern "C" void kernel_launch(void* const* d_in, const int* in_sizes, int n_in,
                              void* d_out, int out_size, void* d_ws, size_t ws_size,
                              hipStream_t stream) {
  const float* trg  = (const float*)d_in[0];
  const float* enc  = (const float*)d_in[1];
  const float* ehid = (const float*)d_in[2];
  const float* zW0 = (const float*)d_in[5];  const float* zb0 = (const float*)d_in[6];
  const float* fW0 = (const float*)d_in[7];  const float* fb0 = (const float*)d_in[8];
  const float* oW0 = (const float*)d_in[9];  const float* ob0 = (const float*)d_in[10];
  const float* iW0 = (const float*)d_in[11]; const float* ib0 = (const float*)d_in[12];
  const float* epzW0 = (const float*)d_in[13]; const float* epzb0 = (const float*)d_in[14];
  const float* epoW0 = (const float*)d_in[15]; const float* epob0 = (const float*)d_in[16];
  const float* epiW0 = (const float*)d_in[17]; const float* epib0 = (const float*)d_in[18];
  const float* zW1 = (const float*)d_in[19]; const float* zb1 = (const float*)d_in[20];
  const float* fW1 = (const float*)d_in[21]; const float* fb1 = (const float*)d_in[22];
  const float* oW1 = (const float*)d_in[23]; const float* ob1 = (const float*)d_in[24];
  const float* epzW1 = (const float*)d_in[25]; const float* epzb1 = (const float*)d_in[26];
  const float* epoW1 = (const float*)d_in[27]; const float* epob1 = (const float*)d_in[28];
  const float* kpW = (const float*)d_in[29]; const float* kpb = (const float*)d_in[30];
  const float* cpW = (const float*)d_in[31]; const float* cpb = (const float*)d_in[32];
  const float* outW = (const float*)d_in[33];

  float* out = (float*)d_out;
  float* att_probs = out + (size_t)65536000;            // B*T*V
  float* att_vec   = att_probs + (size_t)262144;        // + B*T*S

  // SMALL (persists) in ws; BIG transients in ws if it fits, else inside
  // d_out's logits region (fully overwritten by the final GEMM).
  const size_t SMALL = 2097152 + 327680;
  const size_t BIG   = 92274688;
  char* pA2  = (char*)d_ws;
  char* pep  = pA2  + 2097152;
  char* big = (ws_size >= SMALL + BIG) ? pep + 327680 : (char*)d_out;
  char* p = big;
  _Float16* A0h  = (_Float16*)p; p += 4194304;
  _Float16* A0l  = (_Float16*)p; p += 4194304;
  _Float16* W0h  = (_Float16*)p; p += 4194304;
  _Float16* W0l  = (_Float16*)p; p += 4194304;
  _Float16* A1h  = (_Float16*)p; p += 4194304;
  _Float16* A1l  = (_Float16*)p; p += 4194304;
  _Float16* W1h  = (_Float16*)p; p += 3145728;
  _Float16* W1l  = (_Float16*)p; p += 3145728;
  _Float16* ench = (_Float16*)p; p += 4194304;
  _Float16* encl = (_Float16*)p; p += 4194304;
  _Float16* kph  = (_Float16*)p; p += 524288;
  _Float16* kpl  = (_Float16*)p; p += 524288;
  float*    C0   = (float*)p;    p += 16777216;
  float*    C1   = (float*)p;    p += 12582912;
  float*    F1   = (float*)p;    p += 4194304;
  float*    O1   = (float*)p;    p += 4194304;
  float*    PZ   = (float*)p;    p += 4194304;
  float*    EP   = (float*)p;    p += 8388608;
  float*    cpWT = (float*)p;    p += 1048576;
  _Float16* A2  = (_Float16*)pA2;
  float*    ep  = (float*)pep;

  hipLaunchKernelGGL(ep_proj, dim3(1280), dim3(256), 0, stream,
      ehid, epzW0,epzb0, epoW0,epob0, epiW0,epib0, epzW1,epzb1, epoW1,epob1, ep);
  hipLaunchKernelGGL(pack2, dim3(32768), dim3(256), 0, stream,
      trg, zW0,fW0,oW0,iW0, zW1,fW1,oW1, enc, kpW, cpW,
      A0h,A0l, W0h,W0l, W1h,W1l, ench,encl, kph,kpl, cpWT);
  hipLaunchKernelGGL(gemm3, dim3(16,16), dim3(256), 0, stream,
      A0h, A0l, W0h, W0l, C0, 1024, 2048);
  hipLaunchKernelGGL(scan0, dim3(64), dim3(256), 0, stream,
      C0, ep, zb0,fb0,ob0,ib0, A1h, A1l);
  hipLaunchKernelGGL(gemm3, dim3(16,12), dim3(256), 0, stream,
      A1h, A1l, W1h, W1l, C1, 1024, 1536);
  hipLaunchKernelGGL(act1, dim3(4096), dim3(256), 0, stream,
      C1, ep, zb1,fb1,ob1, F1, O1, PZ);
  hipLaunchKernelGGL(gemm3, dim3(32,4), dim3(256), 0, stream,
      ench, encl, kph, kpl, EP, 512, 512);
  hipLaunchKernelGGL(decode2, dim3(32), dim3(1024), 0, stream,
      ench, encl, F1, O1, PZ, EP, cpWT, kpb, cpb, att_probs, att_vec, A2);
  hipLaunchKernelGGL(gemm_hf, dim3(16,250), dim3(256), 0, stream,
      A2, outW, out, 512, 32000);
}

// Round 16
// 1300.629 us; speedup vs baseline: 2.1747x; 1.0387x over previous
//
#include <hip/hip_runtime.h>
#include <cmath>

// ---------------------------------------------------------------------------
// QRNN decoder, MI355X. B=32 T=64 S=128 EMB=H=E=512 V=32000 K=2.
// NUMERICS INVARIANT (r4/r6/r10/r11/r14/r15 pass vs r7/r8/r9 fail): anything
// feeding the c1/h1 recurrence (cpW GEMV, EP) must be f32-exact; fp16 only on
// output-side paths (att_vec, logits) or as hi/lo split pairs.
// PERF (r15 post-mortem): decode 14.9us/step vs 9.2 TA-line floor (22K
// lines/step: gv 16K + kp 4K + scores 2K). This round: balance intervals
// (gv split 72/56 so A=2K+9.2K vs B=4K+7.2K lines) and deepen unrolls
// (kp/scores 8) to keep the TA saturated. All reductions bit-identical.
// ---------------------------------------------------------------------------

typedef _Float16 half8  __attribute__((ext_vector_type(8)));
typedef float    f32x4  __attribute__((ext_vector_type(4)));

#define DEVFN static __device__ __forceinline__

DEVFN float sigp(float x){ return 1.f/(1.f+expf(-x)); }

DEVFN void glds16(const _Float16* g, _Float16* l){
  __builtin_amdgcn_global_load_lds((const __attribute__((address_space(1))) void*)g,
                                   (__attribute__((address_space(3))) void*)l, 16, 0, 0);
}

// ---------------- encoder-hidden projections: 5 x (B,E)@(E,H), f32 ---------
__global__ void ep_proj(const float* __restrict__ ehid,
    const float* __restrict__ w0, const float* __restrict__ b0,
    const float* __restrict__ w1, const float* __restrict__ b1,
    const float* __restrict__ w2, const float* __restrict__ b2,
    const float* __restrict__ w3, const float* __restrict__ b3,
    const float* __restrict__ w4, const float* __restrict__ b4,
    float* __restrict__ ep)
{
  int gid = blockIdx.x*256 + threadIdx.x;            // 5*32*512*4 = 327680
  int q = gid & 3, h = (gid>>2)&511, b = (gid>>11)&31, p = gid>>16;
  const float* w    = (p==0)?w0:(p==1)?w1:(p==2)?w2:(p==3)?w3:w4;
  const float* bias = (p==0)?b0:(p==1)?b1:(p==2)?b2:(p==3)?b3:b4;
  const float* x  = ehid + ((p>=3)?32*512:0) + b*512 + q*128;
  const float* wr = w + (size_t)h*512 + q*128;
  float acc = 0.f;
  #pragma unroll 8
  for (int j=0;j<128;j+=4){
    float4 wv = *(const float4*)(wr+j);
    float4 xv = *(const float4*)(x+j);
    acc += wv.x*xv.x + wv.y*xv.y + wv.z*xv.z + wv.w*xv.w;
  }
  acc += __shfl_xor(acc,1); acc += __shfl_xor(acc,2);
  if (q==0) ep[p*16384 + b*512 + h] = acc + bias[h];
}

// ---------------- hi/lo fp16 packing + cpW transpose -----------------------
__global__ void pack2(const float* __restrict__ trg,
  const float* __restrict__ zW0, const float* __restrict__ fW0,
  const float* __restrict__ oW0, const float* __restrict__ iW0,
  const float* __restrict__ zW1, const float* __restrict__ fW1,
  const float* __restrict__ oW1,
  const float* __restrict__ enc, const float* __restrict__ kpW,
  const float* __restrict__ cpW,
  _Float16* __restrict__ A0h, _Float16* __restrict__ A0l,
  _Float16* __restrict__ W0h, _Float16* __restrict__ W0l,
  _Float16* __restrict__ W1h, _Float16* __restrict__ W1l,
  _Float16* __restrict__ ench, _Float16* __restrict__ encl,
  _Float16* __restrict__ kph, _Float16* __restrict__ kpl,
  float* __restrict__ cpWT)
{
  int gid = blockIdx.x*256 + threadIdx.x;            // 8,388,608 total
  float v; _Float16 *ph, *pl; int idx;
  if (gid < 2097152) {
    idx = gid;
    int m = idx >> 10, c = idx & 1023, t = m & 63, kk = c >> 9, i = c & 511;
    v = (kk==0) ? ((t>0) ? trg[(size_t)(m-1)*512 + i] : 0.f)
                : trg[(size_t)m*512 + i];
    ph = A0h; pl = A0l;
  } else if (gid < 4194304) {
    idx = gid - 2097152;
    int r = idx >> 10, c = idx & 1023, g = r >> 9, o = r & 511, kk = c >> 9, i = c & 511;
    const float* W = (g==0)?zW0:(g==1)?fW0:(g==2)?oW0:iW0;
    v = W[(size_t)o*1024 + i*2 + kk];
    ph = W0h; pl = W0l;
  } else if (gid < 5767168) {
    idx = gid - 4194304;
    int r = idx >> 10, c = idx & 1023, g = r >> 9, o = r & 511, kk = c >> 9, i = c & 511;
    const float* W = (g==0)?zW1:(g==1)?fW1:oW1;
    v = W[(size_t)o*1024 + i*2 + kk];
    ph = W1h; pl = W1l;
  } else if (gid < 7864320) {
    idx = gid - 5767168;
    v = enc[idx];
    ph = ench; pl = encl;
  } else if (gid < 8126464) {
    idx = gid - 7864320;
    v = kpW[idx];
    ph = kph; pl = kpl;
  } else {                                            // cpWT[c][h] = cpW[h][c]
    idx = gid - 8126464;                              // 262144
    int h = idx >> 9, c = idx & 511;
    cpWT[(size_t)c*512 + h] = cpW[(size_t)h*512 + c];
    return;
  }
  _Float16 hi = (_Float16)v;
  _Float16 lo = (_Float16)(v - (float)hi);
  ph[idx] = hi; pl[idx] = lo;
}

// ---------------- split-fp16 3-term MFMA GEMM ------------------------------
__global__ __launch_bounds__(256) void gemm3(
    const _Float16* __restrict__ Ah, const _Float16* __restrict__ Al,
    const _Float16* __restrict__ Bh, const _Float16* __restrict__ Bl,
    float* __restrict__ C, int Kd, int ldc)
{
  __shared__ __align__(16) _Float16 Ahs[4096];
  __shared__ __align__(16) _Float16 Als[4096];
  __shared__ __align__(16) _Float16 Bhs[4096];
  __shared__ __align__(16) _Float16 Bls[4096];
  const int tid = threadIdx.x, lane = tid & 63, wave = tid >> 6;
  const int bm = blockIdx.x, bn = blockIdx.y;
  const int wm = wave >> 1, wn = wave & 1;
  const size_t aoff = ((size_t)bm*128 + wave*16 + (lane>>2))*Kd + (lane&3)*8;
  const size_t boff = ((size_t)bn*128 + wave*16 + (lane>>2))*Kd + (lane&3)*8;
  const size_t hstep = (size_t)64*Kd;
  _Float16* Ahl = Ahs + wave*512;
  _Float16* All = Als + wave*512;
  _Float16* Bhl = Bhs + wave*512;
  _Float16* Bll = Bls + wave*512;
  f32x4 acc[4][4] = {};
  for (int k0 = 0; k0 < Kd; k0 += 32) {
    glds16(Ah + aoff + k0, Ahl);  glds16(Ah + aoff + hstep + k0, Ahl + 2048);
    glds16(Al + aoff + k0, All);  glds16(Al + aoff + hstep + k0, All + 2048);
    glds16(Bh + boff + k0, Bhl);  glds16(Bh + boff + hstep + k0, Bhl + 2048);
    glds16(Bl + boff + k0, Bll);  glds16(Bl + boff + hstep + k0, Bll + 2048);
    __syncthreads();
    const int ar = lane & 15, kb = (lane>>4)*8;
    half8 ah[4], al[4], bh[4], bl[4];
    #pragma unroll
    for (int m=0;m<4;++m){
      ah[m] = *(const half8*)&Ahs[(wm*64 + m*16 + ar)*32 + kb];
      al[m] = *(const half8*)&Als[(wm*64 + m*16 + ar)*32 + kb];
    }
    #pragma unroll
    for (int n=0;n<4;++n){
      bh[n] = *(const half8*)&Bhs[(wn*64 + n*16 + ar)*32 + kb];
      bl[n] = *(const half8*)&Bls[(wn*64 + n*16 + ar)*32 + kb];
    }
    #pragma unroll
    for (int m=0;m<4;++m)
      #pragma unroll
      for (int n=0;n<4;++n){
        acc[m][n] = __builtin_amdgcn_mfma_f32_16x16x32_f16(ah[m], bh[n], acc[m][n], 0,0,0);
        acc[m][n] = __builtin_amdgcn_mfma_f32_16x16x32_f16(ah[m], bl[n], acc[m][n], 0,0,0);
        acc[m][n] = __builtin_amdgcn_mfma_f32_16x16x32_f16(al[m], bh[n], acc[m][n], 0,0,0);
      }
    __syncthreads();
  }
  const int r0 = bm*128 + wm*64 + ((lane>>4)<<2);
  const int c0 = bn*128 + wn*64 + (lane&15);
  #pragma unroll
  for (int m=0;m<4;++m)
    #pragma unroll
    for (int n=0;n<4;++n)
      #pragma unroll
      for (int e=0;e<4;++e)
        C[(size_t)(r0 + m*16 + e)*ldc + c0 + n*16] = acc[m][n][e];
}

// ---------------- vocab GEMM: plain fp16 A x f32->fp16 B -------------------
__global__ __launch_bounds__(256) void gemm_hf(
    const _Float16* __restrict__ A, const float* __restrict__ Bf,
    float* __restrict__ C, int Kd, int ldc)
{
  __shared__ __align__(16) _Float16 As[128*32];
  __shared__ __align__(16) _Float16 Bs[128*32];
  const int tid = threadIdx.x, lane = tid & 63, wave = tid >> 6;
  const int bm = blockIdx.x, bn = blockIdx.y;
  const int wm = wave >> 1, wn = wave & 1;
  const _Float16* Ag = A + ((size_t)bm*128 + wave*16 + (lane>>2))*Kd + (lane&3)*8;
  _Float16* Al = As + wave*512;
  const float* Bg = Bf + ((size_t)bn*128 + (tid>>2))*Kd + (tid&3)*8;
  f32x4 acc[4][4] = {};
  for (int k0 = 0; k0 < Kd; k0 += 32) {
    glds16(Ag + k0, Al);
    glds16(Ag + (size_t)64*Kd + k0, Al + 2048);
    #pragma unroll
    for (int i=0;i<2;++i){
      const float* src = Bg + (size_t)i*64*Kd + k0;
      float4 f0 = *(const float4*)src;
      float4 f1 = *(const float4*)(src+4);
      half8 hv = {(_Float16)f0.x,(_Float16)f0.y,(_Float16)f0.z,(_Float16)f0.w,
                  (_Float16)f1.x,(_Float16)f1.y,(_Float16)f1.z,(_Float16)f1.w};
      *(half8*)&Bs[i*2048 + tid*8] = hv;
    }
    __syncthreads();
    half8 af[4], bf[4];
    const int ar = lane & 15, kb = (lane>>4)*8;
    #pragma unroll
    for (int m=0;m<4;++m) af[m] = *(const half8*)&As[(wm*64 + m*16 + ar)*32 + kb];
    #pragma unroll
    for (int n=0;n<4;++n) bf[n] = *(const half8*)&Bs[(wn*64 + n*16 + ar)*32 + kb];
    #pragma unroll
    for (int m=0;m<4;++m)
      #pragma unroll
      for (int n=0;n<4;++n)
        acc[m][n] = __builtin_amdgcn_mfma_f32_16x16x32_f16(af[m], bf[n], acc[m][n], 0,0,0);
    __syncthreads();
  }
  const int r0 = bm*128 + wm*64 + ((lane>>4)<<2);
  const int c0 = bn*128 + wn*64 + (lane&15);
  #pragma unroll
  for (int m=0;m<4;++m)
    #pragma unroll
    for (int n=0;n<4;++n)
      #pragma unroll
      for (int e=0;e<4;++e)
        C[(size_t)(r0 + m*16 + e)*ldc + c0 + n*16] = acc[m][n][e];
}

// ---------------- layer-0 scan: f32, writes A1 hi/lo -----------------------
__global__ void scan0(const float* __restrict__ C0, const float* __restrict__ ep,
    const float* __restrict__ zb0, const float* __restrict__ fb0,
    const float* __restrict__ ob0, const float* __restrict__ ib0,
    _Float16* __restrict__ A1h, _Float16* __restrict__ A1l)
{
  int gid = blockIdx.x*256 + threadIdx.x;   // 16384
  int h = gid & 511, b = gid >> 9;
  float ez = ep[b*512 + h];
  float eo = ep[16384 + b*512 + h];
  float ei = ep[32768 + b*512 + h];
  float bz = zb0[h], bff = fb0[h], bo = ob0[h], bi = ib0[h];
  float c = 0.f;
  size_t base = (size_t)b*64*1024;
  A1h[base + h] = (_Float16)0.f;
  A1l[base + h] = (_Float16)0.f;
  for (int t=0;t<64;++t){
    size_t row = (size_t)b*64 + t;
    const float* g = C0 + row*2048;
    float z = tanhf(g[h]      + bz  + ez);
    float f = sigp (g[512+h]  + bff + ez);   // f0 uses epz0 (per reference)
    float o = sigp (g[1024+h] + bo  + eo);
    float i = sigp (g[1536+h] + bi  + ei);
    c = f*c + i*z;
    float h0 = o*c;
    _Float16 hi = (_Float16)h0;
    _Float16 lo = (_Float16)(h0 - (float)hi);
    A1h[row*1024 + 512 + h] = hi;
    A1l[row*1024 + 512 + h] = lo;
    if (t < 63){
      A1h[(row+1)*1024 + h] = hi;
      A1l[(row+1)*1024 + h] = lo;
    }
  }
}

// ---------------- layer-1 activations: F1, O1, PZ=(1-f1)*z1 ----------------
__global__ void act1(const float* __restrict__ C1, const float* __restrict__ ep,
    const float* __restrict__ zb1, const float* __restrict__ fb1,
    const float* __restrict__ ob1,
    float* __restrict__ F1, float* __restrict__ O1, float* __restrict__ PZ)
{
  int gid = blockIdx.x*256 + threadIdx.x;   // 2048*512
  int h = gid & 511; size_t row = gid >> 9; int b = (int)(row >> 6);
  const float* g = C1 + row*1536;
  float ez = ep[3*16384 + b*512 + h];
  float eo = ep[4*16384 + b*512 + h];
  float z1 = tanhf(g[h]      + zb1[h] + ez);
  float f1 = sigp (g[512+h]  + fb1[h] + ez);   // f1 uses epz1 (per reference)
  float o1 = sigp (g[1024+h] + ob1[h] + eo);
  F1[gid] = f1; O1[gid] = o1; PZ[gid] = (1.f - f1)*z1;
}

// ---------------- decode2: 32 blocks (1/b), 1024 threads, 3 barriers/step --
// body = [P1; bar; A: scores(0-7)||gv c0..71(8-15); bar;
//         B: softmax+kp(0-3) || softmax+kv(4-7) || gv c72..127(8-15); bar; P5]
// gv split 72/56 balances TA lines per interval (A: 2K+9.2K, B: 4K+7.2K).
// Per-thread gv order unchanged (c ascending) -> bit-identical sums.
__global__ __launch_bounds__(1024)
__attribute__((amdgpu_waves_per_eu(4, 4)))
void decode2(
  const _Float16* __restrict__ ench_g, const _Float16* __restrict__ encl_g,
  const float* __restrict__ F1, const float* __restrict__ O1,
  const float* __restrict__ PZ, const float* __restrict__ EP,
  const float* __restrict__ cpWT, const float* __restrict__ kpb,
  const float* __restrict__ cpb,
  float* __restrict__ att_probs, float* __restrict__ att_vec,
  _Float16* __restrict__ A2)
{
  __shared__ __align__(16) unsigned char encs[131072];
  __shared__ __align__(16) float kpq[4][512];       // kp partials (f32)
  __shared__ __align__(16) _Float16 kqh[4][512];    // kv partials (fp16, output-only)
  __shared__ __align__(16) float gvp[4][512];       // gv partials (f32)
  __shared__ __align__(16) float c1s[512];
  __shared__ float scores[128];
  // LDS: 131072+8192+4096+8192+2048+512 = 154112 <= 163840
  const int b = blockIdx.x, tid = threadIdx.x;
  const int w = tid >> 6, l = tid & 63;
  const _Float16* enchb = ench_g + (size_t)b*65536;
  const _Float16* enclb = encl_g + (size_t)b*65536;
  const float*    EPb   = EP     + (size_t)b*65536;

  // preload enc-hi into LDS, swizzled (16B chunks; swz flips bit4 -> 16B-safe)
  for (int idx = tid; idx < 8192; idx += 1024) {
    int s = idx >> 6, c = idx & 63;
    half8 v = *(const half8*)(enchb + (size_t)s*512 + c*8);
    int byte = (s*1024 + c*16) ^ ((s&7)<<4);
    *(half8*)(encs + byte) = v;
  }
  float h1 = 0.f;
  const float bsum = (tid < 512) ? (kpb[tid] + cpb[tid]) : 0.f;
  const int gvg = (tid >> 7) & 3, gvh = tid & 127;   // gv chunk/col (waves 8-15)
  const float* gwt = cpWT + (size_t)(gvg*128)*512 + gvh*4;
  __syncthreads();

  for (int t = 0; t < 64; ++t) {
    const size_t bt = (size_t)b*64 + t;
    // P1: c1n = f1*h1 + (1-f1)*z1   (h1 in register, thread tid<512 owns h=tid)
    if (tid < 512)
      c1s[tid] = F1[bt*512 + tid]*h1 + PZ[bt*512 + tid];
    __syncthreads();
    float ga0 = 0.f, ga1 = 0.f, ga2 = 0.f, ga3 = 0.f;  // gv accumulators
    // ---- interval A: scores (waves 0-7)  ||  gv c = 0..71 (waves 8-15)
    if (tid < 512) {
      int s = tid >> 2, q = tid & 3;
      const _Float16* el = enclb + (size_t)s*512;
      float acc = 0.f;
      #pragma unroll 8
      for (int j = 0; j < 16; ++j) {
        int col = j*32 + q*8;
        int byte = (s*1024 + col*2) ^ ((s&7)<<4);
        half8 eh  = *(const half8*)(encs + byte);
        half8 elv = *(const half8*)(el + col);
        const float* cr = c1s + col;
        #pragma unroll
        for (int u = 0; u < 8; ++u)
          acc += ((float)eh[u] + (float)elv[u]) * cr[u];
      }
      acc += __shfl_xor(acc,1); acc += __shfl_xor(acc,2);
      if (q == 0) scores[s] = acc;
    } else {
      #pragma unroll 8
      for (int c = 0; c < 72; ++c) {
        float cv = c1s[gvg*128 + c];
        float4 wv = *(const float4*)(gwt + (size_t)c*512);
        ga0 += wv.x*cv; ga1 += wv.y*cv; ga2 += wv.z*cv; ga3 += wv.w*cv;
      }
    }
    __syncthreads();
    // ---- interval B: per-wave softmax + kp (w 0-3) / kv (w 4-7) || gv tail
    float a0 = 0.f, a1 = 0.f;
    if (w < 8) {   // inline softmax, identical reduce sequence per wave
      float s0 = scores[l], s1 = scores[l+64];
      float m = fmaxf(s0, s1);
      #pragma unroll
      for (int off=32; off; off>>=1) m = fmaxf(m, __shfl_xor(m, off));
      float e0 = expf(s0-m), e1 = expf(s1-m);
      float sm = e0+e1;
      #pragma unroll
      for (int off=32; off; off>>=1) sm += __shfl_xor(sm, off);
      float inv = 1.f/sm;
      a0 = e0*inv; a1 = e1*inv;
      if (w == 0) {
        att_probs[bt*128 + l]      = a0;
        att_probs[bt*128 + 64 + l] = a1;
      }
    }
    if (w < 4) {        // kp partials = alpha . EP (f32, coalesced)
      const float* pr = EPb + (size_t)(w*32)*512 + l*8;
      float p0=0,p1=0,p2=0,p3=0,p4=0,p5=0,p6=0,p7=0;
      #pragma unroll 8
      for (int si = 0; si < 32; ++si) {
        int s = w*32 + si;
        float a = (s < 64) ? __shfl(a0, s) : __shfl(a1, s - 64);
        float4 q0 = *(const float4*)(pr + (size_t)si*512);
        float4 q1 = *(const float4*)(pr + (size_t)si*512 + 4);
        p0 += a*q0.x; p1 += a*q0.y; p2 += a*q0.z; p3 += a*q0.w;
        p4 += a*q1.x; p5 += a*q1.y; p6 += a*q1.z; p7 += a*q1.w;
      }
      *(float4*)&kpq[w][l*8]   = make_float4(p0,p1,p2,p3);
      *(float4*)&kpq[w][l*8+4] = make_float4(p4,p5,p6,p7);
    } else if (w < 8) { // kv partials = alpha . enc_hi (LDS rows, fp16 out-only)
      int wv = w - 4;
      float k0=0,k1=0,k2=0,k3=0,k4=0,k5=0,k6=0,k7=0;
      #pragma unroll 4
      for (int si = 0; si < 32; ++si) {
        int s = wv*32 + si;
        float a = (s < 64) ? __shfl(a0, s) : __shfl(a1, s - 64);
        int byte = (s*1024 + l*16) ^ ((s&7)<<4);
        half8 v = *(const half8*)(encs + byte);
        k0 += a*(float)v[0]; k1 += a*(float)v[1];
        k2 += a*(float)v[2]; k3 += a*(float)v[3];
        k4 += a*(float)v[4]; k5 += a*(float)v[5];
        k6 += a*(float)v[6]; k7 += a*(float)v[7];
      }
      half8 st = {(_Float16)k0,(_Float16)k1,(_Float16)k2,(_Float16)k3,
                  (_Float16)k4,(_Float16)k5,(_Float16)k6,(_Float16)k7};
      *(half8*)&kqh[wv][l*8] = st;
    } else {            // gv tail c = 72..127
      #pragma unroll 8
      for (int c = 72; c < 128; ++c) {
        float cv = c1s[gvg*128 + c];
        float4 wv = *(const float4*)(gwt + (size_t)c*512);
        ga0 += wv.x*cv; ga1 += wv.y*cv; ga2 += wv.z*cv; ga3 += wv.w*cv;
      }
      *(float4*)&gvp[gvg][gvh*4] = make_float4(ga0,ga1,ga2,ga3);
    }
    __syncthreads();
    // P5: combine -> h1n (threads tid<512); no barrier before next P1
    if (tid < 512) {
      float kp = kpq[0][tid] + kpq[1][tid] + kpq[2][tid] + kpq[3][tid];
      float kv = (float)kqh[0][tid] + (float)kqh[1][tid]
               + (float)kqh[2][tid] + (float)kqh[3][tid];
      float gvv = gvp[0][tid] + gvp[1][tid] + gvp[2][tid] + gvp[3][tid];
      att_vec[bt*512 + tid] = kv;
      float h1n = (gvv + kp + bsum) * O1[bt*512 + tid];
      h1 = h1n;
      A2[bt*512 + tid] = (_Float16)h1n;
    }
  }
}

// ---------------------------------------------------------------------------
extern "C" void kernel_launch(void* const* d_in, const int* in_sizes, int n_in,
                              void* d_out, int out_size, void* d_ws, size_t ws_size,
                              hipStream_t stream) {
  const float* trg  = (const float*)d_in[0];
  const float* enc  = (const float*)d_in[1];
  const float* ehid = (const float*)d_in[2];
  const float* zW0 = (const float*)d_in[5];  const float* zb0 = (const float*)d_in[6];
  const float* fW0 = (const float*)d_in[7];  const float* fb0 = (const float*)d_in[8];
  const float* oW0 = (const float*)d_in[9];  const float* ob0 = (const float*)d_in[10];
  const float* iW0 = (const float*)d_in[11]; const float* ib0 = (const float*)d_in[12];
  const float* epzW0 = (const float*)d_in[13]; const float* epzb0 = (const float*)d_in[14];
  const float* epoW0 = (const float*)d_in[15]; const float* epob0 = (const float*)d_in[16];
  const float* epiW0 = (const float*)d_in[17]; const float* epib0 = (const float*)d_in[18];
  const float* zW1 = (const float*)d_in[19]; const float* zb1 = (const float*)d_in[20];
  const float* fW1 = (const float*)d_in[21]; const float* fb1 = (const float*)d_in[22];
  const float* oW1 = (const float*)d_in[23]; const float* ob1 = (const float*)d_in[24];
  const float* epzW1 = (const float*)d_in[25]; const float* epzb1 = (const float*)d_in[26];
  const float* epoW1 = (const float*)d_in[27]; const float* epob1 = (const float*)d_in[28];
  const float* kpW = (const float*)d_in[29]; const float* kpb = (const float*)d_in[30];
  const float* cpW = (const float*)d_in[31]; const float* cpb = (const float*)d_in[32];
  const float* outW = (const float*)d_in[33];

  float* out = (float*)d_out;
  float* att_probs = out + (size_t)65536000;            // B*T*V
  float* att_vec   = att_probs + (size_t)262144;        // + B*T*S

  // SMALL (persists) in ws; BIG transients in ws if it fits, else inside
  // d_out's logits region (fully overwritten by the final GEMM).
  const size_t SMALL = 2097152 + 327680;
  const size_t BIG   = 92274688;
  char* pA2  = (char*)d_ws;
  char* pep  = pA2  + 2097152;
  char* big = (ws_size >= SMALL + BIG) ? pep + 327680 : (char*)d_out;
  char* p = big;
  _Float16* A0h  = (_Float16*)p; p += 4194304;
  _Float16* A0l  = (_Float16*)p; p += 4194304;
  _Float16* W0h  = (_Float16*)p; p += 4194304;
  _Float16* W0l  = (_Float16*)p; p += 4194304;
  _Float16* A1h  = (_Float16*)p; p += 4194304;
  _Float16* A1l  = (_Float16*)p; p += 4194304;
  _Float16* W1h  = (_Float16*)p; p += 3145728;
  _Float16* W1l  = (_Float16*)p; p += 3145728;
  _Float16* ench = (_Float16*)p; p += 4194304;
  _Float16* encl = (_Float16*)p; p += 4194304;
  _Float16* kph  = (_Float16*)p; p += 524288;
  _Float16* kpl  = (_Float16*)p; p += 524288;
  float*    C0   = (float*)p;    p += 16777216;
  float*    C1   = (float*)p;    p += 12582912;
  float*    F1   = (float*)p;    p += 4194304;
  float*    O1   = (float*)p;    p += 4194304;
  float*    PZ   = (float*)p;    p += 4194304;
  float*    EP   = (float*)p;    p += 8388608;
  float*    cpWT = (float*)p;    p += 1048576;
  _Float16* A2  = (_Float16*)pA2;
  float*    ep  = (float*)pep;

  hipLaunchKernelGGL(ep_proj, dim3(1280), dim3(256), 0, stream,
      ehid, epzW0,epzb0, epoW0,epob0, epiW0,epib0, epzW1,epzb1, epoW1,epob1, ep);
  hipLaunchKernelGGL(pack2, dim3(32768), dim3(256), 0, stream,
      trg, zW0,fW0,oW0,iW0, zW1,fW1,oW1, enc, kpW, cpW,
      A0h,A0l, W0h,W0l, W1h,W1l, ench,encl, kph,kpl, cpWT);
  hipLaunchKernelGGL(gemm3, dim3(16,16), dim3(256), 0, stream,
      A0h, A0l, W0h, W0l, C0, 1024, 2048);
  hipLaunchKernelGGL(scan0, dim3(64), dim3(256), 0, stream,
      C0, ep, zb0,fb0,ob0,ib0, A1h, A1l);
  hipLaunchKernelGGL(gemm3, dim3(16,12), dim3(256), 0, stream,
      A1h, A1l, W1h, W1l, C1, 1024, 1536);
  hipLaunchKernelGGL(act1, dim3(4096), dim3(256), 0, stream,
      C1, ep, zb1,fb1,ob1, F1, O1, PZ);
  hipLaunchKernelGGL(gemm3, dim3(32,4), dim3(256), 0, stream,
      ench, encl, kph, kpl, EP, 512, 512);
  hipLaunchKernelGGL(decode2, dim3(32), dim3(1024), 0, stream,
      ench, encl, F1, O1, PZ, EP, cpWT, kpb, cpb, att_probs, att_vec, A2);
  hipLaunchKernelGGL(gemm_hf, dim3(16,250), dim3(256), 0, stream,
      A2, outW, out, 512, 32000);
}

// Round 17
// 1277.826 us; speedup vs baseline: 2.2135x; 1.0178x over previous
//
#include <hip/hip_runtime.h>
#include <cmath>

// ---------------------------------------------------------------------------
// QRNN decoder, MI355X. B=32 T=64 S=128 EMB=H=E=512 V=32000 K=2.
// NUMERICS INVARIANT (r4..r16): anything feeding the c1/h1 recurrence
// (cpW GEMV, EP) must be f32-exact; fp16 only on output-side paths
// (att_vec, logits) or as hi/lo split pairs.
// PERF: decode2 frozen at r16 (907us, ~70% TA util). This round attacks the
// tail: vocab GEMM's in-kernel f32->fp16 B-convert (VALU-bound staging)
// replaced by a one-time outW cast + two-operand fp16 gemm_hh (glds16 both
// operands). Bit-identical logits (same cast, hoisted). Legacy path kept for
// small-ws configs.
// ---------------------------------------------------------------------------

typedef _Float16 half8  __attribute__((ext_vector_type(8)));
typedef float    f32x4  __attribute__((ext_vector_type(4)));

#define DEVFN static __device__ __forceinline__

DEVFN float sigp(float x){ return 1.f/(1.f+expf(-x)); }

DEVFN void glds16(const _Float16* g, _Float16* l){
  __builtin_amdgcn_global_load_lds((const __attribute__((address_space(1))) void*)g,
                                   (__attribute__((address_space(3))) void*)l, 16, 0, 0);
}

// ---------------- encoder-hidden projections: 5 x (B,E)@(E,H), f32 ---------
__global__ void ep_proj(const float* __restrict__ ehid,
    const float* __restrict__ w0, const float* __restrict__ b0,
    const float* __restrict__ w1, const float* __restrict__ b1,
    const float* __restrict__ w2, const float* __restrict__ b2,
    const float* __restrict__ w3, const float* __restrict__ b3,
    const float* __restrict__ w4, const float* __restrict__ b4,
    float* __restrict__ ep)
{
  int gid = blockIdx.x*256 + threadIdx.x;            // 5*32*512*4 = 327680
  int q = gid & 3, h = (gid>>2)&511, b = (gid>>11)&31, p = gid>>16;
  const float* w    = (p==0)?w0:(p==1)?w1:(p==2)?w2:(p==3)?w3:w4;
  const float* bias = (p==0)?b0:(p==1)?b1:(p==2)?b2:(p==3)?b3:b4;
  const float* x  = ehid + ((p>=3)?32*512:0) + b*512 + q*128;
  const float* wr = w + (size_t)h*512 + q*128;
  float acc = 0.f;
  #pragma unroll 8
  for (int j=0;j<128;j+=4){
    float4 wv = *(const float4*)(wr+j);
    float4 xv = *(const float4*)(x+j);
    acc += wv.x*xv.x + wv.y*xv.y + wv.z*xv.z + wv.w*xv.w;
  }
  acc += __shfl_xor(acc,1); acc += __shfl_xor(acc,2);
  if (q==0) ep[p*16384 + b*512 + h] = acc + bias[h];
}

// ---------------- hi/lo fp16 packing + cpW transpose -----------------------
__global__ void pack2(const float* __restrict__ trg,
  const float* __restrict__ zW0, const float* __restrict__ fW0,
  const float* __restrict__ oW0, const float* __restrict__ iW0,
  const float* __restrict__ zW1, const float* __restrict__ fW1,
  const float* __restrict__ oW1,
  const float* __restrict__ enc, const float* __restrict__ kpW,
  const float* __restrict__ cpW,
  _Float16* __restrict__ A0h, _Float16* __restrict__ A0l,
  _Float16* __restrict__ W0h, _Float16* __restrict__ W0l,
  _Float16* __restrict__ W1h, _Float16* __restrict__ W1l,
  _Float16* __restrict__ ench, _Float16* __restrict__ encl,
  _Float16* __restrict__ kph, _Float16* __restrict__ kpl,
  float* __restrict__ cpWT)
{
  int gid = blockIdx.x*256 + threadIdx.x;            // 8,388,608 total
  float v; _Float16 *ph, *pl; int idx;
  if (gid < 2097152) {
    idx = gid;
    int m = idx >> 10, c = idx & 1023, t = m & 63, kk = c >> 9, i = c & 511;
    v = (kk==0) ? ((t>0) ? trg[(size_t)(m-1)*512 + i] : 0.f)
                : trg[(size_t)m*512 + i];
    ph = A0h; pl = A0l;
  } else if (gid < 4194304) {
    idx = gid - 2097152;
    int r = idx >> 10, c = idx & 1023, g = r >> 9, o = r & 511, kk = c >> 9, i = c & 511;
    const float* W = (g==0)?zW0:(g==1)?fW0:(g==2)?oW0:iW0;
    v = W[(size_t)o*1024 + i*2 + kk];
    ph = W0h; pl = W0l;
  } else if (gid < 5767168) {
    idx = gid - 4194304;
    int r = idx >> 10, c = idx & 1023, g = r >> 9, o = r & 511, kk = c >> 9, i = c & 511;
    const float* W = (g==0)?zW1:(g==1)?fW1:oW1;
    v = W[(size_t)o*1024 + i*2 + kk];
    ph = W1h; pl = W1l;
  } else if (gid < 7864320) {
    idx = gid - 5767168;
    v = enc[idx];
    ph = ench; pl = encl;
  } else if (gid < 8126464) {
    idx = gid - 7864320;
    v = kpW[idx];
    ph = kph; pl = kpl;
  } else {                                            // cpWT[c][h] = cpW[h][c]
    idx = gid - 8126464;                              // 262144
    int h = idx >> 9, c = idx & 511;
    cpWT[(size_t)c*512 + h] = cpW[(size_t)h*512 + c];
    return;
  }
  _Float16 hi = (_Float16)v;
  _Float16 lo = (_Float16)(v - (float)hi);
  ph[idx] = hi; pl[idx] = lo;
}

// ---------------- f32 -> fp16 bulk cast (outW), half8-vectorized -----------
__global__ void casth_out(const float* __restrict__ src, _Float16* __restrict__ dst)
{
  size_t i = ((size_t)blockIdx.x*256 + threadIdx.x)*8;   // n = 16,384,000
  float4 f0 = *(const float4*)(src + i);
  float4 f1 = *(const float4*)(src + i + 4);
  half8 hv = {(_Float16)f0.x,(_Float16)f0.y,(_Float16)f0.z,(_Float16)f0.w,
              (_Float16)f1.x,(_Float16)f1.y,(_Float16)f1.z,(_Float16)f1.w};
  *(half8*)(dst + i) = hv;
}

// ---------------- split-fp16 3-term MFMA GEMM ------------------------------
__global__ __launch_bounds__(256) void gemm3(
    const _Float16* __restrict__ Ah, const _Float16* __restrict__ Al,
    const _Float16* __restrict__ Bh, const _Float16* __restrict__ Bl,
    float* __restrict__ C, int Kd, int ldc)
{
  __shared__ __align__(16) _Float16 Ahs[4096];
  __shared__ __align__(16) _Float16 Als[4096];
  __shared__ __align__(16) _Float16 Bhs[4096];
  __shared__ __align__(16) _Float16 Bls[4096];
  const int tid = threadIdx.x, lane = tid & 63, wave = tid >> 6;
  const int bm = blockIdx.x, bn = blockIdx.y;
  const int wm = wave >> 1, wn = wave & 1;
  const size_t aoff = ((size_t)bm*128 + wave*16 + (lane>>2))*Kd + (lane&3)*8;
  const size_t boff = ((size_t)bn*128 + wave*16 + (lane>>2))*Kd + (lane&3)*8;
  const size_t hstep = (size_t)64*Kd;
  _Float16* Ahl = Ahs + wave*512;
  _Float16* All = Als + wave*512;
  _Float16* Bhl = Bhs + wave*512;
  _Float16* Bll = Bls + wave*512;
  f32x4 acc[4][4] = {};
  for (int k0 = 0; k0 < Kd; k0 += 32) {
    glds16(Ah + aoff + k0, Ahl);  glds16(Ah + aoff + hstep + k0, Ahl + 2048);
    glds16(Al + aoff + k0, All);  glds16(Al + aoff + hstep + k0, All + 2048);
    glds16(Bh + boff + k0, Bhl);  glds16(Bh + boff + hstep + k0, Bhl + 2048);
    glds16(Bl + boff + k0, Bll);  glds16(Bl + boff + hstep + k0, Bll + 2048);
    __syncthreads();
    const int ar = lane & 15, kb = (lane>>4)*8;
    half8 ah[4], al[4], bh[4], bl[4];
    #pragma unroll
    for (int m=0;m<4;++m){
      ah[m] = *(const half8*)&Ahs[(wm*64 + m*16 + ar)*32 + kb];
      al[m] = *(const half8*)&Als[(wm*64 + m*16 + ar)*32 + kb];
    }
    #pragma unroll
    for (int n=0;n<4;++n){
      bh[n] = *(const half8*)&Bhs[(wn*64 + n*16 + ar)*32 + kb];
      bl[n] = *(const half8*)&Bls[(wn*64 + n*16 + ar)*32 + kb];
    }
    #pragma unroll
    for (int m=0;m<4;++m)
      #pragma unroll
      for (int n=0;n<4;++n){
        acc[m][n] = __builtin_amdgcn_mfma_f32_16x16x32_f16(ah[m], bh[n], acc[m][n], 0,0,0);
        acc[m][n] = __builtin_amdgcn_mfma_f32_16x16x32_f16(ah[m], bl[n], acc[m][n], 0,0,0);
        acc[m][n] = __builtin_amdgcn_mfma_f32_16x16x32_f16(al[m], bh[n], acc[m][n], 0,0,0);
      }
    __syncthreads();
  }
  const int r0 = bm*128 + wm*64 + ((lane>>4)<<2);
  const int c0 = bn*128 + wn*64 + (lane&15);
  #pragma unroll
  for (int m=0;m<4;++m)
    #pragma unroll
    for (int n=0;n<4;++n)
      #pragma unroll
      for (int e=0;e<4;++e)
        C[(size_t)(r0 + m*16 + e)*ldc + c0 + n*16] = acc[m][n][e];
}

// ---------------- two-operand fp16 GEMM (vocab, pre-cast B) ----------------
__global__ __launch_bounds__(256) void gemm_hh(
    const _Float16* __restrict__ A, const _Float16* __restrict__ B,
    float* __restrict__ C, int Kd, int ldc)
{
  __shared__ __align__(16) _Float16 As[128*32];
  __shared__ __align__(16) _Float16 Bs[128*32];
  const int tid = threadIdx.x, lane = tid & 63, wave = tid >> 6;
  const int bm = blockIdx.x, bn = blockIdx.y;
  const int wm = wave >> 1, wn = wave & 1;
  const _Float16* Ag = A + ((size_t)bm*128 + wave*16 + (lane>>2))*Kd + (lane&3)*8;
  const _Float16* Bg = B + ((size_t)bn*128 + wave*16 + (lane>>2))*Kd + (lane&3)*8;
  _Float16* Al = As + wave*512;
  _Float16* Bl = Bs + wave*512;
  f32x4 acc[4][4] = {};
  for (int k0 = 0; k0 < Kd; k0 += 32) {
    glds16(Ag + k0, Al);
    glds16(Ag + (size_t)64*Kd + k0, Al + 2048);
    glds16(Bg + k0, Bl);
    glds16(Bg + (size_t)64*Kd + k0, Bl + 2048);
    __syncthreads();
    half8 af[4], bf[4];
    const int ar = lane & 15, kb = (lane>>4)*8;
    #pragma unroll
    for (int m=0;m<4;++m) af[m] = *(const half8*)&As[(wm*64 + m*16 + ar)*32 + kb];
    #pragma unroll
    for (int n=0;n<4;++n) bf[n] = *(const half8*)&Bs[(wn*64 + n*16 + ar)*32 + kb];
    #pragma unroll
    for (int m=0;m<4;++m)
      #pragma unroll
      for (int n=0;n<4;++n)
        acc[m][n] = __builtin_amdgcn_mfma_f32_16x16x32_f16(af[m], bf[n], acc[m][n], 0,0,0);
    __syncthreads();
  }
  const int r0 = bm*128 + wm*64 + ((lane>>4)<<2);
  const int c0 = bn*128 + wn*64 + (lane&15);
  #pragma unroll
  for (int m=0;m<4;++m)
    #pragma unroll
    for (int n=0;n<4;++n)
      #pragma unroll
      for (int e=0;e<4;++e)
        C[(size_t)(r0 + m*16 + e)*ldc + c0 + n*16] = acc[m][n][e];
}

// ---------------- vocab GEMM (legacy): fp16 A x f32->fp16 B in-kernel ------
__global__ __launch_bounds__(256) void gemm_hf(
    const _Float16* __restrict__ A, const float* __restrict__ Bf,
    float* __restrict__ C, int Kd, int ldc)
{
  __shared__ __align__(16) _Float16 As[128*32];
  __shared__ __align__(16) _Float16 Bs[128*32];
  const int tid = threadIdx.x, lane = tid & 63, wave = tid >> 6;
  const int bm = blockIdx.x, bn = blockIdx.y;
  const int wm = wave >> 1, wn = wave & 1;
  const _Float16* Ag = A + ((size_t)bm*128 + wave*16 + (lane>>2))*Kd + (lane&3)*8;
  _Float16* Al = As + wave*512;
  const float* Bg = Bf + ((size_t)bn*128 + (tid>>2))*Kd + (tid&3)*8;
  f32x4 acc[4][4] = {};
  for (int k0 = 0; k0 < Kd; k0 += 32) {
    glds16(Ag + k0, Al);
    glds16(Ag + (size_t)64*Kd + k0, Al + 2048);
    #pragma unroll
    for (int i=0;i<2;++i){
      const float* src = Bg + (size_t)i*64*Kd + k0;
      float4 f0 = *(const float4*)src;
      float4 f1 = *(const float4*)(src+4);
      half8 hv = {(_Float16)f0.x,(_Float16)f0.y,(_Float16)f0.z,(_Float16)f0.w,
                  (_Float16)f1.x,(_Float16)f1.y,(_Float16)f1.z,(_Float16)f1.w};
      *(half8*)&Bs[i*2048 + tid*8] = hv;
    }
    __syncthreads();
    half8 af[4], bf[4];
    const int ar = lane & 15, kb = (lane>>4)*8;
    #pragma unroll
    for (int m=0;m<4;++m) af[m] = *(const half8*)&As[(wm*64 + m*16 + ar)*32 + kb];
    #pragma unroll
    for (int n=0;n<4;++n) bf[n] = *(const half8*)&Bs[(wn*64 + n*16 + ar)*32 + kb];
    #pragma unroll
    for (int m=0;m<4;++m)
      #pragma unroll
      for (int n=0;n<4;++n)
        acc[m][n] = __builtin_amdgcn_mfma_f32_16x16x32_f16(af[m], bf[n], acc[m][n], 0,0,0);
    __syncthreads();
  }
  const int r0 = bm*128 + wm*64 + ((lane>>4)<<2);
  const int c0 = bn*128 + wn*64 + (lane&15);
  #pragma unroll
  for (int m=0;m<4;++m)
    #pragma unroll
    for (int n=0;n<4;++n)
      #pragma unroll
      for (int e=0;e<4;++e)
        C[(size_t)(r0 + m*16 + e)*ldc + c0 + n*16] = acc[m][n][e];
}

// ---------------- layer-0 scan: f32, writes A1 hi/lo -----------------------
__global__ void scan0(const float* __restrict__ C0, const float* __restrict__ ep,
    const float* __restrict__ zb0, const float* __restrict__ fb0,
    const float* __restrict__ ob0, const float* __restrict__ ib0,
    _Float16* __restrict__ A1h, _Float16* __restrict__ A1l)
{
  int gid = blockIdx.x*256 + threadIdx.x;   // 16384
  int h = gid & 511, b = gid >> 9;
  float ez = ep[b*512 + h];
  float eo = ep[16384 + b*512 + h];
  float ei = ep[32768 + b*512 + h];
  float bz = zb0[h], bff = fb0[h], bo = ob0[h], bi = ib0[h];
  float c = 0.f;
  size_t base = (size_t)b*64*1024;
  A1h[base + h] = (_Float16)0.f;
  A1l[base + h] = (_Float16)0.f;
  for (int t=0;t<64;++t){
    size_t row = (size_t)b*64 + t;
    const float* g = C0 + row*2048;
    float z = tanhf(g[h]      + bz  + ez);
    float f = sigp (g[512+h]  + bff + ez);   // f0 uses epz0 (per reference)
    float o = sigp (g[1024+h] + bo  + eo);
    float i = sigp (g[1536+h] + bi  + ei);
    c = f*c + i*z;
    float h0 = o*c;
    _Float16 hi = (_Float16)h0;
    _Float16 lo = (_Float16)(h0 - (float)hi);
    A1h[row*1024 + 512 + h] = hi;
    A1l[row*1024 + 512 + h] = lo;
    if (t < 63){
      A1h[(row+1)*1024 + h] = hi;
      A1l[(row+1)*1024 + h] = lo;
    }
  }
}

// ---------------- layer-1 activations: F1, O1, PZ=(1-f1)*z1 ----------------
__global__ void act1(const float* __restrict__ C1, const float* __restrict__ ep,
    const float* __restrict__ zb1, const float* __restrict__ fb1,
    const float* __restrict__ ob1,
    float* __restrict__ F1, float* __restrict__ O1, float* __restrict__ PZ)
{
  int gid = blockIdx.x*256 + threadIdx.x;   // 2048*512
  int h = gid & 511; size_t row = gid >> 9; int b = (int)(row >> 6);
  const float* g = C1 + row*1536;
  float ez = ep[3*16384 + b*512 + h];
  float eo = ep[4*16384 + b*512 + h];
  float z1 = tanhf(g[h]      + zb1[h] + ez);
  float f1 = sigp (g[512+h]  + fb1[h] + ez);   // f1 uses epz1 (per reference)
  float o1 = sigp (g[1024+h] + ob1[h] + eo);
  F1[gid] = f1; O1[gid] = o1; PZ[gid] = (1.f - f1)*z1;
}

// ---------------- decode2: byte-identical to round 16 (907us, proven) ------
__global__ __launch_bounds__(1024)
__attribute__((amdgpu_waves_per_eu(4, 4)))
void decode2(
  const _Float16* __restrict__ ench_g, const _Float16* __restrict__ encl_g,
  const float* __restrict__ F1, const float* __restrict__ O1,
  const float* __restrict__ PZ, const float* __restrict__ EP,
  const float* __restrict__ cpWT, const float* __restrict__ kpb,
  const float* __restrict__ cpb,
  float* __restrict__ att_probs, float* __restrict__ att_vec,
  _Float16* __restrict__ A2)
{
  __shared__ __align__(16) unsigned char encs[131072];
  __shared__ __align__(16) float kpq[4][512];
  __shared__ __align__(16) _Float16 kqh[4][512];
  __shared__ __align__(16) float gvp[4][512];
  __shared__ __align__(16) float c1s[512];
  __shared__ float scores[128];
  const int b = blockIdx.x, tid = threadIdx.x;
  const int w = tid >> 6, l = tid & 63;
  const _Float16* enchb = ench_g + (size_t)b*65536;
  const _Float16* enclb = encl_g + (size_t)b*65536;
  const float*    EPb   = EP     + (size_t)b*65536;

  for (int idx = tid; idx < 8192; idx += 1024) {
    int s = idx >> 6, c = idx & 63;
    half8 v = *(const half8*)(enchb + (size_t)s*512 + c*8);
    int byte = (s*1024 + c*16) ^ ((s&7)<<4);
    *(half8*)(encs + byte) = v;
  }
  float h1 = 0.f;
  const float bsum = (tid < 512) ? (kpb[tid] + cpb[tid]) : 0.f;
  const int gvg = (tid >> 7) & 3, gvh = tid & 127;
  const float* gwt = cpWT + (size_t)(gvg*128)*512 + gvh*4;
  __syncthreads();

  for (int t = 0; t < 64; ++t) {
    const size_t bt = (size_t)b*64 + t;
    if (tid < 512)
      c1s[tid] = F1[bt*512 + tid]*h1 + PZ[bt*512 + tid];
    __syncthreads();
    float ga0 = 0.f, ga1 = 0.f, ga2 = 0.f, ga3 = 0.f;
    if (tid < 512) {
      int s = tid >> 2, q = tid & 3;
      const _Float16* el = enclb + (size_t)s*512;
      float acc = 0.f;
      #pragma unroll 8
      for (int j = 0; j < 16; ++j) {
        int col = j*32 + q*8;
        int byte = (s*1024 + col*2) ^ ((s&7)<<4);
        half8 eh  = *(const half8*)(encs + byte);
        half8 elv = *(const half8*)(el + col);
        const float* cr = c1s + col;
        #pragma unroll
        for (int u = 0; u < 8; ++u)
          acc += ((float)eh[u] + (float)elv[u]) * cr[u];
      }
      acc += __shfl_xor(acc,1); acc += __shfl_xor(acc,2);
      if (q == 0) scores[s] = acc;
    } else {
      #pragma unroll 8
      for (int c = 0; c < 72; ++c) {
        float cv = c1s[gvg*128 + c];
        float4 wv = *(const float4*)(gwt + (size_t)c*512);
        ga0 += wv.x*cv; ga1 += wv.y*cv; ga2 += wv.z*cv; ga3 += wv.w*cv;
      }
    }
    __syncthreads();
    float a0 = 0.f, a1 = 0.f;
    if (w < 8) {
      float s0 = scores[l], s1 = scores[l+64];
      float m = fmaxf(s0, s1);
      #pragma unroll
      for (int off=32; off; off>>=1) m = fmaxf(m, __shfl_xor(m, off));
      float e0 = expf(s0-m), e1 = expf(s1-m);
      float sm = e0+e1;
      #pragma unroll
      for (int off=32; off; off>>=1) sm += __shfl_xor(sm, off);
      float inv = 1.f/sm;
      a0 = e0*inv; a1 = e1*inv;
      if (w == 0) {
        att_probs[bt*128 + l]      = a0;
        att_probs[bt*128 + 64 + l] = a1;
      }
    }
    if (w < 4) {
      const float* pr = EPb + (size_t)(w*32)*512 + l*8;
      float p0=0,p1=0,p2=0,p3=0,p4=0,p5=0,p6=0,p7=0;
      #pragma unroll 8
      for (int si = 0; si < 32; ++si) {
        int s = w*32 + si;
        float a = (s < 64) ? __shfl(a0, s) : __shfl(a1, s - 64);
        float4 q0 = *(const float4*)(pr + (size_t)si*512);
        float4 q1 = *(const float4*)(pr + (size_t)si*512 + 4);
        p0 += a*q0.x; p1 += a*q0.y; p2 += a*q0.z; p3 += a*q0.w;
        p4 += a*q1.x; p5 += a*q1.y; p6 += a*q1.z; p7 += a*q1.w;
      }
      *(float4*)&kpq[w][l*8]   = make_float4(p0,p1,p2,p3);
      *(float4*)&kpq[w][l*8+4] = make_float4(p4,p5,p6,p7);
    } else if (w < 8) {
      int wv = w - 4;
      float k0=0,k1=0,k2=0,k3=0,k4=0,k5=0,k6=0,k7=0;
      #pragma unroll 4
      for (int si = 0; si < 32; ++si) {
        int s = wv*32 + si;
        float a = (s < 64) ? __shfl(a0, s) : __shfl(a1, s - 64);
        int byte = (s*1024 + l*16) ^ ((s&7)<<4);
        half8 v = *(const half8*)(encs + byte);
        k0 += a*(float)v[0]; k1 += a*(float)v[1];
        k2 += a*(float)v[2]; k3 += a*(float)v[3];
        k4 += a*(float)v[4]; k5 += a*(float)v[5];
        k6 += a*(float)v[6]; k7 += a*(float)v[7];
      }
      half8 st = {(_Float16)k0,(_Float16)k1,(_Float16)k2,(_Float16)k3,
                  (_Float16)k4,(_Float16)k5,(_Float16)k6,(_Float16)k7};
      *(half8*)&kqh[wv][l*8] = st;
    } else {
      #pragma unroll 8
      for (int c = 72; c < 128; ++c) {
        float cv = c1s[gvg*128 + c];
        float4 wv = *(const float4*)(gwt + (size_t)c*512);
        ga0 += wv.x*cv; ga1 += wv.y*cv; ga2 += wv.z*cv; ga3 += wv.w*cv;
      }
      *(float4*)&gvp[gvg][gvh*4] = make_float4(ga0,ga1,ga2,ga3);
    }
    __syncthreads();
    if (tid < 512) {
      float kp = kpq[0][tid] + kpq[1][tid] + kpq[2][tid] + kpq[3][tid];
      float kv = (float)kqh[0][tid] + (float)kqh[1][tid]
               + (float)kqh[2][tid] + (float)kqh[3][tid];
      float gvv = gvp[0][tid] + gvp[1][tid] + gvp[2][tid] + gvp[3][tid];
      att_vec[bt*512 + tid] = kv;
      float h1n = (gvv + kp + bsum) * O1[bt*512 + tid];
      h1 = h1n;
      A2[bt*512 + tid] = (_Float16)h1n;
    }
  }
}

// ---------------------------------------------------------------------------
extern "C" void kernel_launch(void* const* d_in, const int* in_sizes, int n_in,
                              void* d_out, int out_size, void* d_ws, size_t ws_size,
                              hipStream_t stream) {
  const float* trg  = (const float*)d_in[0];
  const float* enc  = (const float*)d_in[1];
  const float* ehid = (const float*)d_in[2];
  const float* zW0 = (const float*)d_in[5];  const float* zb0 = (const float*)d_in[6];
  const float* fW0 = (const float*)d_in[7];  const float* fb0 = (const float*)d_in[8];
  const float* oW0 = (const float*)d_in[9];  const float* ob0 = (const float*)d_in[10];
  const float* iW0 = (const float*)d_in[11]; const float* ib0 = (const float*)d_in[12];
  const float* epzW0 = (const float*)d_in[13]; const float* epzb0 = (const float*)d_in[14];
  const float* epoW0 = (const float*)d_in[15]; const float* epob0 = (const float*)d_in[16];
  const float* epiW0 = (const float*)d_in[17]; const float* epib0 = (const float*)d_in[18];
  const float* zW1 = (const float*)d_in[19]; const float* zb1 = (const float*)d_in[20];
  const float* fW1 = (const float*)d_in[21]; const float* fb1 = (const float*)d_in[22];
  const float* oW1 = (const float*)d_in[23]; const float* ob1 = (const float*)d_in[24];
  const float* epzW1 = (const float*)d_in[25]; const float* epzb1 = (const float*)d_in[26];
  const float* epoW1 = (const float*)d_in[27]; const float* epob1 = (const float*)d_in[28];
  const float* kpW = (const float*)d_in[29]; const float* kpb = (const float*)d_in[30];
  const float* cpW = (const float*)d_in[31]; const float* cpb = (const float*)d_in[32];
  const float* outW = (const float*)d_in[33];

  float* out = (float*)d_out;
  float* att_probs = out + (size_t)65536000;            // B*T*V
  float* att_vec   = att_probs + (size_t)262144;        // + B*T*S

  // SMALL (persists) in ws; BIG transients in ws if it fits, else inside
  // d_out's logits region (fully overwritten by the final GEMM). outWh only
  // exists (and the fast vocab path only runs) if ws also covers it — it is
  // read BY the final GEMM and must not alias d_out.
  const size_t SMALL = 2097152 + 327680;
  const size_t BIG   = 92274688;
  const size_t OUTWH = 33554432;
  char* pA2  = (char*)d_ws;
  char* pep  = pA2  + 2097152;
  bool fit1 = (ws_size >= SMALL + BIG);
  bool fit2 = (ws_size >= SMALL + BIG + OUTWH);
  char* big = fit1 ? pep + 327680 : (char*)d_out;
  char* p = big;
  _Float16* A0h  = (_Float16*)p; p += 4194304;
  _Float16* A0l  = (_Float16*)p; p += 4194304;
  _Float16* W0h  = (_Float16*)p; p += 4194304;
  _Float16* W0l  = (_Float16*)p; p += 4194304;
  _Float16* A1h  = (_Float16*)p; p += 4194304;
  _Float16* A1l  = (_Float16*)p; p += 4194304;
  _Float16* W1h  = (_Float16*)p; p += 3145728;
  _Float16* W1l  = (_Float16*)p; p += 3145728;
  _Float16* ench = (_Float16*)p; p += 4194304;
  _Float16* encl = (_Float16*)p; p += 4194304;
  _Float16* kph  = (_Float16*)p; p += 524288;
  _Float16* kpl  = (_Float16*)p; p += 524288;
  float*    C0   = (float*)p;    p += 16777216;
  float*    C1   = (float*)p;    p += 12582912;
  float*    F1   = (float*)p;    p += 4194304;
  float*    O1   = (float*)p;    p += 4194304;
  float*    PZ   = (float*)p;    p += 4194304;
  float*    EP   = (float*)p;    p += 8388608;
  float*    cpWT = (float*)p;    p += 1048576;
  _Float16* outWh = (_Float16*)p;                       // valid only if fit2
  _Float16* A2  = (_Float16*)pA2;
  float*    ep  = (float*)pep;

  hipLaunchKernelGGL(ep_proj, dim3(1280), dim3(256), 0, stream,
      ehid, epzW0,epzb0, epoW0,epob0, epiW0,epib0, epzW1,epzb1, epoW1,epob1, ep);
  hipLaunchKernelGGL(pack2, dim3(32768), dim3(256), 0, stream,
      trg, zW0,fW0,oW0,iW0, zW1,fW1,oW1, enc, kpW, cpW,
      A0h,A0l, W0h,W0l, W1h,W1l, ench,encl, kph,kpl, cpWT);
  if (fit2)
    hipLaunchKernelGGL(casth_out, dim3(8000), dim3(256), 0, stream, outW, outWh);
  hipLaunchKernelGGL(gemm3, dim3(16,16), dim3(256), 0, stream,
      A0h, A0l, W0h, W0l, C0, 1024, 2048);
  hipLaunchKernelGGL(scan0, dim3(64), dim3(256), 0, stream,
      C0, ep, zb0,fb0,ob0,ib0, A1h, A1l);
  hipLaunchKernelGGL(gemm3, dim3(16,12), dim3(256), 0, stream,
      A1h, A1l, W1h, W1l, C1, 1024, 1536);
  hipLaunchKernelGGL(act1, dim3(4096), dim3(256), 0, stream,
      C1, ep, zb1,fb1,ob1, F1, O1, PZ);
  hipLaunchKernelGGL(gemm3, dim3(32,4), dim3(256), 0, stream,
      ench, encl, kph, kpl, EP, 512, 512);
  hipLaunchKernelGGL(decode2, dim3(32), dim3(1024), 0, stream,
      ench, encl, F1, O1, PZ, EP, cpWT, kpb, cpb, att_probs, att_vec, A2);
  if (fit2)
    hipLaunchKernelGGL(gemm_hh, dim3(16,250), dim3(256), 0, stream,
        A2, outWh, out, 512, 32000);
  else
    hipLaunchKernelGGL(gemm_hf, dim3(16,250), dim3(256), 0, stream,
        A2, outW, out, 512, 32000);
}

// Round 18
// 1182.681 us; speedup vs baseline: 2.3916x; 1.0804x over previous
//
#include <hip/hip_runtime.h>
#include <cmath>

// ---------------------------------------------------------------------------
// QRNN decoder, MI355X. B=32 T=64 S=128 EMB=H=E=512 V=32000 K=2.
// NUMERICS INVARIANT (r4..r17): anything feeding the c1/h1 recurrence
// (cpW GEMV, EP) must be f32-exact; fp16 only on output-side paths
// (att_vec, logits) or as hi/lo split pairs.
// PERF: decode2 frozen at r16/r17 (907us, ~70% of TA-line floor). This round:
// act1 fused into the C1 GEMM epilogue (gemm3a writes Z1/F1/O1 directly,
// saving one launch + 25MB C1 round-trip); decode computes (1-f1)*z1 inline.
// ---------------------------------------------------------------------------

typedef _Float16 half8  __attribute__((ext_vector_type(8)));
typedef float    f32x4  __attribute__((ext_vector_type(4)));

#define DEVFN static __device__ __forceinline__

DEVFN float sigp(float x){ return 1.f/(1.f+expf(-x)); }

DEVFN void glds16(const _Float16* g, _Float16* l){
  __builtin_amdgcn_global_load_lds((const __attribute__((address_space(1))) void*)g,
                                   (__attribute__((address_space(3))) void*)l, 16, 0, 0);
}

// ---------------- encoder-hidden projections: 5 x (B,E)@(E,H), f32 ---------
__global__ void ep_proj(const float* __restrict__ ehid,
    const float* __restrict__ w0, const float* __restrict__ b0,
    const float* __restrict__ w1, const float* __restrict__ b1,
    const float* __restrict__ w2, const float* __restrict__ b2,
    const float* __restrict__ w3, const float* __restrict__ b3,
    const float* __restrict__ w4, const float* __restrict__ b4,
    float* __restrict__ ep)
{
  int gid = blockIdx.x*256 + threadIdx.x;            // 5*32*512*4 = 327680
  int q = gid & 3, h = (gid>>2)&511, b = (gid>>11)&31, p = gid>>16;
  const float* w    = (p==0)?w0:(p==1)?w1:(p==2)?w2:(p==3)?w3:w4;
  const float* bias = (p==0)?b0:(p==1)?b1:(p==2)?b2:(p==3)?b3:b4;
  const float* x  = ehid + ((p>=3)?32*512:0) + b*512 + q*128;
  const float* wr = w + (size_t)h*512 + q*128;
  float acc = 0.f;
  #pragma unroll 8
  for (int j=0;j<128;j+=4){
    float4 wv = *(const float4*)(wr+j);
    float4 xv = *(const float4*)(x+j);
    acc += wv.x*xv.x + wv.y*xv.y + wv.z*xv.z + wv.w*xv.w;
  }
  acc += __shfl_xor(acc,1); acc += __shfl_xor(acc,2);
  if (q==0) ep[p*16384 + b*512 + h] = acc + bias[h];
}

// ---------------- hi/lo fp16 packing + cpW transpose -----------------------
__global__ void pack2(const float* __restrict__ trg,
  const float* __restrict__ zW0, const float* __restrict__ fW0,
  const float* __restrict__ oW0, const float* __restrict__ iW0,
  const float* __restrict__ zW1, const float* __restrict__ fW1,
  const float* __restrict__ oW1,
  const float* __restrict__ enc, const float* __restrict__ kpW,
  const float* __restrict__ cpW,
  _Float16* __restrict__ A0h, _Float16* __restrict__ A0l,
  _Float16* __restrict__ W0h, _Float16* __restrict__ W0l,
  _Float16* __restrict__ W1h, _Float16* __restrict__ W1l,
  _Float16* __restrict__ ench, _Float16* __restrict__ encl,
  _Float16* __restrict__ kph, _Float16* __restrict__ kpl,
  float* __restrict__ cpWT)
{
  int gid = blockIdx.x*256 + threadIdx.x;            // 8,388,608 total
  float v; _Float16 *ph, *pl; int idx;
  if (gid < 2097152) {
    idx = gid;
    int m = idx >> 10, c = idx & 1023, t = m & 63, kk = c >> 9, i = c & 511;
    v = (kk==0) ? ((t>0) ? trg[(size_t)(m-1)*512 + i] : 0.f)
                : trg[(size_t)m*512 + i];
    ph = A0h; pl = A0l;
  } else if (gid < 4194304) {
    idx = gid - 2097152;
    int r = idx >> 10, c = idx & 1023, g = r >> 9, o = r & 511, kk = c >> 9, i = c & 511;
    const float* W = (g==0)?zW0:(g==1)?fW0:(g==2)?oW0:iW0;
    v = W[(size_t)o*1024 + i*2 + kk];
    ph = W0h; pl = W0l;
  } else if (gid < 5767168) {
    idx = gid - 4194304;
    int r = idx >> 10, c = idx & 1023, g = r >> 9, o = r & 511, kk = c >> 9, i = c & 511;
    const float* W = (g==0)?zW1:(g==1)?fW1:oW1;
    v = W[(size_t)o*1024 + i*2 + kk];
    ph = W1h; pl = W1l;
  } else if (gid < 7864320) {
    idx = gid - 5767168;
    v = enc[idx];
    ph = ench; pl = encl;
  } else if (gid < 8126464) {
    idx = gid - 7864320;
    v = kpW[idx];
    ph = kph; pl = kpl;
  } else {                                            // cpWT[c][h] = cpW[h][c]
    idx = gid - 8126464;                              // 262144
    int h = idx >> 9, c = idx & 511;
    cpWT[(size_t)c*512 + h] = cpW[(size_t)h*512 + c];
    return;
  }
  _Float16 hi = (_Float16)v;
  _Float16 lo = (_Float16)(v - (float)hi);
  ph[idx] = hi; pl[idx] = lo;
}

// ---------------- f32 -> fp16 bulk cast (outW), half8-vectorized -----------
__global__ void casth_out(const float* __restrict__ src, _Float16* __restrict__ dst)
{
  size_t i = ((size_t)blockIdx.x*256 + threadIdx.x)*8;   // n = 16,384,000
  float4 f0 = *(const float4*)(src + i);
  float4 f1 = *(const float4*)(src + i + 4);
  half8 hv = {(_Float16)f0.x,(_Float16)f0.y,(_Float16)f0.z,(_Float16)f0.w,
              (_Float16)f1.x,(_Float16)f1.y,(_Float16)f1.z,(_Float16)f1.w};
  *(half8*)(dst + i) = hv;
}

// ---------------- split-fp16 3-term MFMA GEMM (plain C-write) --------------
__global__ __launch_bounds__(256) void gemm3(
    const _Float16* __restrict__ Ah, const _Float16* __restrict__ Al,
    const _Float16* __restrict__ Bh, const _Float16* __restrict__ Bl,
    float* __restrict__ C, int Kd, int ldc)
{
  __shared__ __align__(16) _Float16 Ahs[4096];
  __shared__ __align__(16) _Float16 Als[4096];
  __shared__ __align__(16) _Float16 Bhs[4096];
  __shared__ __align__(16) _Float16 Bls[4096];
  const int tid = threadIdx.x, lane = tid & 63, wave = tid >> 6;
  const int bm = blockIdx.x, bn = blockIdx.y;
  const int wm = wave >> 1, wn = wave & 1;
  const size_t aoff = ((size_t)bm*128 + wave*16 + (lane>>2))*Kd + (lane&3)*8;
  const size_t boff = ((size_t)bn*128 + wave*16 + (lane>>2))*Kd + (lane&3)*8;
  const size_t hstep = (size_t)64*Kd;
  _Float16* Ahl = Ahs + wave*512;
  _Float16* All = Als + wave*512;
  _Float16* Bhl = Bhs + wave*512;
  _Float16* Bll = Bls + wave*512;
  f32x4 acc[4][4] = {};
  for (int k0 = 0; k0 < Kd; k0 += 32) {
    glds16(Ah + aoff + k0, Ahl);  glds16(Ah + aoff + hstep + k0, Ahl + 2048);
    glds16(Al + aoff + k0, All);  glds16(Al + aoff + hstep + k0, All + 2048);
    glds16(Bh + boff + k0, Bhl);  glds16(Bh + boff + hstep + k0, Bhl + 2048);
    glds16(Bl + boff + k0, Bll);  glds16(Bl + boff + hstep + k0, Bll + 2048);
    __syncthreads();
    const int ar = lane & 15, kb = (lane>>4)*8;
    half8 ah[4], al[4], bh[4], bl[4];
    #pragma unroll
    for (int m=0;m<4;++m){
      ah[m] = *(const half8*)&Ahs[(wm*64 + m*16 + ar)*32 + kb];
      al[m] = *(const half8*)&Als[(wm*64 + m*16 + ar)*32 + kb];
    }
    #pragma unroll
    for (int n=0;n<4;++n){
      bh[n] = *(const half8*)&Bhs[(wn*64 + n*16 + ar)*32 + kb];
      bl[n] = *(const half8*)&Bls[(wn*64 + n*16 + ar)*32 + kb];
    }
    #pragma unroll
    for (int m=0;m<4;++m)
      #pragma unroll
      for (int n=0;n<4;++n){
        acc[m][n] = __builtin_amdgcn_mfma_f32_16x16x32_f16(ah[m], bh[n], acc[m][n], 0,0,0);
        acc[m][n] = __builtin_amdgcn_mfma_f32_16x16x32_f16(ah[m], bl[n], acc[m][n], 0,0,0);
        acc[m][n] = __builtin_amdgcn_mfma_f32_16x16x32_f16(al[m], bh[n], acc[m][n], 0,0,0);
      }
    __syncthreads();
  }
  const int r0 = bm*128 + wm*64 + ((lane>>4)<<2);
  const int c0 = bn*128 + wn*64 + (lane&15);
  #pragma unroll
  for (int m=0;m<4;++m)
    #pragma unroll
    for (int n=0;n<4;++n)
      #pragma unroll
      for (int e=0;e<4;++e)
        C[(size_t)(r0 + m*16 + e)*ldc + c0 + n*16] = acc[m][n][e];
}

// ------- split-fp16 3-term MFMA GEMM + fused layer-1 activations -----------
// N=1536 (z|f|o gates). Each 128-col tile lies in one gate (bn>>2).
// Writes Z1/F1/O1[row*512+h] with the exact act1 formulas (bit-identical).
__global__ __launch_bounds__(256) void gemm3a(
    const _Float16* __restrict__ Ah, const _Float16* __restrict__ Al,
    const _Float16* __restrict__ Bh, const _Float16* __restrict__ Bl,
    const float* __restrict__ ep,
    const float* __restrict__ zb1, const float* __restrict__ fb1,
    const float* __restrict__ ob1,
    float* __restrict__ Z1, float* __restrict__ F1, float* __restrict__ O1,
    int Kd)
{
  __shared__ __align__(16) _Float16 Ahs[4096];
  __shared__ __align__(16) _Float16 Als[4096];
  __shared__ __align__(16) _Float16 Bhs[4096];
  __shared__ __align__(16) _Float16 Bls[4096];
  const int tid = threadIdx.x, lane = tid & 63, wave = tid >> 6;
  const int bm = blockIdx.x, bn = blockIdx.y;
  const int wm = wave >> 1, wn = wave & 1;
  const size_t aoff = ((size_t)bm*128 + wave*16 + (lane>>2))*Kd + (lane&3)*8;
  const size_t boff = ((size_t)bn*128 + wave*16 + (lane>>2))*Kd + (lane&3)*8;
  const size_t hstep = (size_t)64*Kd;
  _Float16* Ahl = Ahs + wave*512;
  _Float16* All = Als + wave*512;
  _Float16* Bhl = Bhs + wave*512;
  _Float16* Bll = Bls + wave*512;
  f32x4 acc[4][4] = {};
  for (int k0 = 0; k0 < Kd; k0 += 32) {
    glds16(Ah + aoff + k0, Ahl);  glds16(Ah + aoff + hstep + k0, Ahl + 2048);
    glds16(Al + aoff + k0, All);  glds16(Al + aoff + hstep + k0, All + 2048);
    glds16(Bh + boff + k0, Bhl);  glds16(Bh + boff + hstep + k0, Bhl + 2048);
    glds16(Bl + boff + k0, Bll);  glds16(Bl + boff + hstep + k0, Bll + 2048);
    __syncthreads();
    const int ar = lane & 15, kb = (lane>>4)*8;
    half8 ah[4], al[4], bh[4], bl[4];
    #pragma unroll
    for (int m=0;m<4;++m){
      ah[m] = *(const half8*)&Ahs[(wm*64 + m*16 + ar)*32 + kb];
      al[m] = *(const half8*)&Als[(wm*64 + m*16 + ar)*32 + kb];
    }
    #pragma unroll
    for (int n=0;n<4;++n){
      bh[n] = *(const half8*)&Bhs[(wn*64 + n*16 + ar)*32 + kb];
      bl[n] = *(const half8*)&Bls[(wn*64 + n*16 + ar)*32 + kb];
    }
    #pragma unroll
    for (int m=0;m<4;++m)
      #pragma unroll
      for (int n=0;n<4;++n){
        acc[m][n] = __builtin_amdgcn_mfma_f32_16x16x32_f16(ah[m], bh[n], acc[m][n], 0,0,0);
        acc[m][n] = __builtin_amdgcn_mfma_f32_16x16x32_f16(ah[m], bl[n], acc[m][n], 0,0,0);
        acc[m][n] = __builtin_amdgcn_mfma_f32_16x16x32_f16(al[m], bh[n], acc[m][n], 0,0,0);
      }
    __syncthreads();
  }
  const int r0 = bm*128 + wm*64 + ((lane>>4)<<2);
  const int c0 = bn*128 + wn*64 + (lane&15);
  const int gate = (bn*128) >> 9;                    // uniform per block
  #pragma unroll
  for (int m=0;m<4;++m)
    #pragma unroll
    for (int n=0;n<4;++n)
      #pragma unroll
      for (int e=0;e<4;++e) {
        int row = r0 + m*16 + e;
        int h   = (c0 + n*16) & 511;
        int b   = row >> 6;
        float v = acc[m][n][e];
        size_t o = (size_t)row*512 + h;
        if (gate == 0)      Z1[o] = tanhf(v + zb1[h] + ep[3*16384 + b*512 + h]);
        else if (gate == 1) F1[o] = sigp (v + fb1[h] + ep[3*16384 + b*512 + h]);
        else                O1[o] = sigp (v + ob1[h] + ep[4*16384 + b*512 + h]);
      }
}

// ---------------- two-operand fp16 GEMM (vocab, pre-cast B) ----------------
__global__ __launch_bounds__(256) void gemm_hh(
    const _Float16* __restrict__ A, const _Float16* __restrict__ B,
    float* __restrict__ C, int Kd, int ldc)
{
  __shared__ __align__(16) _Float16 As[128*32];
  __shared__ __align__(16) _Float16 Bs[128*32];
  const int tid = threadIdx.x, lane = tid & 63, wave = tid >> 6;
  const int bm = blockIdx.x, bn = blockIdx.y;
  const int wm = wave >> 1, wn = wave & 1;
  const _Float16* Ag = A + ((size_t)bm*128 + wave*16 + (lane>>2))*Kd + (lane&3)*8;
  const _Float16* Bg = B + ((size_t)bn*128 + wave*16 + (lane>>2))*Kd + (lane&3)*8;
  _Float16* Al = As + wave*512;
  _Float16* Bl = Bs + wave*512;
  f32x4 acc[4][4] = {};
  for (int k0 = 0; k0 < Kd; k0 += 32) {
    glds16(Ag + k0, Al);
    glds16(Ag + (size_t)64*Kd + k0, Al + 2048);
    glds16(Bg + k0, Bl);
    glds16(Bg + (size_t)64*Kd + k0, Bl + 2048);
    __syncthreads();
    half8 af[4], bf[4];
    const int ar = lane & 15, kb = (lane>>4)*8;
    #pragma unroll
    for (int m=0;m<4;++m) af[m] = *(const half8*)&As[(wm*64 + m*16 + ar)*32 + kb];
    #pragma unroll
    for (int n=0;n<4;++n) bf[n] = *(const half8*)&Bs[(wn*64 + n*16 + ar)*32 + kb];
    #pragma unroll
    for (int m=0;m<4;++m)
      #pragma unroll
      for (int n=0;n<4;++n)
        acc[m][n] = __builtin_amdgcn_mfma_f32_16x16x32_f16(af[m], bf[n], acc[m][n], 0,0,0);
    __syncthreads();
  }
  const int r0 = bm*128 + wm*64 + ((lane>>4)<<2);
  const int c0 = bn*128 + wn*64 + (lane&15);
  #pragma unroll
  for (int m=0;m<4;++m)
    #pragma unroll
    for (int n=0;n<4;++n)
      #pragma unroll
      for (int e=0;e<4;++e)
        C[(size_t)(r0 + m*16 + e)*ldc + c0 + n*16] = acc[m][n][e];
}

// ---------------- vocab GEMM (legacy): fp16 A x f32->fp16 B in-kernel ------
__global__ __launch_bounds__(256) void gemm_hf(
    const _Float16* __restrict__ A, const float* __restrict__ Bf,
    float* __restrict__ C, int Kd, int ldc)
{
  __shared__ __align__(16) _Float16 As[128*32];
  __shared__ __align__(16) _Float16 Bs[128*32];
  const int tid = threadIdx.x, lane = tid & 63, wave = tid >> 6;
  const int bm = blockIdx.x, bn = blockIdx.y;
  const int wm = wave >> 1, wn = wave & 1;
  const _Float16* Ag = A + ((size_t)bm*128 + wave*16 + (lane>>2))*Kd + (lane&3)*8;
  _Float16* Al = As + wave*512;
  const float* Bg = Bf + ((size_t)bn*128 + (tid>>2))*Kd + (tid&3)*8;
  f32x4 acc[4][4] = {};
  for (int k0 = 0; k0 < Kd; k0 += 32) {
    glds16(Ag + k0, Al);
    glds16(Ag + (size_t)64*Kd + k0, Al + 2048);
    #pragma unroll
    for (int i=0;i<2;++i){
      const float* src = Bg + (size_t)i*64*Kd + k0;
      float4 f0 = *(const float4*)src;
      float4 f1 = *(const float4*)(src+4);
      half8 hv = {(_Float16)f0.x,(_Float16)f0.y,(_Float16)f0.z,(_Float16)f0.w,
                  (_Float16)f1.x,(_Float16)f1.y,(_Float16)f1.z,(_Float16)f1.w};
      *(half8*)&Bs[i*2048 + tid*8] = hv;
    }
    __syncthreads();
    half8 af[4], bf[4];
    const int ar = lane & 15, kb = (lane>>4)*8;
    #pragma unroll
    for (int m=0;m<4;++m) af[m] = *(const half8*)&As[(wm*64 + m*16 + ar)*32 + kb];
    #pragma unroll
    for (int n=0;n<4;++n) bf[n] = *(const half8*)&Bs[(wn*64 + n*16 + ar)*32 + kb];
    #pragma unroll
    for (int m=0;m<4;++m)
      #pragma unroll
      for (int n=0;n<4;++n)
        acc[m][n] = __builtin_amdgcn_mfma_f32_16x16x32_f16(af[m], bf[n], acc[m][n], 0,0,0);
    __syncthreads();
  }
  const int r0 = bm*128 + wm*64 + ((lane>>4)<<2);
  const int c0 = bn*128 + wn*64 + (lane&15);
  #pragma unroll
  for (int m=0;m<4;++m)
    #pragma unroll
    for (int n=0;n<4;++n)
      #pragma unroll
      for (int e=0;e<4;++e)
        C[(size_t)(r0 + m*16 + e)*ldc + c0 + n*16] = acc[m][n][e];
}

// ---------------- layer-0 scan: f32, writes A1 hi/lo -----------------------
__global__ void scan0(const float* __restrict__ C0, const float* __restrict__ ep,
    const float* __restrict__ zb0, const float* __restrict__ fb0,
    const float* __restrict__ ob0, const float* __restrict__ ib0,
    _Float16* __restrict__ A1h, _Float16* __restrict__ A1l)
{
  int gid = blockIdx.x*256 + threadIdx.x;   // 16384
  int h = gid & 511, b = gid >> 9;
  float ez = ep[b*512 + h];
  float eo = ep[16384 + b*512 + h];
  float ei = ep[32768 + b*512 + h];
  float bz = zb0[h], bff = fb0[h], bo = ob0[h], bi = ib0[h];
  float c = 0.f;
  size_t base = (size_t)b*64*1024;
  A1h[base + h] = (_Float16)0.f;
  A1l[base + h] = (_Float16)0.f;
  for (int t=0;t<64;++t){
    size_t row = (size_t)b*64 + t;
    const float* g = C0 + row*2048;
    float z = tanhf(g[h]      + bz  + ez);
    float f = sigp (g[512+h]  + bff + ez);   // f0 uses epz0 (per reference)
    float o = sigp (g[1024+h] + bo  + eo);
    float i = sigp (g[1536+h] + bi  + ei);
    c = f*c + i*z;
    float h0 = o*c;
    _Float16 hi = (_Float16)h0;
    _Float16 lo = (_Float16)(h0 - (float)hi);
    A1h[row*1024 + 512 + h] = hi;
    A1l[row*1024 + 512 + h] = lo;
    if (t < 63){
      A1h[(row+1)*1024 + h] = hi;
      A1l[(row+1)*1024 + h] = lo;
    }
  }
}

// ---------------- decode2: r16-frozen except PZ -> Z1 (pz computed inline) -
__global__ __launch_bounds__(1024)
__attribute__((amdgpu_waves_per_eu(4, 4)))
void decode2(
  const _Float16* __restrict__ ench_g, const _Float16* __restrict__ encl_g,
  const float* __restrict__ F1, const float* __restrict__ O1,
  const float* __restrict__ Z1, const float* __restrict__ EP,
  const float* __restrict__ cpWT, const float* __restrict__ kpb,
  const float* __restrict__ cpb,
  float* __restrict__ att_probs, float* __restrict__ att_vec,
  _Float16* __restrict__ A2)
{
  __shared__ __align__(16) unsigned char encs[131072];
  __shared__ __align__(16) float kpq[4][512];
  __shared__ __align__(16) _Float16 kqh[4][512];
  __shared__ __align__(16) float gvp[4][512];
  __shared__ __align__(16) float c1s[512];
  __shared__ float scores[128];
  const int b = blockIdx.x, tid = threadIdx.x;
  const int w = tid >> 6, l = tid & 63;
  const _Float16* enchb = ench_g + (size_t)b*65536;
  const _Float16* enclb = encl_g + (size_t)b*65536;
  const float*    EPb   = EP     + (size_t)b*65536;

  for (int idx = tid; idx < 8192; idx += 1024) {
    int s = idx >> 6, c = idx & 63;
    half8 v = *(const half8*)(enchb + (size_t)s*512 + c*8);
    int byte = (s*1024 + c*16) ^ ((s&7)<<4);
    *(half8*)(encs + byte) = v;
  }
  float h1 = 0.f;
  const float bsum = (tid < 512) ? (kpb[tid] + cpb[tid]) : 0.f;
  const int gvg = (tid >> 7) & 3, gvh = tid & 127;
  const float* gwt = cpWT + (size_t)(gvg*128)*512 + gvh*4;
  __syncthreads();

  for (int t = 0; t < 64; ++t) {
    const size_t bt = (size_t)b*64 + t;
    if (tid < 512) {
      float f1 = F1[bt*512 + tid];
      float z1 = Z1[bt*512 + tid];
      c1s[tid] = f1*h1 + (1.f - f1)*z1;
    }
    __syncthreads();
    float ga0 = 0.f, ga1 = 0.f, ga2 = 0.f, ga3 = 0.f;
    if (tid < 512) {
      int s = tid >> 2, q = tid & 3;
      const _Float16* el = enclb + (size_t)s*512;
      float acc = 0.f;
      #pragma unroll 8
      for (int j = 0; j < 16; ++j) {
        int col = j*32 + q*8;
        int byte = (s*1024 + col*2) ^ ((s&7)<<4);
        half8 eh  = *(const half8*)(encs + byte);
        half8 elv = *(const half8*)(el + col);
        const float* cr = c1s + col;
        #pragma unroll
        for (int u = 0; u < 8; ++u)
          acc += ((float)eh[u] + (float)elv[u]) * cr[u];
      }
      acc += __shfl_xor(acc,1); acc += __shfl_xor(acc,2);
      if (q == 0) scores[s] = acc;
    } else {
      #pragma unroll 8
      for (int c = 0; c < 72; ++c) {
        float cv = c1s[gvg*128 + c];
        float4 wv = *(const float4*)(gwt + (size_t)c*512);
        ga0 += wv.x*cv; ga1 += wv.y*cv; ga2 += wv.z*cv; ga3 += wv.w*cv;
      }
    }
    __syncthreads();
    float a0 = 0.f, a1 = 0.f;
    if (w < 8) {
      float s0 = scores[l], s1 = scores[l+64];
      float m = fmaxf(s0, s1);
      #pragma unroll
      for (int off=32; off; off>>=1) m = fmaxf(m, __shfl_xor(m, off));
      float e0 = expf(s0-m), e1 = expf(s1-m);
      float sm = e0+e1;
      #pragma unroll
      for (int off=32; off; off>>=1) sm += __shfl_xor(sm, off);
      float inv = 1.f/sm;
      a0 = e0*inv; a1 = e1*inv;
      if (w == 0) {
        att_probs[bt*128 + l]      = a0;
        att_probs[bt*128 + 64 + l] = a1;
      }
    }
    if (w < 4) {
      const float* pr = EPb + (size_t)(w*32)*512 + l*8;
      float p0=0,p1=0,p2=0,p3=0,p4=0,p5=0,p6=0,p7=0;
      #pragma unroll 8
      for (int si = 0; si < 32; ++si) {
        int s = w*32 + si;
        float a = (s < 64) ? __shfl(a0, s) : __shfl(a1, s - 64);
        float4 q0 = *(const float4*)(pr + (size_t)si*512);
        float4 q1 = *(const float4*)(pr + (size_t)si*512 + 4);
        p0 += a*q0.x; p1 += a*q0.y; p2 += a*q0.z; p3 += a*q0.w;
        p4 += a*q1.x; p5 += a*q1.y; p6 += a*q1.z; p7 += a*q1.w;
      }
      *(float4*)&kpq[w][l*8]   = make_float4(p0,p1,p2,p3);
      *(float4*)&kpq[w][l*8+4] = make_float4(p4,p5,p6,p7);
    } else if (w < 8) {
      int wv = w - 4;
      float k0=0,k1=0,k2=0,k3=0,k4=0,k5=0,k6=0,k7=0;
      #pragma unroll 4
      for (int si = 0; si < 32; ++si) {
        int s = wv*32 + si;
        float a = (s < 64) ? __shfl(a0, s) : __shfl(a1, s - 64);
        int byte = (s*1024 + l*16) ^ ((s&7)<<4);
        half8 v = *(const half8*)(encs + byte);
        k0 += a*(float)v[0]; k1 += a*(float)v[1];
        k2 += a*(float)v[2]; k3 += a*(float)v[3];
        k4 += a*(float)v[4]; k5 += a*(float)v[5];
        k6 += a*(float)v[6]; k7 += a*(float)v[7];
      }
      half8 st = {(_Float16)k0,(_Float16)k1,(_Float16)k2,(_Float16)k3,
                  (_Float16)k4,(_Float16)k5,(_Float16)k6,(_Float16)k7};
      *(half8*)&kqh[wv][l*8] = st;
    } else {
      #pragma unroll 8
      for (int c = 72; c < 128; ++c) {
        float cv = c1s[gvg*128 + c];
        float4 wv = *(const float4*)(gwt + (size_t)c*512);
        ga0 += wv.x*cv; ga1 += wv.y*cv; ga2 += wv.z*cv; ga3 += wv.w*cv;
      }
      *(float4*)&gvp[gvg][gvh*4] = make_float4(ga0,ga1,ga2,ga3);
    }
    __syncthreads();
    if (tid < 512) {
      float kp = kpq[0][tid] + kpq[1][tid] + kpq[2][tid] + kpq[3][tid];
      float kv = (float)kqh[0][tid] + (float)kqh[1][tid]
               + (float)kqh[2][tid] + (float)kqh[3][tid];
      float gvv = gvp[0][tid] + gvp[1][tid] + gvp[2][tid] + gvp[3][tid];
      att_vec[bt*512 + tid] = kv;
      float h1n = (gvv + kp + bsum) * O1[bt*512 + tid];
      h1 = h1n;
      A2[bt*512 + tid] = (_Float16)h1n;
    }
  }
}

// ---------------------------------------------------------------------------
extern "C" void kernel_launch(void* const* d_in, const int* in_sizes, int n_in,
                              void* d_out, int out_size, void* d_ws, size_t ws_size,
                              hipStream_t stream) {
  const float* trg  = (const float*)d_in[0];
  const float* enc  = (const float*)d_in[1];
  const float* ehid = (const float*)d_in[2];
  const float* zW0 = (const float*)d_in[5];  const float* zb0 = (const float*)d_in[6];
  const float* fW0 = (const float*)d_in[7];  const float* fb0 = (const float*)d_in[8];
  const float* oW0 = (const float*)d_in[9];  const float* ob0 = (const float*)d_in[10];
  const float* iW0 = (const float*)d_in[11]; const float* ib0 = (const float*)d_in[12];
  const float* epzW0 = (const float*)d_in[13]; const float* epzb0 = (const float*)d_in[14];
  const float* epoW0 = (const float*)d_in[15]; const float* epob0 = (const float*)d_in[16];
  const float* epiW0 = (const float*)d_in[17]; const float* epib0 = (const float*)d_in[18];
  const float* zW1 = (const float*)d_in[19]; const float* zb1 = (const float*)d_in[20];
  const float* fW1 = (const float*)d_in[21]; const float* fb1 = (const float*)d_in[22];
  const float* oW1 = (const float*)d_in[23]; const float* ob1 = (const float*)d_in[24];
  const float* epzW1 = (const float*)d_in[25]; const float* epzb1 = (const float*)d_in[26];
  const float* epoW1 = (const float*)d_in[27]; const float* epob1 = (const float*)d_in[28];
  const float* kpW = (const float*)d_in[29]; const float* kpb = (const float*)d_in[30];
  const float* cpW = (const float*)d_in[31]; const float* cpb = (const float*)d_in[32];
  const float* outW = (const float*)d_in[33];

  float* out = (float*)d_out;
  float* att_probs = out + (size_t)65536000;            // B*T*V
  float* att_vec   = att_probs + (size_t)262144;        // + B*T*S

  // SMALL (persists) in ws; BIG transients in ws if it fits, else inside
  // d_out's logits region (fully overwritten by the final GEMM). outWh only
  // exists (and the fast vocab path only runs) if ws also covers it.
  const size_t SMALL = 2097152 + 327680;
  const size_t BIG   = 79691776;
  const size_t OUTWH = 33554432;
  char* pA2  = (char*)d_ws;
  char* pep  = pA2  + 2097152;
  bool fit1 = (ws_size >= SMALL + BIG);
  bool fit2 = (ws_size >= SMALL + BIG + OUTWH);
  char* big = fit1 ? pep + 327680 : (char*)d_out;
  char* p = big;
  _Float16* A0h  = (_Float16*)p; p += 4194304;
  _Float16* A0l  = (_Float16*)p; p += 4194304;
  _Float16* W0h  = (_Float16*)p; p += 4194304;
  _Float16* W0l  = (_Float16*)p; p += 4194304;
  _Float16* A1h  = (_Float16*)p; p += 4194304;
  _Float16* A1l  = (_Float16*)p; p += 4194304;
  _Float16* W1h  = (_Float16*)p; p += 3145728;
  _Float16* W1l  = (_Float16*)p; p += 3145728;
  _Float16* ench = (_Float16*)p; p += 4194304;
  _Float16* encl = (_Float16*)p; p += 4194304;
  _Float16* kph  = (_Float16*)p; p += 524288;
  _Float16* kpl  = (_Float16*)p; p += 524288;
  float*    C0   = (float*)p;    p += 16777216;
  float*    F1   = (float*)p;    p += 4194304;
  float*    O1   = (float*)p;    p += 4194304;
  float*    Z1   = (float*)p;    p += 4194304;
  float*    EP   = (float*)p;    p += 8388608;
  float*    cpWT = (float*)p;    p += 1048576;
  _Float16* outWh = (_Float16*)p;                       // valid only if fit2
  _Float16* A2  = (_Float16*)pA2;
  float*    ep  = (float*)pep;

  hipLaunchKernelGGL(ep_proj, dim3(1280), dim3(256), 0, stream,
      ehid, epzW0,epzb0, epoW0,epob0, epiW0,epib0, epzW1,epzb1, epoW1,epob1, ep);
  hipLaunchKernelGGL(pack2, dim3(32768), dim3(256), 0, stream,
      trg, zW0,fW0,oW0,iW0, zW1,fW1,oW1, enc, kpW, cpW,
      A0h,A0l, W0h,W0l, W1h,W1l, ench,encl, kph,kpl, cpWT);
  if (fit2)
    hipLaunchKernelGGL(casth_out, dim3(8000), dim3(256), 0, stream, outW, outWh);
  hipLaunchKernelGGL(gemm3, dim3(16,16), dim3(256), 0, stream,
      A0h, A0l, W0h, W0l, C0, 1024, 2048);
  hipLaunchKernelGGL(scan0, dim3(64), dim3(256), 0, stream,
      C0, ep, zb0,fb0,ob0,ib0, A1h, A1l);
  hipLaunchKernelGGL(gemm3a, dim3(16,12), dim3(256), 0, stream,
      A1h, A1l, W1h, W1l, ep, zb1, fb1, ob1, Z1, F1, O1, 1024);
  hipLaunchKernelGGL(gemm3, dim3(32,4), dim3(256), 0, stream,
      ench, encl, kph, kpl, EP, 512, 512);
  hipLaunchKernelGGL(decode2, dim3(32), dim3(1024), 0, stream,
      ench, encl, F1, O1, Z1, EP, cpWT, kpb, cpb, att_probs, att_vec, A2);
  if (fit2)
    hipLaunchKernelGGL(gemm_hh, dim3(16,250), dim3(256), 0, stream,
        A2, outWh, out, 512, 32000);
  else
    hipLaunchKernelGGL(gemm_hf, dim3(16,250), dim3(256), 0, stream,
        A2, outW, out, 512, 32000);
}